// Round 7
// baseline (455.601 us; speedup 1.0000x reference)
//
#include <hip/hip_runtime.h>

#define D_MODEL 512
#define DINNER  1024
#define DSTATE  64
#define DTRANK  32
#define BSZ     2
#define NLEN    2048
#define NROWS   (BSZ*NLEN)   // 4096
#define XDBL_W  (DTRANK + 2*DSTATE)  // 160
#define NCH     8            // scan chunks
#define CHL     (NLEN/NCH)   // 256

typedef __attribute__((ext_vector_type(8))) short  bf16x8;
typedef __attribute__((ext_vector_type(4))) float  f32x4;
typedef __attribute__((ext_vector_type(8))) unsigned short u16x8;

__device__ __forceinline__ unsigned int rne16(float f) {
    unsigned int u = __float_as_uint(f);
    return (u + 0x7fffu + ((u >> 16) & 1)) >> 16;
}

// ---------------- LayerNorm: one wave per row ----------------
__global__ __launch_bounds__(256) void ln_kernel(const float* __restrict__ x,
        const float* __restrict__ w, const float* __restrict__ bvec,
        float* __restrict__ xn) {
    const int wid = threadIdx.x >> 6, lane = threadIdx.x & 63;
    const int row = (blockIdx.x << 2) + wid;
    const float4* xp = (const float4*)(x + (size_t)row * D_MODEL);
    float4 v0 = xp[lane], v1 = xp[lane + 64];
    float s = v0.x + v0.y + v0.z + v0.w + v1.x + v1.y + v1.z + v1.w;
    float q = v0.x*v0.x + v0.y*v0.y + v0.z*v0.z + v0.w*v0.w
            + v1.x*v1.x + v1.y*v1.y + v1.z*v1.z + v1.w*v1.w;
    #pragma unroll
    for (int m = 32; m; m >>= 1) { s += __shfl_xor(s, m); q += __shfl_xor(q, m); }
    const float mean = s * (1.f / D_MODEL);
    const float var  = q * (1.f / D_MODEL) - mean * mean;
    const float rstd = rsqrtf(var + 1e-5f);
    const float4* wp = (const float4*)w;
    const float4* bp = (const float4*)bvec;
    float4 w0 = wp[lane], w1 = wp[lane + 64], b0 = bp[lane], b1 = bp[lane + 64];
    float4 o0, o1;
    o0.x = (v0.x - mean) * rstd * w0.x + b0.x;
    o0.y = (v0.y - mean) * rstd * w0.y + b0.y;
    o0.z = (v0.z - mean) * rstd * w0.z + b0.z;
    o0.w = (v0.w - mean) * rstd * w0.w + b0.w;
    o1.x = (v1.x - mean) * rstd * w1.x + b1.x;
    o1.y = (v1.y - mean) * rstd * w1.y + b1.y;
    o1.z = (v1.z - mean) * rstd * w1.z + b1.z;
    o1.w = (v1.w - mean) * rstd * w1.w + b1.w;
    float4* op = (float4*)(xn + (size_t)row * D_MODEL);
    op[lane] = o0; op[lane + 64] = o1;
}

// ---- pack fp32 (R x K row-major) -> fragment-major split-bf16 [2*K/32][Rpad/16][64][8]
__global__ __launch_bounds__(256) void pack_hilo(const float* __restrict__ src,
        unsigned short* __restrict__ dst, int R, int RT /* Rpad/16 */, int K) {
    const int wid = threadIdx.x >> 6, lane = threadIdx.x & 63;
    const int gid = blockIdx.x * 4 + wid;          // in [0, (K/32)*RT)
    const int kt = gid / RT, rt = gid - kt * RT;
    const int row = (rt << 4) + (lane & 15);
    const int KTK = K >> 5;
    u16x8 hi = {}, lo = {};
    if (row < R) {
        const float* s = src + (size_t)row * K + kt * 32 + ((lane >> 4) << 3);
        float4 f0 = *(const float4*)s;
        float4 f1 = *(const float4*)(s + 4);
        float ff[8] = {f0.x,f0.y,f0.z,f0.w,f1.x,f1.y,f1.z,f1.w};
        #pragma unroll
        for (int j = 0; j < 8; ++j) {
            unsigned int hb = rne16(ff[j]);
            float rem = ff[j] - __uint_as_float(hb << 16);
            hi[j] = (unsigned short)hb;
            lo[j] = (unsigned short)rne16(rem);
        }
    }
    *(u16x8*)(dst + ((size_t)kt * RT + rt) * 512 + lane * 8) = hi;
    *(u16x8*)(dst + ((size_t)(kt + KTK) * RT + rt) * 512 + lane * 8) = lo;
}

// ---- MFMA GEMM on packed operands (round-6 structure, unchanged) ----
template<int BM, int BN, int WR, int WC>
__global__ __launch_bounds__(256) void gemm_mfma(
        const unsigned short* __restrict__ Ap, const unsigned short* __restrict__ Bp,
        int M, int N, int K, int cols3,
        float* __restrict__ out0, float* __restrict__ out1, int split) {
    constexpr int MI = BM / (WR * 16);
    constexpr int NI = BN / (WC * 16);
    constexpr int APASS = (BM * 64) / 4096;
    constexpr int BPASS = (BN * 64) / 4096;
    __shared__ __align__(16) unsigned short sA[BM * 32];
    __shared__ __align__(16) unsigned short sB[BN * 32];
    const int tid = threadIdx.x;
    const int wid = tid >> 6, lane = tid & 63;
    const int wr = wid / WC, wc = wid % WC;
    const int m0 = blockIdx.y * BM, n0 = blockIdx.x * BN;
    const int MT = M >> 4, NT = N >> 4;
    const int KTK = K >> 5;
    const int KTv = (n0 < cols3) ? 3 * KTK : KTK;
    f32x4 acc[MI][NI] = {};
    for (int kt = 0; kt < KTv; ++kt) {
        const int a_kt = (kt < 2 * KTK) ? kt : kt - 2 * KTK;   // hi, lo, hi
        const int b_kt = (kt < KTK) ? kt : kt - KTK;           // hi, hi, lo
        const char* gA = (const char*)(Ap + ((size_t)a_kt * MT + (m0 >> 4)) * 512);
        const char* gB = (const char*)(Bp + ((size_t)b_kt * NT + (n0 >> 4)) * 512);
        __syncthreads();
        #pragma unroll
        for (int p = 0; p < APASS; ++p)
            __builtin_amdgcn_global_load_lds(
                (const __attribute__((address_space(1))) void*)(gA + p * 4096 + tid * 16),
                (__attribute__((address_space(3))) void*)((char*)sA + p * 4096 + tid * 16),
                16, 0, 0);
        #pragma unroll
        for (int p = 0; p < BPASS; ++p)
            __builtin_amdgcn_global_load_lds(
                (const __attribute__((address_space(1))) void*)(gB + p * 4096 + tid * 16),
                (__attribute__((address_space(3))) void*)((char*)sB + p * 4096 + tid * 16),
                16, 0, 0);
        __syncthreads();
        bf16x8 af[MI], bfr[NI];
        #pragma unroll
        for (int mi = 0; mi < MI; ++mi)
            af[mi] = *(const bf16x8*)((const char*)sA + (wr*MI + mi)*1024 + lane*16);
        #pragma unroll
        for (int ni = 0; ni < NI; ++ni)
            bfr[ni] = *(const bf16x8*)((const char*)sB + (wc*NI + ni)*1024 + lane*16);
        #pragma unroll
        for (int mi = 0; mi < MI; ++mi)
            #pragma unroll
            for (int ni = 0; ni < NI; ++ni)
                acc[mi][ni] = __builtin_amdgcn_mfma_f32_16x16x32_bf16(
                    af[mi], bfr[ni], acc[mi][ni], 0, 0, 0);
    }
    #pragma unroll
    for (int mi = 0; mi < MI; ++mi) {
        #pragma unroll
        for (int ni = 0; ni < NI; ++ni) {
            const int col = n0 + (wc*NI + ni)*16 + (lane & 15);
            const int rb_ = m0 + (wr*MI + mi)*16 + ((lane >> 4) << 2);
            if (col < split) {
                #pragma unroll
                for (int r = 0; r < 4; ++r)
                    out0[(size_t)(rb_ + r) * split + col] = acc[mi][ni][r];
            } else if (out1 != nullptr) {
                #pragma unroll
                for (int r = 0; r < 4; ++r)
                    out1[(size_t)(rb_ + r) * (N - split) + (col - split)] = acc[mi][ni][r];
            }
        }
    }
}

// ---------------- causal depthwise conv (k=4) + SiLU ----------------
__global__ __launch_bounds__(256) void conv_kernel(const float* __restrict__ xr,
        const float* __restrict__ cw, const float* __restrict__ cb,
        float* __restrict__ xi) {
    const int g = blockIdx.x * 256 + threadIdx.x;
    const int d = g & (DINNER - 1);
    const int n = (g >> 10) & (NLEN - 1);
    const float4 wv = *(const float4*)(cw + d * 4);
    const float* p = xr + g;
    float acc = cb[d];
    acc = fmaf(wv.w, p[0], acc);
    if (n >= 1) acc = fmaf(wv.z, p[-DINNER], acc);
    if (n >= 2) acc = fmaf(wv.y, p[-2 * DINNER], acc);
    if (n >= 3) acc = fmaf(wv.x, p[-3 * DINNER], acc);
    xi[g] = acc / (1.f + expf(-acc));
}

// ---------------- dt = softplus(dtr @ W^T + b) ----------------
__global__ __launch_bounds__(256) void dt_kernel(const float* __restrict__ xdbl,
        const float* __restrict__ W, const float* __restrict__ bias,
        float* __restrict__ dt) {
    const int row = blockIdx.x;
    __shared__ float r[DTRANK];
    if (threadIdx.x < DTRANK) r[threadIdx.x] = xdbl[(size_t)row * XDBL_W + threadIdx.x];
    __syncthreads();
    #pragma unroll
    for (int q = 0; q < 4; ++q) {
        const int d = (q << 8) + threadIdx.x;
        float acc = bias[d];
        const float* wp = W + (size_t)d * DTRANK;
        #pragma unroll
        for (int j = 0; j < DTRANK; ++j) acc = fmaf(r[j], wp[j], acc);
        dt[(size_t)row * DINNER + d] = (acc > 20.f) ? acc : log1pf(expf(acc));
    }
}

// ---- pack B,C (from xdbl) into one u32: lo=bf16(B), hi=bf16(C) ----
__global__ __launch_bounds__(256) void bc_pack(const float* __restrict__ xdbl,
        unsigned int* __restrict__ bc) {
    const int g = blockIdx.x * 256 + threadIdx.x;   // row*64+s, row=b*NLEN+n
    const int s = g & 63, row = g >> 6;
    const float Bv = xdbl[(size_t)row * XDBL_W + DTRANK + s];
    const float Cv = xdbl[(size_t)row * XDBL_W + DTRANK + DSTATE + s];
    bc[g] = rne16(Bv) | (rne16(Cv) << 16);
}

// ---- scan phase 1: per (b,chunk,d) local scan with h_start=0 ----
// w = (b*8+c)*1024+d; block = 4 waves, same (b,c), consecutive d (L1 reuse of BC).
// Writes y_local to yt, h_last, T_c = sum(dt over chunk).
__global__ __launch_bounds__(256) void scan_p1(const float* __restrict__ dt,
        const float* __restrict__ u, const unsigned int* __restrict__ bc,
        const float* __restrict__ A_log, float* __restrict__ yt,
        float* __restrict__ hlast, float* __restrict__ Tc) {
    __shared__ float p[4][32][65];
    const int wid = threadIdx.x >> 6, lane = threadIdx.x & 63;
    const int w = (blockIdx.x << 2) + wid;
    const int d = w & 1023, c = (w >> 10) & 7, b = w >> 13;
    const int nbase = c * CHL;
    const float* dtp = dt + ((size_t)b * NLEN + nbase) * DINNER + d;
    const float* up  = u  + ((size_t)b * NLEN + nbase) * DINNER + d;
    const unsigned int* bcp = bc + ((size_t)b * NLEN + nbase) * 64 + lane;
    float* yp = yt + ((size_t)b * DINNER + d) * NLEN + nbase;
    const float kA = -__builtin_amdgcn_exp2f(A_log[d * DSTATE + lane] * 1.44269504f)
                     * 1.44269504f;
    float (*pw)[65] = p[wid];
    const int rn = lane & 31, rs = (lane >> 5) << 5;
    float h = 0.f, tsum = 0.f;
    for (int n0 = 0; n0 < CHL; n0 += 64) {
        const float dtv = dtp[(size_t)(n0 + lane) * DINNER];
        const float uv  = up [(size_t)(n0 + lane) * DINNER];
        const float dtu = dtv * uv;
        tsum += dtv;
        #pragma unroll
        for (int half = 0; half < 2; ++half) {
            const unsigned int* bn = bcp + (size_t)(n0 + 32 * half) * 64;
            #pragma unroll
            for (int j = 0; j < 32; ++j) {
                const unsigned int q = bn[(size_t)j * 64];
                const float Bv = __uint_as_float(q << 16);
                const float Cv = __uint_as_float(q & 0xffff0000u);
                const float sdt = __int_as_float(
                    __builtin_amdgcn_readlane(__float_as_int(dtv), 32 * half + j));
                const float sdu = __int_as_float(
                    __builtin_amdgcn_readlane(__float_as_int(dtu), 32 * half + j));
                h = fmaf(__builtin_amdgcn_exp2f(kA * sdt), h, sdu * Bv);
                pw[j][lane] = h * Cv;
            }
            float y0 = 0.f, y1 = 0.f, y2 = 0.f, y3 = 0.f;
            #pragma unroll
            for (int i = 0; i < 32; i += 4) {
                y0 += pw[rn][rs + i];
                y1 += pw[rn][rs + i + 1];
                y2 += pw[rn][rs + i + 2];
                y3 += pw[rn][rs + i + 3];
            }
            float y = (y0 + y1) + (y2 + y3);
            y += __shfl_xor(y, 32);
            if (lane < 32) yp[n0 + 32 * half + rn] = y;
        }
    }
    hlast[(size_t)w * 64 + lane] = h;
    #pragma unroll
    for (int m = 32; m; m >>= 1) tsum += __shfl_xor(tsum, m);
    if (lane == 0) Tc[w] = tsum;
}

// ---- scan phase 2: per (b,d) chunk-prefix: h_start_c ----
__global__ __launch_bounds__(256) void scan_p2(const float* __restrict__ hlast,
        const float* __restrict__ Tc, const float* __restrict__ A_log,
        float* __restrict__ hstart) {
    const int wid = threadIdx.x >> 6, lane = threadIdx.x & 63;
    const int w = (blockIdx.x << 2) + wid;   // b*1024+d
    const int d = w & 1023, b = w >> 10;
    const float kA = -__builtin_amdgcn_exp2f(A_log[d * DSTATE + lane] * 1.44269504f)
                     * 1.44269504f;
    float h = 0.f;
    #pragma unroll
    for (int c = 0; c < NCH; ++c) {
        const size_t idx = ((size_t)(b * 8 + c) << 10) + d;
        hstart[idx * 64 + lane] = h;
        const float T = Tc[idx];
        h = fmaf(__builtin_amdgcn_exp2f(kA * T), h, hlast[idx * 64 + lane]);
    }
}

// ---- scan phase 3: correction y_n += sum_s C_n[s]*exp2(kA_s*S_n)*hstart[s] ----
// w = (b*7 + (c-1))*1024 + d, c in [1,8). S_n = running dt prefix (scalar add).
__global__ __launch_bounds__(256) void scan_p3(const float* __restrict__ dt,
        const unsigned int* __restrict__ bc, const float* __restrict__ hstart,
        const float* __restrict__ A_log, float* __restrict__ yt) {
    __shared__ float p[4][32][65];
    const int wid = threadIdx.x >> 6, lane = threadIdx.x & 63;
    const int w = (blockIdx.x << 2) + wid;
    const int d = w & 1023;
    const int t = w >> 10;                    // b*7 + (c-1), t in [0,14)
    const int b = (t >= 7) ? 1 : 0;
    const int c = t - b * 7 + 1;
    const int nbase = c * CHL;
    const float* dtp = dt + ((size_t)b * NLEN + nbase) * DINNER + d;
    const unsigned int* bcp = bc + ((size_t)b * NLEN + nbase) * 64 + lane;
    float* yp = yt + ((size_t)b * DINNER + d) * NLEN + nbase;
    const float kA = -__builtin_amdgcn_exp2f(A_log[d * DSTATE + lane] * 1.44269504f)
                     * 1.44269504f;
    const float hs = hstart[(((size_t)(b * 8 + c) << 10) + d) * 64 + lane];
    float (*pw)[65] = p[wid];
    const int rn = lane & 31, rs = (lane >> 5) << 5;
    float S = 0.f;
    for (int n0 = 0; n0 < CHL; n0 += 64) {
        const float dtv = dtp[(size_t)(n0 + lane) * DINNER];
        #pragma unroll
        for (int half = 0; half < 2; ++half) {
            const unsigned int* bn = bcp + (size_t)(n0 + 32 * half) * 64;
            #pragma unroll
            for (int j = 0; j < 32; ++j) {
                const unsigned int q = bn[(size_t)j * 64];
                const float Cv = __uint_as_float(q & 0xffff0000u);
                S += __int_as_float(
                    __builtin_amdgcn_readlane(__float_as_int(dtv), 32 * half + j));
                pw[j][lane] = __builtin_amdgcn_exp2f(kA * S) * hs * Cv;
            }
            float y0 = 0.f, y1 = 0.f, y2 = 0.f, y3 = 0.f;
            #pragma unroll
            for (int i = 0; i < 32; i += 4) {
                y0 += pw[rn][rs + i];
                y1 += pw[rn][rs + i + 1];
                y2 += pw[rn][rs + i + 2];
                y3 += pw[rn][rs + i + 3];
            }
            float y = (y0 + y1) + (y2 + y3);
            y += __shfl_xor(y, 32);
            if (lane < 32) yp[n0 + 32 * half + rn] += y;
        }
    }
}

// ---------------- gate: yg = (yt^T + xi*D) * silu(z) ----------------
__global__ __launch_bounds__(256) void gate_kernel(const float* __restrict__ yt,
        const float* __restrict__ xi, const float* __restrict__ z,
        const float* __restrict__ Dv, float* __restrict__ yg) {
    const int g = blockIdx.x * 256 + threadIdx.x;
    const int d = g & (DINNER - 1);
    const int n = (g >> 10) & (NLEN - 1);
    const int b = g >> 21;
    const float yv = yt[((size_t)b * DINNER + d) * NLEN + n];
    const float zv = z[g];
    yg[g] = fmaf(xi[g], Dv[d], yv) * (zv / (1.f + expf(-zv)));
}

extern "C" void kernel_launch(void* const* d_in, const int* in_sizes, int n_in,
                              void* d_out, int out_size, void* d_ws, size_t ws_size,
                              hipStream_t stream) {
    const float* x         = (const float*)d_in[0];
    const float* norm_w    = (const float*)d_in[1];
    const float* norm_b    = (const float*)d_in[2];
    const float* in_proj_w = (const float*)d_in[3];
    const float* conv_w    = (const float*)d_in[4];
    const float* conv_b    = (const float*)d_in[5];
    const float* x_proj_w  = (const float*)d_in[6];
    const float* dt_proj_w = (const float*)d_in[7];
    const float* dt_proj_b = (const float*)d_in[8];
    const float* A_log     = (const float*)d_in[9];
    const float* Dvec      = (const float*)d_in[10];
    const float* out_proj_w= (const float*)d_in[11];
    float* out = (float*)d_out;
    float* ws  = (float*)d_ws;

    const size_t M1 = (size_t)1024 * 1024;
    float* xn_dt = ws;                  // xn (2M f) then dt (4M f)
    float* xiraw = ws + 4*M1;           // xi pre-conv; later yg
    float* zbuf  = ws + 8*M1;
    float* xibuf = ws + 12*M1;
    float* xdbl  = ws + 16*M1;          // 0.66M f
    float* ytbuf = ws + 17*M1;          // 4M f
    unsigned short* Apack = (unsigned short*)(ws + 21*M1);  // up to 8.4M u16
    unsigned short* Bpack = (unsigned short*)(ws + 26*M1);  // up to 2.1M u16
    // scan scratch overlaps the Apack region (dead between x_proj and out_proj):
    unsigned int* bcbuf = (unsigned int*)(ws + 21*M1);      // 256K u32
    float* hlast  = ws + 22*M1;         // 1M f
    float* hstart = ws + 23*M1;         // 1M f
    float* Tcbuf  = ws + 24*M1;         // 16K f

    ln_kernel<<<NROWS / 4, 256, 0, stream>>>(x, norm_w, norm_b, xn_dt);

    // ---- in_proj: M=4096,N=2048,K=512; xi half 3-term, z half 1-term ----
    pack_hilo<<<(16 * 256) / 4, 256, 0, stream>>>(xn_dt, Apack, 4096, 256, 512);
    pack_hilo<<<(16 * 128) / 4, 256, 0, stream>>>(in_proj_w, Bpack, 2048, 128, 512);
    gemm_mfma<128,128,2,2><<<dim3(16, 32), 256, 0, stream>>>(
        Apack, Bpack, 4096, 2048, 512, /*cols3=*/DINNER, xiraw, zbuf, DINNER);

    conv_kernel<<<(BSZ * NLEN * DINNER) / 256, 256, 0, stream>>>(
        xiraw, conv_w, conv_b, xibuf);

    // ---- x_proj: M=4096,N=160(pad 192),K=1024; 3-term ----
    pack_hilo<<<(32 * 256) / 4, 256, 0, stream>>>(xibuf, Apack, 4096, 256, 1024);
    pack_hilo<<<(32 * 16) / 4, 256, 0, stream>>>(x_proj_w, Bpack, 160, 16, 1024);
    gemm_mfma<64,64,2,2><<<dim3(3, 64), 256, 0, stream>>>(
        Apack, Bpack, 4096, 256, 1024, /*cols3=*/256, xdbl, nullptr, XDBL_W);

    // ---- scan (chunk-parallel, 3 phases) ----
    bc_pack<<<(NROWS * 64) / 256, 256, 0, stream>>>(xdbl, bcbuf);
    dt_kernel<<<NROWS, 256, 0, stream>>>(xdbl, dt_proj_w, dt_proj_b, xn_dt);
    scan_p1<<<(BSZ * NCH * DINNER) / 4, 256, 0, stream>>>(
        xn_dt, xibuf, bcbuf, A_log, ytbuf, hlast, Tcbuf);
    scan_p2<<<(BSZ * DINNER) / 4, 256, 0, stream>>>(hlast, Tcbuf, A_log, hstart);
    scan_p3<<<(BSZ * (NCH - 1) * DINNER) / 4, 256, 0, stream>>>(
        xn_dt, bcbuf, hstart, A_log, ytbuf);

    gate_kernel<<<(BSZ * NLEN * DINNER) / 256, 256, 0, stream>>>(
        ytbuf, xibuf, zbuf, Dvec, xiraw);

    // ---- out_proj: M=4096,N=512,K=1024; 3-term ----
    pack_hilo<<<(32 * 256) / 4, 256, 0, stream>>>(xiraw, Apack, 4096, 256, 1024);
    pack_hilo<<<(32 * 32) / 4, 256, 0, stream>>>(out_proj_w, Bpack, 512, 32, 1024);
    gemm_mfma<64,64,2,2><<<dim3(8, 64), 256, 0, stream>>>(
        Apack, Bpack, 4096, 512, 1024, /*cols3=*/512, out, nullptr, D_MODEL);
}

// Round 8
// 388.439 us; speedup vs baseline: 1.1729x; 1.1729x over previous
//
#include <hip/hip_runtime.h>

#define D_MODEL 512
#define DINNER  1024
#define DSTATE  64
#define DTRANK  32
#define BSZ     2
#define NLEN    2048
#define NROWS   (BSZ*NLEN)   // 4096
#define XDBL_W  (DTRANK + 2*DSTATE)  // 160

typedef __attribute__((ext_vector_type(8))) short  bf16x8;
typedef __attribute__((ext_vector_type(4))) float  f32x4;
typedef __attribute__((ext_vector_type(8))) unsigned short u16x8;

__device__ __forceinline__ unsigned int rne16(float f) {
    unsigned int u = __float_as_uint(f);
    return (u + 0x7fffu + ((u >> 16) & 1)) >> 16;
}

// ---------------- zero-init for atomic-accumulated outputs ----------------
__global__ __launch_bounds__(256) void zero2_kernel(float* __restrict__ p0, int n0,
        float* __restrict__ p1, int n1) {
    const int i = (blockIdx.x * 256 + threadIdx.x) * 4;
    if (i < n0) *(float4*)(p0 + i) = make_float4(0.f, 0.f, 0.f, 0.f);
    const int j = i - n0;
    if (j >= 0 && j < n1) *(float4*)(p1 + j) = make_float4(0.f, 0.f, 0.f, 0.f);
}

// ---------------- LayerNorm: one wave per row ----------------
__global__ __launch_bounds__(256) void ln_kernel(const float* __restrict__ x,
        const float* __restrict__ w, const float* __restrict__ bvec,
        float* __restrict__ xn) {
    const int wid = threadIdx.x >> 6, lane = threadIdx.x & 63;
    const int row = (blockIdx.x << 2) + wid;
    const float4* xp = (const float4*)(x + (size_t)row * D_MODEL);
    float4 v0 = xp[lane], v1 = xp[lane + 64];
    float s = v0.x + v0.y + v0.z + v0.w + v1.x + v1.y + v1.z + v1.w;
    float q = v0.x*v0.x + v0.y*v0.y + v0.z*v0.z + v0.w*v0.w
            + v1.x*v1.x + v1.y*v1.y + v1.z*v1.z + v1.w*v1.w;
    #pragma unroll
    for (int m = 32; m; m >>= 1) { s += __shfl_xor(s, m); q += __shfl_xor(q, m); }
    const float mean = s * (1.f / D_MODEL);
    const float var  = q * (1.f / D_MODEL) - mean * mean;
    const float rstd = rsqrtf(var + 1e-5f);
    const float4* wp = (const float4*)w;
    const float4* bp = (const float4*)bvec;
    float4 w0 = wp[lane], w1 = wp[lane + 64], b0 = bp[lane], b1 = bp[lane + 64];
    float4 o0, o1;
    o0.x = (v0.x - mean) * rstd * w0.x + b0.x;
    o0.y = (v0.y - mean) * rstd * w0.y + b0.y;
    o0.z = (v0.z - mean) * rstd * w0.z + b0.z;
    o0.w = (v0.w - mean) * rstd * w0.w + b0.w;
    o1.x = (v1.x - mean) * rstd * w1.x + b1.x;
    o1.y = (v1.y - mean) * rstd * w1.y + b1.y;
    o1.z = (v1.z - mean) * rstd * w1.z + b1.z;
    o1.w = (v1.w - mean) * rstd * w1.w + b1.w;
    float4* op = (float4*)(xn + (size_t)row * D_MODEL);
    op[lane] = o0; op[lane + 64] = o1;
}

// ---- pack fp32 (R x K row-major) -> fragment-major split-bf16 [2*K/32][Rpad/16][64][8]
__global__ __launch_bounds__(256) void pack_hilo(const float* __restrict__ src,
        unsigned short* __restrict__ dst, int R, int RT /* Rpad/16 */, int K) {
    const int wid = threadIdx.x >> 6, lane = threadIdx.x & 63;
    const int gid = blockIdx.x * 4 + wid;          // in [0, (K/32)*RT)
    const int kt = gid / RT, rt = gid - kt * RT;
    const int row = (rt << 4) + (lane & 15);
    const int KTK = K >> 5;
    u16x8 hi = {}, lo = {};
    if (row < R) {
        const float* s = src + (size_t)row * K + kt * 32 + ((lane >> 4) << 3);
        float4 f0 = *(const float4*)s;
        float4 f1 = *(const float4*)(s + 4);
        float ff[8] = {f0.x,f0.y,f0.z,f0.w,f1.x,f1.y,f1.z,f1.w};
        #pragma unroll
        for (int j = 0; j < 8; ++j) {
            unsigned int hb = rne16(ff[j]);
            float rem = ff[j] - __uint_as_float(hb << 16);
            hi[j] = (unsigned short)hb;
            lo[j] = (unsigned short)rne16(rem);
        }
    }
    *(u16x8*)(dst + ((size_t)kt * RT + rt) * 512 + lane * 8) = hi;
    *(u16x8*)(dst + ((size_t)(kt + KTK) * RT + rt) * 512 + lane * 8) = lo;
}

// ---- MFMA GEMM on packed operands, BK=64 (2 k-tiles per barrier pair).
// ATOMIC=false: per-block term count by cols3 (3-term split xi / 1-term z),
//               store epilogue split across out0/out1.
// ATOMIC=true : one term per blockIdx.z (0:hi*hi, 1:lo*hi, 2:hi*lo), K-tiles=K/32,
//               atomicAdd epilogue into zero-initialized out0 (cols >= split dropped).
template<int BM, int BN, int WR, int WC, bool ATOMIC>
__global__ __launch_bounds__(256) void gemm_mfma(
        const unsigned short* __restrict__ Ap, const unsigned short* __restrict__ Bp,
        int M, int N, int K, int cols3,
        float* __restrict__ out0, float* __restrict__ out1, int split) {
    constexpr int MI = BM / (WR * 16);
    constexpr int NI = BN / (WC * 16);
    constexpr int APASS = BM / 64;   // 4KB LDS per pass, 256 thr x 16B
    constexpr int BPASS = BN / 64;
    __shared__ __align__(16) unsigned short sA[2 * BM * 32];
    __shared__ __align__(16) unsigned short sB[2 * BN * 32];
    const int tid = threadIdx.x;
    const int wid = tid >> 6, lane = tid & 63;
    const int wr = wid / WC, wc = wid % WC;
    const int m0 = blockIdx.y * BM, n0 = blockIdx.x * BN;
    const int MT = M >> 4, NT = N >> 4;
    const int KTK = K >> 5;
    const int KTv = ATOMIC ? KTK : ((n0 < cols3) ? 3 * KTK : KTK);
    const int aoff = (ATOMIC && blockIdx.z == 1) ? KTK : 0;
    const int boff = (ATOMIC && blockIdx.z == 2) ? KTK : 0;
    f32x4 acc[MI][NI] = {};
    for (int kt2 = 0; kt2 < KTv; kt2 += 2) {
        __syncthreads();   // previous tile's readers done
        #pragma unroll
        for (int tt = 0; tt < 2; ++tt) {
            const int kt = kt2 + tt;
            int a_kt, b_kt;
            if (ATOMIC) { a_kt = kt + aoff; b_kt = kt + boff; }
            else { a_kt = (kt < 2 * KTK) ? kt : kt - 2 * KTK;   // hi, lo, hi
                   b_kt = (kt < KTK) ? kt : kt - KTK; }         // hi, hi, lo
            const char* gA = (const char*)(Ap + ((size_t)a_kt * MT + (m0 >> 4)) * 512);
            const char* gB = (const char*)(Bp + ((size_t)b_kt * NT + (n0 >> 4)) * 512);
            #pragma unroll
            for (int p = 0; p < APASS; ++p)
                __builtin_amdgcn_global_load_lds(
                    (const __attribute__((address_space(1))) void*)(gA + p * 4096 + tid * 16),
                    (__attribute__((address_space(3))) void*)((char*)sA + tt * BM * 64 + p * 4096 + tid * 16),
                    16, 0, 0);
            #pragma unroll
            for (int p = 0; p < BPASS; ++p)
                __builtin_amdgcn_global_load_lds(
                    (const __attribute__((address_space(1))) void*)(gB + p * 4096 + tid * 16),
                    (__attribute__((address_space(3))) void*)((char*)sB + tt * BN * 64 + p * 4096 + tid * 16),
                    16, 0, 0);
        }
        __syncthreads();   // compiler drains vmcnt(0) before barrier -> tiles ready
        #pragma unroll
        for (int tt = 0; tt < 2; ++tt) {
            bf16x8 af[MI], bfr[NI];
            #pragma unroll
            for (int mi = 0; mi < MI; ++mi)
                af[mi] = *(const bf16x8*)((const char*)sA + tt*BM*64 + (wr*MI + mi)*1024 + lane*16);
            #pragma unroll
            for (int ni = 0; ni < NI; ++ni)
                bfr[ni] = *(const bf16x8*)((const char*)sB + tt*BN*64 + (wc*NI + ni)*1024 + lane*16);
            #pragma unroll
            for (int mi = 0; mi < MI; ++mi)
                #pragma unroll
                for (int ni = 0; ni < NI; ++ni)
                    acc[mi][ni] = __builtin_amdgcn_mfma_f32_16x16x32_bf16(
                        af[mi], bfr[ni], acc[mi][ni], 0, 0, 0);
        }
    }
    // epilogue: C/D layout col=lane&15, row=(lane>>4)*4+reg (m89-verified)
    #pragma unroll
    for (int mi = 0; mi < MI; ++mi) {
        #pragma unroll
        for (int ni = 0; ni < NI; ++ni) {
            const int col = n0 + (wc*NI + ni)*16 + (lane & 15);
            const int rb_ = m0 + (wr*MI + mi)*16 + ((lane >> 4) << 2);
            if (col < split) {
                #pragma unroll
                for (int r = 0; r < 4; ++r) {
                    if (ATOMIC) atomicAdd(&out0[(size_t)(rb_ + r) * split + col], acc[mi][ni][r]);
                    else        out0[(size_t)(rb_ + r) * split + col] = acc[mi][ni][r];
                }
            } else if (!ATOMIC && out1 != nullptr) {
                #pragma unroll
                for (int r = 0; r < 4; ++r)
                    out1[(size_t)(rb_ + r) * (N - split) + (col - split)] = acc[mi][ni][r];
            }
        }
    }
}

// ---------------- causal depthwise conv (k=4) + SiLU ----------------
__global__ __launch_bounds__(256) void conv_kernel(const float* __restrict__ xr,
        const float* __restrict__ cw, const float* __restrict__ cb,
        float* __restrict__ xi) {
    const int g = blockIdx.x * 256 + threadIdx.x;
    const int d = g & (DINNER - 1);
    const int n = (g >> 10) & (NLEN - 1);
    const float4 wv = *(const float4*)(cw + d * 4);
    const float* p = xr + g;
    float acc = cb[d];
    acc = fmaf(wv.w, p[0], acc);
    if (n >= 1) acc = fmaf(wv.z, p[-DINNER], acc);
    if (n >= 2) acc = fmaf(wv.y, p[-2 * DINNER], acc);
    if (n >= 3) acc = fmaf(wv.x, p[-3 * DINNER], acc);
    xi[g] = acc / (1.f + expf(-acc));
}

// ---- fused: dt=softplus(xdbl[:,:32]@W^T+b), du=dt*u, both stored TRANSPOSED
// [b][d][n] (coalesced for scan); plus bc pack (bf16 B | bf16 C) per (row,s).
__global__ __launch_bounds__(256) void bcdt_kernel(const float* __restrict__ xdbl,
        const float* __restrict__ W, const float* __restrict__ bias,
        const float* __restrict__ u, float* __restrict__ dtT,
        float* __restrict__ duT, unsigned int* __restrict__ bc) {
    const int row = blockIdx.x;               // b*NLEN + n
    const int n = row & (NLEN - 1), b = row >> 11;
    __shared__ float r[DTRANK];
    if (threadIdx.x < DTRANK) r[threadIdx.x] = xdbl[(size_t)row * XDBL_W + threadIdx.x];
    __syncthreads();
    #pragma unroll
    for (int q = 0; q < 4; ++q) {
        const int d = (q << 8) + threadIdx.x;
        float acc = bias[d];
        const float* wp = W + (size_t)d * DTRANK;
        #pragma unroll
        for (int j = 0; j < DTRANK; ++j) acc = fmaf(r[j], wp[j], acc);
        const float dtv = (acc > 20.f) ? acc : log1pf(expf(acc));
        const float uv = u[(size_t)row * DINNER + d];
        const size_t t = ((size_t)(b * DINNER + d)) * NLEN + n;
        dtT[t] = dtv;
        duT[t] = dtv * uv;
    }
    if (threadIdx.x < DSTATE) {
        const float Bv = xdbl[(size_t)row * XDBL_W + DTRANK + threadIdx.x];
        const float Cv = xdbl[(size_t)row * XDBL_W + DTRANK + DSTATE + threadIdx.x];
        bc[(size_t)row * 64 + threadIdx.x] = rne16(Bv) | (rne16(Cv) << 16);
    }
}

// ---------------- selective scan: one wave per (b,d); lane = state s ----------------
// Single pass. Coalesced dtT/duT gathers (transposed layout), packed bf16 B|C
// (1 dword load + 2 bit-ops per step). Critical chain = h-FMA only; y via
// LDS-transpose reduce off the critical path (round-4 structure).
__global__ __launch_bounds__(256) void scan_kernel(const float* __restrict__ dtT,
        const float* __restrict__ duT, const unsigned int* __restrict__ bc,
        const float* __restrict__ A_log, float* __restrict__ yt) {
    __shared__ float p[4][32][65];
    const int wid = threadIdx.x >> 6;
    const int w = (blockIdx.x << 2) + wid;   // b*1024+d
    const int lane = threadIdx.x & 63;
    const int b = w >> 10, d = w & (DINNER - 1);
    const float* dtp = dtT + (size_t)w * NLEN;
    const float* dup = duT + (size_t)w * NLEN;
    const unsigned int* bcp = bc + (size_t)b * NLEN * 64 + lane;
    float* yp = yt + (size_t)w * NLEN;
    const float kA = -__builtin_amdgcn_exp2f(A_log[d * DSTATE + lane] * 1.44269504f)
                     * 1.44269504f;   // A*log2(e)
    float (*pw)[65] = p[wid];
    const int rn = lane & 31, rs = (lane >> 5) << 5;
    float h = 0.f;
    for (int n0 = 0; n0 < NLEN; n0 += 64) {
        const float dtv = dtp[n0 + lane];   // coalesced
        const float dtu = dup[n0 + lane];   // coalesced
        #pragma unroll
        for (int half = 0; half < 2; ++half) {
            const unsigned int* bn = bcp + (size_t)(n0 + 32 * half) * 64;
            #pragma unroll
            for (int j = 0; j < 32; ++j) {
                const unsigned int q = bn[(size_t)j * 64];
                const float Bv = __uint_as_float(q << 16);
                const float Cv = __uint_as_float(q & 0xffff0000u);
                const float sdt = __int_as_float(
                    __builtin_amdgcn_readlane(__float_as_int(dtv), 32 * half + j));
                const float sdu = __int_as_float(
                    __builtin_amdgcn_readlane(__float_as_int(dtu), 32 * half + j));
                h = fmaf(__builtin_amdgcn_exp2f(kA * sdt), h, sdu * Bv);
                pw[j][lane] = h * Cv;
            }
            float y0 = 0.f, y1 = 0.f, y2 = 0.f, y3 = 0.f;
            #pragma unroll
            for (int i = 0; i < 32; i += 4) {
                y0 += pw[rn][rs + i];
                y1 += pw[rn][rs + i + 1];
                y2 += pw[rn][rs + i + 2];
                y3 += pw[rn][rs + i + 3];
            }
            float y = (y0 + y1) + (y2 + y3);
            y += __shfl_xor(y, 32);
            if (lane < 32) yp[n0 + 32 * half + rn] = y;
        }
    }
}

// ---------------- gate: yg = (yt^T + xi*D) * silu(z) ----------------
__global__ __launch_bounds__(256) void gate_kernel(const float* __restrict__ yt,
        const float* __restrict__ xi, const float* __restrict__ z,
        const float* __restrict__ Dv, float* __restrict__ yg) {
    const int g = blockIdx.x * 256 + threadIdx.x;
    const int d = g & (DINNER - 1);
    const int n = (g >> 10) & (NLEN - 1);
    const int b = g >> 21;
    const float yv = yt[((size_t)b * DINNER + d) * NLEN + n];
    const float zv = z[g];
    yg[g] = fmaf(xi[g], Dv[d], yv) * (zv / (1.f + expf(-zv)));
}

extern "C" void kernel_launch(void* const* d_in, const int* in_sizes, int n_in,
                              void* d_out, int out_size, void* d_ws, size_t ws_size,
                              hipStream_t stream) {
    const float* x         = (const float*)d_in[0];
    const float* norm_w    = (const float*)d_in[1];
    const float* norm_b    = (const float*)d_in[2];
    const float* in_proj_w = (const float*)d_in[3];
    const float* conv_w    = (const float*)d_in[4];
    const float* conv_b    = (const float*)d_in[5];
    const float* x_proj_w  = (const float*)d_in[6];
    const float* dt_proj_w = (const float*)d_in[7];
    const float* dt_proj_b = (const float*)d_in[8];
    const float* A_log     = (const float*)d_in[9];
    const float* Dvec      = (const float*)d_in[10];
    const float* out_proj_w= (const float*)d_in[11];
    float* out = (float*)d_out;
    float* ws  = (float*)d_ws;

    const size_t M1 = (size_t)1024 * 1024;
    float* xn_dtT = ws;                 // xn (2M f, dead after packA_in) then dtT (4M f)
    float* xi_duT = ws + 4*M1;          // xiraw (dead after conv) -> duT -> yg
    float* zbuf   = ws + 8*M1;
    float* xibuf  = ws + 12*M1;
    float* xdbl   = ws + 16*M1;         // 0.66M f (atomic-accumulated)
    float* ytbuf  = ws + 17*M1;         // 4M f
    unsigned short* Apack = (unsigned short*)(ws + 21*M1);  // up to 8.4M u16
    unsigned short* Bpack = (unsigned short*)(ws + 26*M1);  // up to 2.1M u16
    unsigned int* bcbuf = (unsigned int*)(ws + 21*M1);      // overlaps Apack (dead)
    // total ~28M floats = 112 MB

    // zero atomic-accumulated outputs (xdbl + out)
    zero2_kernel<<<(NROWS*XDBL_W + NROWS*D_MODEL + 1023) / 1024, 256, 0, stream>>>(
        xdbl, NROWS * XDBL_W, out, NROWS * D_MODEL);

    ln_kernel<<<NROWS / 4, 256, 0, stream>>>(x, norm_w, norm_b, xn_dtT);

    // ---- in_proj: M=4096,N=2048,K=512; xi half 3-term, z half 1-term ----
    pack_hilo<<<(16 * 256) / 4, 256, 0, stream>>>(xn_dtT, Apack, 4096, 256, 512);
    pack_hilo<<<(16 * 128) / 4, 256, 0, stream>>>(in_proj_w, Bpack, 2048, 128, 512);
    gemm_mfma<128,128,2,2,false><<<dim3(16, 32), 256, 0, stream>>>(
        Apack, Bpack, 4096, 2048, 512, /*cols3=*/DINNER, xi_duT, zbuf, DINNER);

    conv_kernel<<<(BSZ * NLEN * DINNER) / 256, 256, 0, stream>>>(
        xi_duT, conv_w, conv_b, xibuf);

    // ---- x_proj: M=4096,N=160(pad 192),K=1024; 3-term via blockIdx.z + atomics ----
    pack_hilo<<<(32 * 256) / 4, 256, 0, stream>>>(xibuf, Apack, 4096, 256, 1024);
    pack_hilo<<<(32 * 16) / 4, 256, 0, stream>>>(x_proj_w, Bpack, 160, 16, 1024);
    gemm_mfma<64,64,2,2,true><<<dim3(3, 64, 3), 256, 0, stream>>>(
        Apack, Bpack, 4096, 256, 1024, 0, xdbl, nullptr, XDBL_W);

    // ---- fused dt/du transpose + bc pack; then single-pass scan ----
    bcdt_kernel<<<NROWS, 256, 0, stream>>>(xdbl, dt_proj_w, dt_proj_b,
        xibuf, xn_dtT, xi_duT, bcbuf);
    scan_kernel<<<(BSZ * DINNER) / 4, 256, 0, stream>>>(
        xn_dtT, xi_duT, bcbuf, A_log, ytbuf);

    gate_kernel<<<(BSZ * NLEN * DINNER) / 256, 256, 0, stream>>>(
        ytbuf, xibuf, zbuf, Dvec, xi_duT);

    // ---- out_proj: M=4096,N=512,K=1024; 3-term via blockIdx.z + atomics ----
    pack_hilo<<<(32 * 256) / 4, 256, 0, stream>>>(xi_duT, Apack, 4096, 256, 1024);
    pack_hilo<<<(32 * 32) / 4, 256, 0, stream>>>(out_proj_w, Bpack, 512, 32, 1024);
    gemm_mfma<64,64,2,2,true><<<dim3(8, 64, 3), 256, 0, stream>>>(
        Apack, Bpack, 4096, 512, 1024, 0, out, nullptr, D_MODEL);
}

// Round 9
// 379.844 us; speedup vs baseline: 1.1994x; 1.0226x over previous
//
#include <hip/hip_runtime.h>

#define D_MODEL 512
#define DINNER  1024
#define DSTATE  64
#define DTRANK  32
#define BSZ     2
#define NLEN    2048
#define NROWS   (BSZ*NLEN)   // 4096
#define XDBL_W  (DTRANK + 2*DSTATE)  // 160

typedef __attribute__((ext_vector_type(8))) short  bf16x8;
typedef __attribute__((ext_vector_type(4))) float  f32x4;
typedef __attribute__((ext_vector_type(8))) unsigned short u16x8;

__device__ __forceinline__ unsigned int rne16(float f) {
    unsigned int u = __float_as_uint(f);
    return (u + 0x7fffu + ((u >> 16) & 1)) >> 16;
}
__device__ __forceinline__ float fsilu(float x) {
    return x / (1.f + __builtin_amdgcn_exp2f(-x * 1.44269504f));
}

// ---------------- zero-init for atomic-accumulated outputs ----------------
__global__ __launch_bounds__(256) void zero2_kernel(float* __restrict__ p0, int n0,
        float* __restrict__ p1, int n1) {
    const int i = (blockIdx.x * 256 + threadIdx.x) * 4;
    if (i < n0) *(float4*)(p0 + i) = make_float4(0.f, 0.f, 0.f, 0.f);
    const int j = i - n0;
    if (j >= 0 && j < n1) *(float4*)(p1 + j) = make_float4(0.f, 0.f, 0.f, 0.f);
}

// ---------------- LayerNorm: one wave per row ----------------
__global__ __launch_bounds__(256) void ln_kernel(const float* __restrict__ x,
        const float* __restrict__ w, const float* __restrict__ bvec,
        float* __restrict__ xn) {
    const int wid = threadIdx.x >> 6, lane = threadIdx.x & 63;
    const int row = (blockIdx.x << 2) + wid;
    const float4* xp = (const float4*)(x + (size_t)row * D_MODEL);
    float4 v0 = xp[lane], v1 = xp[lane + 64];
    float s = v0.x + v0.y + v0.z + v0.w + v1.x + v1.y + v1.z + v1.w;
    float q = v0.x*v0.x + v0.y*v0.y + v0.z*v0.z + v0.w*v0.w
            + v1.x*v1.x + v1.y*v1.y + v1.z*v1.z + v1.w*v1.w;
    #pragma unroll
    for (int m = 32; m; m >>= 1) { s += __shfl_xor(s, m); q += __shfl_xor(q, m); }
    const float mean = s * (1.f / D_MODEL);
    const float var  = q * (1.f / D_MODEL) - mean * mean;
    const float rstd = rsqrtf(var + 1e-5f);
    const float4* wp = (const float4*)w;
    const float4* bp = (const float4*)bvec;
    float4 w0 = wp[lane], w1 = wp[lane + 64], b0 = bp[lane], b1 = bp[lane + 64];
    float4 o0, o1;
    o0.x = (v0.x - mean) * rstd * w0.x + b0.x;
    o0.y = (v0.y - mean) * rstd * w0.y + b0.y;
    o0.z = (v0.z - mean) * rstd * w0.z + b0.z;
    o0.w = (v0.w - mean) * rstd * w0.w + b0.w;
    o1.x = (v1.x - mean) * rstd * w1.x + b1.x;
    o1.y = (v1.y - mean) * rstd * w1.y + b1.y;
    o1.z = (v1.z - mean) * rstd * w1.z + b1.z;
    o1.w = (v1.w - mean) * rstd * w1.w + b1.w;
    float4* op = (float4*)(xn + (size_t)row * D_MODEL);
    op[lane] = o0; op[lane + 64] = o1;
}

// ---- pack fp32 (R x K row-major) -> fragment-major split-bf16 [2*K/32][Rpad/16][64][8]
__global__ __launch_bounds__(256) void pack_hilo(const float* __restrict__ src,
        unsigned short* __restrict__ dst, int R, int RT /* Rpad/16 */, int K) {
    const int wid = threadIdx.x >> 6, lane = threadIdx.x & 63;
    const int gid = blockIdx.x * 4 + wid;          // in [0, (K/32)*RT)
    const int kt = gid / RT, rt = gid - kt * RT;
    const int row = (rt << 4) + (lane & 15);
    const int KTK = K >> 5;
    u16x8 hi = {}, lo = {};
    if (row < R) {
        const float* s = src + (size_t)row * K + kt * 32 + ((lane >> 4) << 3);
        float4 f0 = *(const float4*)s;
        float4 f1 = *(const float4*)(s + 4);
        float ff[8] = {f0.x,f0.y,f0.z,f0.w,f1.x,f1.y,f1.z,f1.w};
        #pragma unroll
        for (int j = 0; j < 8; ++j) {
            unsigned int hb = rne16(ff[j]);
            float rem = ff[j] - __uint_as_float(hb << 16);
            hi[j] = (unsigned short)hb;
            lo[j] = (unsigned short)rne16(rem);
        }
    }
    *(u16x8*)(dst + ((size_t)kt * RT + rt) * 512 + lane * 8) = hi;
    *(u16x8*)(dst + ((size_t)(kt + KTK) * RT + rt) * 512 + lane * 8) = lo;
}

// ---- MFMA GEMM on packed operands, BK=64 (round-8 structure, unchanged) ----
template<int BM, int BN, int WR, int WC, bool ATOMIC>
__global__ __launch_bounds__(256) void gemm_mfma(
        const unsigned short* __restrict__ Ap, const unsigned short* __restrict__ Bp,
        int M, int N, int K, int cols3,
        float* __restrict__ out0, float* __restrict__ out1, int split) {
    constexpr int MI = BM / (WR * 16);
    constexpr int NI = BN / (WC * 16);
    constexpr int APASS = BM / 64;
    constexpr int BPASS = BN / 64;
    __shared__ __align__(16) unsigned short sA[2 * BM * 32];
    __shared__ __align__(16) unsigned short sB[2 * BN * 32];
    const int tid = threadIdx.x;
    const int wid = tid >> 6, lane = tid & 63;
    const int wr = wid / WC, wc = wid % WC;
    const int m0 = blockIdx.y * BM, n0 = blockIdx.x * BN;
    const int MT = M >> 4, NT = N >> 4;
    const int KTK = K >> 5;
    const int KTv = ATOMIC ? KTK : ((n0 < cols3) ? 3 * KTK : KTK);
    const int aoff = (ATOMIC && blockIdx.z == 1) ? KTK : 0;
    const int boff = (ATOMIC && blockIdx.z == 2) ? KTK : 0;
    f32x4 acc[MI][NI] = {};
    for (int kt2 = 0; kt2 < KTv; kt2 += 2) {
        __syncthreads();
        #pragma unroll
        for (int tt = 0; tt < 2; ++tt) {
            const int kt = kt2 + tt;
            int a_kt, b_kt;
            if (ATOMIC) { a_kt = kt + aoff; b_kt = kt + boff; }
            else { a_kt = (kt < 2 * KTK) ? kt : kt - 2 * KTK;   // hi, lo, hi
                   b_kt = (kt < KTK) ? kt : kt - KTK; }         // hi, hi, lo
            const char* gA = (const char*)(Ap + ((size_t)a_kt * MT + (m0 >> 4)) * 512);
            const char* gB = (const char*)(Bp + ((size_t)b_kt * NT + (n0 >> 4)) * 512);
            #pragma unroll
            for (int p = 0; p < APASS; ++p)
                __builtin_amdgcn_global_load_lds(
                    (const __attribute__((address_space(1))) void*)(gA + p * 4096 + tid * 16),
                    (__attribute__((address_space(3))) void*)((char*)sA + tt * BM * 64 + p * 4096 + tid * 16),
                    16, 0, 0);
            #pragma unroll
            for (int p = 0; p < BPASS; ++p)
                __builtin_amdgcn_global_load_lds(
                    (const __attribute__((address_space(1))) void*)(gB + p * 4096 + tid * 16),
                    (__attribute__((address_space(3))) void*)((char*)sB + tt * BN * 64 + p * 4096 + tid * 16),
                    16, 0, 0);
        }
        __syncthreads();
        #pragma unroll
        for (int tt = 0; tt < 2; ++tt) {
            bf16x8 af[MI], bfr[NI];
            #pragma unroll
            for (int mi = 0; mi < MI; ++mi)
                af[mi] = *(const bf16x8*)((const char*)sA + tt*BM*64 + (wr*MI + mi)*1024 + lane*16);
            #pragma unroll
            for (int ni = 0; ni < NI; ++ni)
                bfr[ni] = *(const bf16x8*)((const char*)sB + tt*BN*64 + (wc*NI + ni)*1024 + lane*16);
            #pragma unroll
            for (int mi = 0; mi < MI; ++mi)
                #pragma unroll
                for (int ni = 0; ni < NI; ++ni)
                    acc[mi][ni] = __builtin_amdgcn_mfma_f32_16x16x32_bf16(
                        af[mi], bfr[ni], acc[mi][ni], 0, 0, 0);
        }
    }
    #pragma unroll
    for (int mi = 0; mi < MI; ++mi) {
        #pragma unroll
        for (int ni = 0; ni < NI; ++ni) {
            const int col = n0 + (wc*NI + ni)*16 + (lane & 15);
            const int rb_ = m0 + (wr*MI + mi)*16 + ((lane >> 4) << 2);
            if (col < split) {
                #pragma unroll
                for (int r = 0; r < 4; ++r) {
                    if (ATOMIC) atomicAdd(&out0[(size_t)(rb_ + r) * split + col], acc[mi][ni][r]);
                    else        out0[(size_t)(rb_ + r) * split + col] = acc[mi][ni][r];
                }
            } else if (!ATOMIC && out1 != nullptr) {
                #pragma unroll
                for (int r = 0; r < 4; ++r)
                    out1[(size_t)(rb_ + r) * (N - split) + (col - split)] = acc[mi][ni][r];
            }
        }
    }
}

// ---- fused causal depthwise conv (k=4) + SiLU + x_proj A-pack ----
// gid=(kt,rt) fragment tile: lane covers row=rt*16+(l&15), d=kt*32+8*(l>>4)+j.
// Writes xi fp32 (for bcdt/gate) AND packed hi/lo fragments (x_proj A operand).
__global__ __launch_bounds__(256) void conv_pack(const float* __restrict__ xr,
        const float* __restrict__ cw, const float* __restrict__ cb,
        float* __restrict__ xi, unsigned short* __restrict__ Ap) {
    const int wid = threadIdx.x >> 6, lane = threadIdx.x & 63;
    const int gid = (blockIdx.x << 2) + wid;     // [0, 32*256)
    const int kt = gid >> 8, rt = gid & 255;
    const int row = (rt << 4) + (lane & 15);
    const int n = row & (NLEN - 1);
    const int d0 = (kt << 5) + ((lane >> 4) << 3);
    const float* base = xr + (size_t)row * DINNER + d0;
    const float4 z4 = make_float4(0.f, 0.f, 0.f, 0.f);
    float4 c0 = *(const float4*)base,          c1 = *(const float4*)(base + 4);
    float4 a0 = (n >= 1) ? *(const float4*)(base - DINNER)     : z4;
    float4 a1 = (n >= 1) ? *(const float4*)(base - DINNER + 4) : z4;
    float4 b0 = (n >= 2) ? *(const float4*)(base - 2*DINNER)     : z4;
    float4 b1 = (n >= 2) ? *(const float4*)(base - 2*DINNER + 4) : z4;
    float4 e0 = (n >= 3) ? *(const float4*)(base - 3*DINNER)     : z4;
    float4 e1 = (n >= 3) ? *(const float4*)(base - 3*DINNER + 4) : z4;
    float cur[8] = {c0.x,c0.y,c0.z,c0.w,c1.x,c1.y,c1.z,c1.w};
    float p1[8]  = {a0.x,a0.y,a0.z,a0.w,a1.x,a1.y,a1.z,a1.w};
    float p2[8]  = {b0.x,b0.y,b0.z,b0.w,b1.x,b1.y,b1.z,b1.w};
    float p3[8]  = {e0.x,e0.y,e0.z,e0.w,e1.x,e1.y,e1.z,e1.w};
    float o[8];
    u16x8 hi, lo;
    #pragma unroll
    for (int j = 0; j < 8; ++j) {
        const float4 wv = *(const float4*)(cw + (d0 + j) * 4);
        float a = cb[d0 + j];
        a = fmaf(wv.w, cur[j], a);
        a = fmaf(wv.z, p1[j], a);
        a = fmaf(wv.y, p2[j], a);
        a = fmaf(wv.x, p3[j], a);
        o[j] = fsilu(a);
        unsigned int hb = rne16(o[j]);
        hi[j] = (unsigned short)hb;
        lo[j] = (unsigned short)rne16(o[j] - __uint_as_float(hb << 16));
    }
    float* xo = xi + (size_t)row * DINNER + d0;
    *(float4*)xo = make_float4(o[0], o[1], o[2], o[3]);
    *(float4*)(xo + 4) = make_float4(o[4], o[5], o[6], o[7]);
    *(u16x8*)(Ap + ((size_t)kt * 256 + rt) * 512 + lane * 8) = hi;
    *(u16x8*)(Ap + ((size_t)(kt + 32) * 256 + rt) * 512 + lane * 8) = lo;
}

// ---- fused dt/du transpose + bc pack (round-8 structure, unchanged) ----
__global__ __launch_bounds__(256) void bcdt_kernel(const float* __restrict__ xdbl,
        const float* __restrict__ W, const float* __restrict__ bias,
        const float* __restrict__ u, float* __restrict__ dtT,
        float* __restrict__ duT, unsigned int* __restrict__ bc) {
    const int row = blockIdx.x;               // b*NLEN + n
    const int n = row & (NLEN - 1), b = row >> 11;
    __shared__ float r[DTRANK];
    if (threadIdx.x < DTRANK) r[threadIdx.x] = xdbl[(size_t)row * XDBL_W + threadIdx.x];
    __syncthreads();
    #pragma unroll
    for (int q = 0; q < 4; ++q) {
        const int d = (q << 8) + threadIdx.x;
        float acc = bias[d];
        const float* wp = W + (size_t)d * DTRANK;
        #pragma unroll
        for (int j = 0; j < DTRANK; ++j) acc = fmaf(r[j], wp[j], acc);
        const float dtv = (acc > 20.f) ? acc : log1pf(expf(acc));
        const float uv = u[(size_t)row * DINNER + d];
        const size_t t = ((size_t)(b * DINNER + d)) * NLEN + n;
        dtT[t] = dtv;
        duT[t] = dtv * uv;
    }
    if (threadIdx.x < DSTATE) {
        const float Bv = xdbl[(size_t)row * XDBL_W + DTRANK + threadIdx.x];
        const float Cv = xdbl[(size_t)row * XDBL_W + DTRANK + DSTATE + threadIdx.x];
        bc[(size_t)row * 64 + threadIdx.x] = rne16(Bv) | (rne16(Cv) << 16);
    }
}

// ---------------- selective scan: LDS-staged bc, double-buffered ----------------
// Block = 4 waves sharing (b); bc block (64 steps x 64 s = 16KB) staged ONCE per
// block via global_load_lds (4x traffic cut) into dbuf LDS; phase A reads it as
// conflict-free ds_read_b32 with imm offsets. dt/du prefetched one block ahead.
// One barrier per 64 steps, placed after ~2000cyc compute so vmcnt drain is free.
__global__ __launch_bounds__(256) void scan_kernel(const float* __restrict__ dtT,
        const float* __restrict__ duT, const unsigned int* __restrict__ bc,
        const float* __restrict__ A_log, float* __restrict__ yt) {
    __shared__ unsigned int bcl[2][4096];
    __shared__ float p[4][32][65];
    const int tid = threadIdx.x;
    const int wid = tid >> 6, lane = tid & 63;
    const int w = (blockIdx.x << 2) + wid;   // b*1024+d  (4 | 1024 -> uniform b)
    const int b = w >> 10, d = w & (DINNER - 1);
    const float* dtp = dtT + (size_t)w * NLEN;
    const float* dup = duT + (size_t)w * NLEN;
    const char* bsrc = (const char*)(bc + (size_t)b * NLEN * 64);
    float* yp = yt + (size_t)w * NLEN;
    const float kA = -__builtin_amdgcn_exp2f(A_log[d * DSTATE + lane] * 1.44269504f)
                     * 1.44269504f;   // A*log2(e)
    float (*pw)[65] = p[wid];
    const int rn = lane & 31, rs = (lane >> 5) << 5;
    // stage block 0
    #pragma unroll
    for (int q4 = 0; q4 < 4; ++q4)
        __builtin_amdgcn_global_load_lds(
            (const __attribute__((address_space(1))) void*)(bsrc + q4 * 4096 + tid * 16),
            (__attribute__((address_space(3))) void*)((char*)&bcl[0][0] + q4 * 4096 + tid * 16),
            16, 0, 0);
    float dtv = dtp[lane], dtu = dup[lane];
    __syncthreads();
    float h = 0.f;
    for (int blk = 0; blk < 32; ++blk) {
        const int n0 = blk << 6;
        const unsigned int* bb = &bcl[blk & 1][0];
        if (blk < 31) {   // stage next block into the other buffer
            const char* src = bsrc + (size_t)(n0 + 64) * 256;
            char* dst = (char*)&bcl[(blk & 1) ^ 1][0];
            #pragma unroll
            for (int q4 = 0; q4 < 4; ++q4)
                __builtin_amdgcn_global_load_lds(
                    (const __attribute__((address_space(1))) void*)(src + q4 * 4096 + tid * 16),
                    (__attribute__((address_space(3))) void*)(dst + q4 * 4096 + tid * 16),
                    16, 0, 0);
        }
        float ndt = 0.f, ndu = 0.f;
        if (blk < 31) { ndt = dtp[n0 + 64 + lane]; ndu = dup[n0 + 64 + lane]; }
        #pragma unroll
        for (int half = 0; half < 2; ++half) {
            #pragma unroll
            for (int j = 0; j < 32; ++j) {
                const int st = (half << 5) + j;
                const unsigned int q = bb[st * 64 + lane];   // ds_read, imm offset
                const float Bv = __uint_as_float(q << 16);
                const float Cv = __uint_as_float(q & 0xffff0000u);
                const float sdt = __int_as_float(
                    __builtin_amdgcn_readlane(__float_as_int(dtv), st));
                const float sdu = __int_as_float(
                    __builtin_amdgcn_readlane(__float_as_int(dtu), st));
                h = fmaf(__builtin_amdgcn_exp2f(kA * sdt), h, sdu * Bv);
                pw[j][lane] = h * Cv;
            }
            float y0 = 0.f, y1 = 0.f, y2 = 0.f, y3 = 0.f;
            #pragma unroll
            for (int i = 0; i < 32; i += 4) {
                y0 += pw[rn][rs + i];
                y1 += pw[rn][rs + i + 1];
                y2 += pw[rn][rs + i + 2];
                y3 += pw[rn][rs + i + 3];
            }
            float y = (y0 + y1) + (y2 + y3);
            y += __shfl_xor(y, 32);
            if (lane < 32) yp[n0 + (half << 5) + rn] = y;
        }
        __syncthreads();   // bcl[buf^1] landed (vmcnt) + all waves done with bcl[buf]
        dtv = ndt; dtu = ndu;
    }
}

// ---- fused gate + out_proj A-pack: yg=(yt^T + xi*D)*silu(z) -> packed hi/lo ----
__global__ __launch_bounds__(256) void gate_pack(const float* __restrict__ yt,
        const float* __restrict__ xi, const float* __restrict__ z,
        const float* __restrict__ Dv, unsigned short* __restrict__ Ap) {
    const int wid = threadIdx.x >> 6, lane = threadIdx.x & 63;
    const int gid = (blockIdx.x << 2) + wid;     // [0, 32*256)
    const int kt = gid >> 8, rt = gid & 255;
    const int row = (rt << 4) + (lane & 15);
    const int n = row & (NLEN - 1), b = row >> 11;
    const int d0 = (kt << 5) + ((lane >> 4) << 3);
    const float* ytp = yt + ((size_t)(b * DINNER + d0)) * NLEN + n;
    const float* xp = xi + (size_t)row * DINNER + d0;
    const float* zp = z  + (size_t)row * DINNER + d0;
    float4 x0 = *(const float4*)xp, x1 = *(const float4*)(xp + 4);
    float4 z0 = *(const float4*)zp, z1 = *(const float4*)(zp + 4);
    float4 D0 = *(const float4*)(Dv + d0), D1 = *(const float4*)(Dv + d0 + 4);
    float xv[8] = {x0.x,x0.y,x0.z,x0.w,x1.x,x1.y,x1.z,x1.w};
    float zv[8] = {z0.x,z0.y,z0.z,z0.w,z1.x,z1.y,z1.z,z1.w};
    float dv[8] = {D0.x,D0.y,D0.z,D0.w,D1.x,D1.y,D1.z,D1.w};
    u16x8 hi, lo;
    #pragma unroll
    for (int j = 0; j < 8; ++j) {
        const float yv = ytp[(size_t)j * NLEN];   // 16-lane groups read 64B contig
        const float g = fmaf(xv[j], dv[j], yv) * fsilu(zv[j]);
        unsigned int hb = rne16(g);
        hi[j] = (unsigned short)hb;
        lo[j] = (unsigned short)rne16(g - __uint_as_float(hb << 16));
    }
    *(u16x8*)(Ap + ((size_t)kt * 256 + rt) * 512 + lane * 8) = hi;
    *(u16x8*)(Ap + ((size_t)(kt + 32) * 256 + rt) * 512 + lane * 8) = lo;
}

extern "C" void kernel_launch(void* const* d_in, const int* in_sizes, int n_in,
                              void* d_out, int out_size, void* d_ws, size_t ws_size,
                              hipStream_t stream) {
    const float* x         = (const float*)d_in[0];
    const float* norm_w    = (const float*)d_in[1];
    const float* norm_b    = (const float*)d_in[2];
    const float* in_proj_w = (const float*)d_in[3];
    const float* conv_w    = (const float*)d_in[4];
    const float* conv_b    = (const float*)d_in[5];
    const float* x_proj_w  = (const float*)d_in[6];
    const float* dt_proj_w = (const float*)d_in[7];
    const float* dt_proj_b = (const float*)d_in[8];
    const float* A_log     = (const float*)d_in[9];
    const float* Dvec      = (const float*)d_in[10];
    const float* out_proj_w= (const float*)d_in[11];
    float* out = (float*)d_out;
    float* ws  = (float*)d_ws;

    const size_t M1 = (size_t)1024 * 1024;
    float* xn_dtT = ws;                 // xn (2M f, dead after packA_in) then dtT (4M f)
    float* xi_duT = ws + 4*M1;          // xiraw (dead after conv_pack) -> duT
    float* zbuf   = ws + 8*M1;
    float* xibuf  = ws + 12*M1;
    float* xdbl   = ws + 16*M1;         // 0.66M f (atomic-accumulated)
    float* ytbuf  = ws + 17*M1;         // 4M f
    unsigned short* Apack = (unsigned short*)(ws + 21*M1);  // 20MB region
    unsigned short* Bpack = (unsigned short*)(ws + 26*M1);
    unsigned int* bcbuf = (unsigned int*)(ws + 21*M1);      // overlaps Apack (dead)

    // zero atomic-accumulated outputs (xdbl + out)
    zero2_kernel<<<(NROWS*XDBL_W + NROWS*D_MODEL + 1023) / 1024, 256, 0, stream>>>(
        xdbl, NROWS * XDBL_W, out, NROWS * D_MODEL);

    ln_kernel<<<NROWS / 4, 256, 0, stream>>>(x, norm_w, norm_b, xn_dtT);

    // ---- in_proj: M=4096,N=2048,K=512; xi half 3-term, z half 1-term ----
    pack_hilo<<<(16 * 256) / 4, 256, 0, stream>>>(xn_dtT, Apack, 4096, 256, 512);
    pack_hilo<<<(16 * 128) / 4, 256, 0, stream>>>(in_proj_w, Bpack, 2048, 128, 512);
    gemm_mfma<128,128,2,2,false><<<dim3(16, 32), 256, 0, stream>>>(
        Apack, Bpack, 4096, 2048, 512, /*cols3=*/DINNER, xi_duT, zbuf, DINNER);

    // ---- fused conv+SiLU+pack: writes xibuf fp32 + Apack (x_proj A) ----
    conv_pack<<<(32 * 256) / 4, 256, 0, stream>>>(
        xi_duT, conv_w, conv_b, xibuf, Apack);

    // ---- x_proj: M=4096,N=160(pad 192),K=1024; 3-term via blockIdx.z + atomics ----
    pack_hilo<<<(32 * 16) / 4, 256, 0, stream>>>(x_proj_w, Bpack, 160, 16, 1024);
    gemm_mfma<64,64,2,2,true><<<dim3(3, 64, 3), 256, 0, stream>>>(
        Apack, Bpack, 4096, 256, 1024, 0, xdbl, nullptr, XDBL_W);

    // ---- fused dt/du transpose + bc pack; then LDS-staged scan ----
    bcdt_kernel<<<NROWS, 256, 0, stream>>>(xdbl, dt_proj_w, dt_proj_b,
        xibuf, xn_dtT, xi_duT, bcbuf);
    scan_kernel<<<(BSZ * DINNER) / 4, 256, 0, stream>>>(
        xn_dtT, xi_duT, bcbuf, A_log, ytbuf);

    // ---- fused gate+pack: Apack = out_proj A operand (bcbuf dead) ----
    gate_pack<<<(32 * 256) / 4, 256, 0, stream>>>(
        ytbuf, xibuf, zbuf, Dvec, Apack);

    // ---- out_proj: M=4096,N=512,K=1024; 3-term via blockIdx.z + atomics ----
    pack_hilo<<<(32 * 32) / 4, 256, 0, stream>>>(out_proj_w, Bpack, 512, 32, 1024);
    gemm_mfma<64,64,2,2,true><<<dim3(8, 64, 3), 256, 0, stream>>>(
        Apack, Bpack, 4096, 512, 1024, 0, out, nullptr, D_MODEL);
}

// Round 10
// 342.719 us; speedup vs baseline: 1.3294x; 1.1083x over previous
//
#include <hip/hip_runtime.h>

#define D_MODEL 512
#define DINNER  1024
#define DSTATE  64
#define DTRANK  32
#define BSZ     2
#define NLEN    2048
#define NROWS   (BSZ*NLEN)   // 4096
#define XDBL_W  (DTRANK + 2*DSTATE)  // 160

typedef __attribute__((ext_vector_type(8))) short  bf16x8;
typedef __attribute__((ext_vector_type(4))) float  f32x4;
typedef __attribute__((ext_vector_type(8))) unsigned short u16x8;

__device__ __forceinline__ unsigned int rne16(float f) {
    unsigned int u = __float_as_uint(f);
    return (u + 0x7fffu + ((u >> 16) & 1)) >> 16;
}
__device__ __forceinline__ float fsilu(float x) {
    return x / (1.f + __builtin_amdgcn_exp2f(-x * 1.44269504f));
}

// ---------------- zero-init for atomic-accumulated outputs ----------------
__global__ __launch_bounds__(256) void zero2_kernel(float* __restrict__ p0, int n0,
        float* __restrict__ p1, int n1) {
    const int i = (blockIdx.x * 256 + threadIdx.x) * 4;
    if (i < n0) *(float4*)(p0 + i) = make_float4(0.f, 0.f, 0.f, 0.f);
    const int j = i - n0;
    if (j >= 0 && j < n1) *(float4*)(p1 + j) = make_float4(0.f, 0.f, 0.f, 0.f);
}

// ---------------- LayerNorm: one wave per row ----------------
__global__ __launch_bounds__(256) void ln_kernel(const float* __restrict__ x,
        const float* __restrict__ w, const float* __restrict__ bvec,
        float* __restrict__ xn) {
    const int wid = threadIdx.x >> 6, lane = threadIdx.x & 63;
    const int row = (blockIdx.x << 2) + wid;
    const float4* xp = (const float4*)(x + (size_t)row * D_MODEL);
    float4 v0 = xp[lane], v1 = xp[lane + 64];
    float s = v0.x + v0.y + v0.z + v0.w + v1.x + v1.y + v1.z + v1.w;
    float q = v0.x*v0.x + v0.y*v0.y + v0.z*v0.z + v0.w*v0.w
            + v1.x*v1.x + v1.y*v1.y + v1.z*v1.z + v1.w*v1.w;
    #pragma unroll
    for (int m = 32; m; m >>= 1) { s += __shfl_xor(s, m); q += __shfl_xor(q, m); }
    const float mean = s * (1.f / D_MODEL);
    const float var  = q * (1.f / D_MODEL) - mean * mean;
    const float rstd = rsqrtf(var + 1e-5f);
    const float4* wp = (const float4*)w;
    const float4* bp = (const float4*)bvec;
    float4 w0 = wp[lane], w1 = wp[lane + 64], b0 = bp[lane], b1 = bp[lane + 64];
    float4 o0, o1;
    o0.x = (v0.x - mean) * rstd * w0.x + b0.x;
    o0.y = (v0.y - mean) * rstd * w0.y + b0.y;
    o0.z = (v0.z - mean) * rstd * w0.z + b0.z;
    o0.w = (v0.w - mean) * rstd * w0.w + b0.w;
    o1.x = (v1.x - mean) * rstd * w1.x + b1.x;
    o1.y = (v1.y - mean) * rstd * w1.y + b1.y;
    o1.z = (v1.z - mean) * rstd * w1.z + b1.z;
    o1.w = (v1.w - mean) * rstd * w1.w + b1.w;
    float4* op = (float4*)(xn + (size_t)row * D_MODEL);
    op[lane] = o0; op[lane + 64] = o1;
}

// ---- pack fp32 (R x K row-major) -> fragment-major split-bf16 [2*K/32][Rpad/16][64][8]
__global__ __launch_bounds__(256) void pack_hilo(const float* __restrict__ src,
        unsigned short* __restrict__ dst, int R, int RT /* Rpad/16 */, int K) {
    const int wid = threadIdx.x >> 6, lane = threadIdx.x & 63;
    const int gid = blockIdx.x * 4 + wid;          // in [0, (K/32)*RT)
    const int kt = gid / RT, rt = gid - kt * RT;
    const int row = (rt << 4) + (lane & 15);
    const int KTK = K >> 5;
    u16x8 hi = {}, lo = {};
    if (row < R) {
        const float* s = src + (size_t)row * K + kt * 32 + ((lane >> 4) << 3);
        float4 f0 = *(const float4*)s;
        float4 f1 = *(const float4*)(s + 4);
        float ff[8] = {f0.x,f0.y,f0.z,f0.w,f1.x,f1.y,f1.z,f1.w};
        #pragma unroll
        for (int j = 0; j < 8; ++j) {
            unsigned int hb = rne16(ff[j]);
            float rem = ff[j] - __uint_as_float(hb << 16);
            hi[j] = (unsigned short)hb;
            lo[j] = (unsigned short)rne16(rem);
        }
    }
    *(u16x8*)(dst + ((size_t)kt * RT + rt) * 512 + lane * 8) = hi;
    *(u16x8*)(dst + ((size_t)(kt + KTK) * RT + rt) * 512 + lane * 8) = lo;
}

// ---- MFMA GEMM on packed operands, BK=64 ----
template<int BM, int BN, int WR, int WC, bool ATOMIC>
__global__ __launch_bounds__(256) void gemm_mfma(
        const unsigned short* __restrict__ Ap, const unsigned short* __restrict__ Bp,
        int M, int N, int K, int cols3,
        float* __restrict__ out0, float* __restrict__ out1, int split) {
    constexpr int MI = BM / (WR * 16);
    constexpr int NI = BN / (WC * 16);
    constexpr int APASS = BM / 64;
    constexpr int BPASS = BN / 64;
    __shared__ __align__(16) unsigned short sA[2 * BM * 32];
    __shared__ __align__(16) unsigned short sB[2 * BN * 32];
    const int tid = threadIdx.x;
    const int wid = tid >> 6, lane = tid & 63;
    const int wr = wid / WC, wc = wid % WC;
    const int m0 = blockIdx.y * BM, n0 = blockIdx.x * BN;
    const int MT = M >> 4, NT = N >> 4;
    const int KTK = K >> 5;
    const int KTv = ATOMIC ? KTK : ((n0 < cols3) ? 3 * KTK : KTK);
    const int aoff = (ATOMIC && blockIdx.z == 1) ? KTK : 0;
    const int boff = (ATOMIC && blockIdx.z == 2) ? KTK : 0;
    f32x4 acc[MI][NI] = {};
    for (int kt2 = 0; kt2 < KTv; kt2 += 2) {
        __syncthreads();
        #pragma unroll
        for (int tt = 0; tt < 2; ++tt) {
            const int kt = kt2 + tt;
            int a_kt, b_kt;
            if (ATOMIC) { a_kt = kt + aoff; b_kt = kt + boff; }
            else { a_kt = (kt < 2 * KTK) ? kt : kt - 2 * KTK;   // hi, lo, hi
                   b_kt = (kt < KTK) ? kt : kt - KTK; }         // hi, hi, lo
            const char* gA = (const char*)(Ap + ((size_t)a_kt * MT + (m0 >> 4)) * 512);
            const char* gB = (const char*)(Bp + ((size_t)b_kt * NT + (n0 >> 4)) * 512);
            #pragma unroll
            for (int p = 0; p < APASS; ++p)
                __builtin_amdgcn_global_load_lds(
                    (const __attribute__((address_space(1))) void*)(gA + p * 4096 + tid * 16),
                    (__attribute__((address_space(3))) void*)((char*)sA + tt * BM * 64 + p * 4096 + tid * 16),
                    16, 0, 0);
            #pragma unroll
            for (int p = 0; p < BPASS; ++p)
                __builtin_amdgcn_global_load_lds(
                    (const __attribute__((address_space(1))) void*)(gB + p * 4096 + tid * 16),
                    (__attribute__((address_space(3))) void*)((char*)sB + tt * BN * 64 + p * 4096 + tid * 16),
                    16, 0, 0);
        }
        __syncthreads();
        #pragma unroll
        for (int tt = 0; tt < 2; ++tt) {
            bf16x8 af[MI], bfr[NI];
            #pragma unroll
            for (int mi = 0; mi < MI; ++mi)
                af[mi] = *(const bf16x8*)((const char*)sA + tt*BM*64 + (wr*MI + mi)*1024 + lane*16);
            #pragma unroll
            for (int ni = 0; ni < NI; ++ni)
                bfr[ni] = *(const bf16x8*)((const char*)sB + tt*BN*64 + (wc*NI + ni)*1024 + lane*16);
            #pragma unroll
            for (int mi = 0; mi < MI; ++mi)
                #pragma unroll
                for (int ni = 0; ni < NI; ++ni)
                    acc[mi][ni] = __builtin_amdgcn_mfma_f32_16x16x32_bf16(
                        af[mi], bfr[ni], acc[mi][ni], 0, 0, 0);
        }
    }
    #pragma unroll
    for (int mi = 0; mi < MI; ++mi) {
        #pragma unroll
        for (int ni = 0; ni < NI; ++ni) {
            const int col = n0 + (wc*NI + ni)*16 + (lane & 15);
            const int rb_ = m0 + (wr*MI + mi)*16 + ((lane >> 4) << 2);
            if (col < split) {
                #pragma unroll
                for (int r = 0; r < 4; ++r) {
                    if (ATOMIC) atomicAdd(&out0[(size_t)(rb_ + r) * split + col], acc[mi][ni][r]);
                    else        out0[(size_t)(rb_ + r) * split + col] = acc[mi][ni][r];
                }
            } else if (!ATOMIC && out1 != nullptr) {
                #pragma unroll
                for (int r = 0; r < 4; ++r)
                    out1[(size_t)(rb_ + r) * (N - split) + (col - split)] = acc[mi][ni][r];
            }
        }
    }
}

// ---- fused causal depthwise conv (k=4) + SiLU + x_proj A-pack ----
__global__ __launch_bounds__(256) void conv_pack(const float* __restrict__ xr,
        const float* __restrict__ cw, const float* __restrict__ cb,
        float* __restrict__ xi, unsigned short* __restrict__ Ap) {
    const int wid = threadIdx.x >> 6, lane = threadIdx.x & 63;
    const int gid = (blockIdx.x << 2) + wid;     // [0, 32*256)
    const int kt = gid >> 8, rt = gid & 255;
    const int row = (rt << 4) + (lane & 15);
    const int n = row & (NLEN - 1);
    const int d0 = (kt << 5) + ((lane >> 4) << 3);
    const float* base = xr + (size_t)row * DINNER + d0;
    const float4 z4 = make_float4(0.f, 0.f, 0.f, 0.f);
    float4 c0 = *(const float4*)base,          c1 = *(const float4*)(base + 4);
    float4 a0 = (n >= 1) ? *(const float4*)(base - DINNER)     : z4;
    float4 a1 = (n >= 1) ? *(const float4*)(base - DINNER + 4) : z4;
    float4 b0 = (n >= 2) ? *(const float4*)(base - 2*DINNER)     : z4;
    float4 b1 = (n >= 2) ? *(const float4*)(base - 2*DINNER + 4) : z4;
    float4 e0 = (n >= 3) ? *(const float4*)(base - 3*DINNER)     : z4;
    float4 e1 = (n >= 3) ? *(const float4*)(base - 3*DINNER + 4) : z4;
    float cur[8] = {c0.x,c0.y,c0.z,c0.w,c1.x,c1.y,c1.z,c1.w};
    float p1[8]  = {a0.x,a0.y,a0.z,a0.w,a1.x,a1.y,a1.z,a1.w};
    float p2[8]  = {b0.x,b0.y,b0.z,b0.w,b1.x,b1.y,b1.z,b1.w};
    float p3[8]  = {e0.x,e0.y,e0.z,e0.w,e1.x,e1.y,e1.z,e1.w};
    float o[8];
    u16x8 hi, lo;
    #pragma unroll
    for (int j = 0; j < 8; ++j) {
        const float4 wv = *(const float4*)(cw + (d0 + j) * 4);
        float a = cb[d0 + j];
        a = fmaf(wv.w, cur[j], a);
        a = fmaf(wv.z, p1[j], a);
        a = fmaf(wv.y, p2[j], a);
        a = fmaf(wv.x, p3[j], a);
        o[j] = fsilu(a);
        unsigned int hb = rne16(o[j]);
        hi[j] = (unsigned short)hb;
        lo[j] = (unsigned short)rne16(o[j] - __uint_as_float(hb << 16));
    }
    float* xo = xi + (size_t)row * DINNER + d0;
    *(float4*)xo = make_float4(o[0], o[1], o[2], o[3]);
    *(float4*)(xo + 4) = make_float4(o[4], o[5], o[6], o[7]);
    *(u16x8*)(Ap + ((size_t)kt * 256 + rt) * 512 + lane * 8) = hi;
    *(u16x8*)(Ap + ((size_t)(kt + 32) * 256 + rt) * 512 + lane * 8) = lo;
}

// ---- dt/du: tiled GEMV + softplus + LDS transpose, coalesced [b][d][n] writes ----
__global__ __launch_bounds__(256) void dtdu_kernel(const float* __restrict__ xdbl,
        const float* __restrict__ W, const float* __restrict__ bias,
        const float* __restrict__ u, float* __restrict__ dtT,
        float* __restrict__ duT) {
    __shared__ float sdtr[64][33];
    __shared__ float sW[64][33];
    __shared__ float tt[64][65];
    const int nb = blockIdx.x & 63, db = blockIdx.x >> 6;
    const int row0 = nb << 6, d0 = db << 6;
    const int i = threadIdx.x >> 2, kq = (threadIdx.x & 3) << 3;
    {
        const float* s = xdbl + (size_t)(row0 + i) * XDBL_W + kq;
        *(float4*)&sdtr[i][kq]     = *(const float4*)s;
        *(float4*)&sdtr[i][kq + 4] = *(const float4*)(s + 4);
        const float* wsrc = W + (size_t)(d0 + i) * DTRANK + kq;
        *(float4*)&sW[i][kq]     = *(const float4*)wsrc;
        *(float4*)&sW[i][kq + 4] = *(const float4*)(wsrc + 4);
    }
    __syncthreads();
    const int i4 = (threadIdx.x >> 4) << 2;   // n sub-row
    const int j4 = (threadIdx.x & 15) << 2;   // d sub-col
    float dtv[4][4], duv[4][4];
    {
        float acc[4][4] = {};
        #pragma unroll
        for (int k = 0; k < DTRANK; ++k) {
            float a[4]  = {sdtr[i4][k], sdtr[i4+1][k], sdtr[i4+2][k], sdtr[i4+3][k]};
            float bb[4] = {sW[j4][k], sW[j4+1][k], sW[j4+2][k], sW[j4+3][k]};
            #pragma unroll
            for (int ii = 0; ii < 4; ++ii)
                #pragma unroll
                for (int jj = 0; jj < 4; ++jj)
                    acc[ii][jj] = fmaf(a[ii], bb[jj], acc[ii][jj]);
        }
        float4 bv = *(const float4*)(bias + d0 + j4);
        float bb4[4] = {bv.x, bv.y, bv.z, bv.w};
        #pragma unroll
        for (int ii = 0; ii < 4; ++ii) {
            float4 uv = *(const float4*)(u + (size_t)(row0 + i4 + ii) * DINNER + d0 + j4);
            float uu[4] = {uv.x, uv.y, uv.z, uv.w};
            #pragma unroll
            for (int jj = 0; jj < 4; ++jj) {
                float z = acc[ii][jj] + bb4[jj];
                float dt = (z > 20.f) ? z : log1pf(expf(z));
                dtv[ii][jj] = dt;
                duv[ii][jj] = dt * uu[jj];
            }
        }
    }
    const int b = row0 >> 11;
    const int n0 = row0 & (NLEN - 1);
    const int jt = threadIdx.x >> 2, iq = (threadIdx.x & 3) << 4;
    float* dstD = dtT + ((size_t)(b * DINNER + d0 + jt)) * NLEN + n0 + iq;
    float* dstU = duT + ((size_t)(b * DINNER + d0 + jt)) * NLEN + n0 + iq;
    // dt pass
    #pragma unroll
    for (int ii = 0; ii < 4; ++ii)
        #pragma unroll
        for (int jj = 0; jj < 4; ++jj)
            tt[i4 + ii][j4 + jj] = dtv[ii][jj];
    __syncthreads();
    #pragma unroll
    for (int r = 0; r < 4; ++r) {
        float4 o = make_float4(tt[iq+4*r+0][jt], tt[iq+4*r+1][jt],
                               tt[iq+4*r+2][jt], tt[iq+4*r+3][jt]);
        *(float4*)(dstD + 4*r) = o;
    }
    __syncthreads();
    // du pass
    #pragma unroll
    for (int ii = 0; ii < 4; ++ii)
        #pragma unroll
        for (int jj = 0; jj < 4; ++jj)
            tt[i4 + ii][j4 + jj] = duv[ii][jj];
    __syncthreads();
    #pragma unroll
    for (int r = 0; r < 4; ++r) {
        float4 o = make_float4(tt[iq+4*r+0][jt], tt[iq+4*r+1][jt],
                               tt[iq+4*r+2][jt], tt[iq+4*r+3][jt]);
        *(float4*)(dstU + 4*r) = o;
    }
}

// ---- B/C pack + transpose: bcT[b][s][n] = bf16(B) | bf16(C)<<16 ----
__global__ __launch_bounds__(256) void bct_kernel(const float* __restrict__ xdbl,
        unsigned int* __restrict__ bcT) {
    __shared__ unsigned int t[64][65];
    const int row0 = blockIdx.x << 6;            // 64 tiles of 64 rows
    const int i = threadIdx.x >> 2, sq = (threadIdx.x & 3) << 4;
    const float* src = xdbl + (size_t)(row0 + i) * XDBL_W + DTRANK;
    #pragma unroll
    for (int k = 0; k < 4; ++k) {
        float4 Bv = *(const float4*)(src + sq + 4*k);
        float4 Cv = *(const float4*)(src + DSTATE + sq + 4*k);
        t[i][sq+4*k+0] = rne16(Bv.x) | (rne16(Cv.x) << 16);
        t[i][sq+4*k+1] = rne16(Bv.y) | (rne16(Cv.y) << 16);
        t[i][sq+4*k+2] = rne16(Bv.z) | (rne16(Cv.z) << 16);
        t[i][sq+4*k+3] = rne16(Bv.w) | (rne16(Cv.w) << 16);
    }
    __syncthreads();
    const int s = threadIdx.x >> 2, iq = (threadIdx.x & 3) << 4;
    const int b = row0 >> 11, n0 = row0 & (NLEN - 1);
    unsigned int* dst = bcT + ((size_t)b << 17) + ((size_t)s << 11) + n0 + iq;
    #pragma unroll
    for (int r = 0; r < 4; ++r) {
        uint4 o = make_uint4(t[iq+4*r+0][s], t[iq+4*r+1][s],
                             t[iq+4*r+2][s], t[iq+4*r+3][s]);
        *(uint4*)(dst + 4*r) = o;
    }
}

// ---------------- selective scan: barrier-free, reg-buffered bcT ----------------
// Wave = (b,d); lane = s. Per 64-step block: 16 dwordx4 loads of this lane's s-
// column (contiguous in n via bcT), double-buffered in VGPRs across blocks.
// dt/du read via wave-uniform scalar loads (SGPR operands). Critical chain =
// h-FMA only; y via per-wave LDS-transpose reduce. NO __syncthreads anywhere.
#define SCAN_LOAD(buf, nb0) { \
    _Pragma("unroll") \
    for (int g = 0; g < 16; ++g) buf[g] = *(const uint4*)(bp + (nb0) + g*4); }

#define SCAN_BLOCK(buf, nb0) { \
    _Pragma("unroll") \
    for (int half = 0; half < 2; ++half) { \
        _Pragma("unroll") \
        for (int j = 0; j < 32; ++j) { \
            const int st = half*32 + j; \
            const uint4 qq = buf[st >> 2]; \
            const unsigned int q = ((st&3)==0) ? qq.x : ((st&3)==1) ? qq.y \
                                 : ((st&3)==2) ? qq.z : qq.w; \
            const float sdt = dtp[(nb0) + st]; \
            const float sdu = dup[(nb0) + st]; \
            h = fmaf(__builtin_amdgcn_exp2f(kA * sdt), h, \
                     sdu * __uint_as_float(q << 16)); \
            pw[j][lane] = h * __uint_as_float(q & 0xffff0000u); \
        } \
        float y0 = 0.f, y1 = 0.f, y2 = 0.f, y3 = 0.f; \
        _Pragma("unroll") \
        for (int i2 = 0; i2 < 32; i2 += 4) { \
            y0 += pw[rn][rs + i2];     y1 += pw[rn][rs + i2 + 1]; \
            y2 += pw[rn][rs + i2 + 2]; y3 += pw[rn][rs + i2 + 3]; } \
        float y = (y0 + y1) + (y2 + y3); \
        y += __shfl_xor(y, 32); \
        if (lane < 32) yp[(nb0) + half*32 + rn] = y; \
    } }

__global__ __launch_bounds__(256, 2) void scan_kernel(const float* __restrict__ dtT,
        const float* __restrict__ duT, const unsigned int* __restrict__ bcT,
        const float* __restrict__ A_log, float* __restrict__ yt) {
    __shared__ float p[4][32][65];
    const int tid = threadIdx.x;
    const int wid = __builtin_amdgcn_readfirstlane(tid >> 6);
    const int lane = tid & 63;
    const int w = (blockIdx.x << 2) + wid;   // b*1024+d  (uniform)
    const int b = w >> 10, d = w & (DINNER - 1);
    const float* dtp = dtT + (size_t)w * NLEN;            // wave-uniform
    const float* dup = duT + (size_t)w * NLEN;            // wave-uniform
    const unsigned int* bp = bcT + ((size_t)b << 17) + ((size_t)lane << 11);
    float* yp = yt + (size_t)w * NLEN;
    const float kA = -__builtin_amdgcn_exp2f(A_log[d * DSTATE + lane] * 1.44269504f)
                     * 1.44269504f;   // A*log2(e)
    float (*pw)[65] = p[wid];
    const int rn = lane & 31, rs = (lane >> 5) << 5;
    float h = 0.f;
    uint4 bufA[16], bufB[16];
    SCAN_LOAD(bufA, 0)
    #pragma unroll 1
    for (int pr = 0; pr < 16; ++pr) {
        const int n0 = pr << 7;
        SCAN_LOAD(bufB, n0 + 64)
        SCAN_BLOCK(bufA, n0)
        if (pr < 15) SCAN_LOAD(bufA, n0 + 128)
        SCAN_BLOCK(bufB, n0 + 64)
    }
}

// ---- fused gate + out_proj A-pack: yg=(yt^T + xi*D)*silu(z) -> packed hi/lo ----
__global__ __launch_bounds__(256) void gate_pack(const float* __restrict__ yt,
        const float* __restrict__ xi, const float* __restrict__ z,
        const float* __restrict__ Dv, unsigned short* __restrict__ Ap) {
    const int wid = threadIdx.x >> 6, lane = threadIdx.x & 63;
    const int gid = (blockIdx.x << 2) + wid;     // [0, 32*256)
    const int kt = gid >> 8, rt = gid & 255;
    const int row = (rt << 4) + (lane & 15);
    const int n = row & (NLEN - 1), b = row >> 11;
    const int d0 = (kt << 5) + ((lane >> 4) << 3);
    const float* ytp = yt + ((size_t)(b * DINNER + d0)) * NLEN + n;
    const float* xp = xi + (size_t)row * DINNER + d0;
    const float* zp = z  + (size_t)row * DINNER + d0;
    float4 x0 = *(const float4*)xp, x1 = *(const float4*)(xp + 4);
    float4 z0 = *(const float4*)zp, z1 = *(const float4*)(zp + 4);
    float4 D0 = *(const float4*)(Dv + d0), D1 = *(const float4*)(Dv + d0 + 4);
    float xv[8] = {x0.x,x0.y,x0.z,x0.w,x1.x,x1.y,x1.z,x1.w};
    float zv[8] = {z0.x,z0.y,z0.z,z0.w,z1.x,z1.y,z1.z,z1.w};
    float dv[8] = {D0.x,D0.y,D0.z,D0.w,D1.x,D1.y,D1.z,D1.w};
    u16x8 hi, lo;
    #pragma unroll
    for (int j = 0; j < 8; ++j) {
        const float yv = ytp[(size_t)j * NLEN];
        const float g = fmaf(xv[j], dv[j], yv) * fsilu(zv[j]);
        unsigned int hb = rne16(g);
        hi[j] = (unsigned short)hb;
        lo[j] = (unsigned short)rne16(g - __uint_as_float(hb << 16));
    }
    *(u16x8*)(Ap + ((size_t)kt * 256 + rt) * 512 + lane * 8) = hi;
    *(u16x8*)(Ap + ((size_t)(kt + 32) * 256 + rt) * 512 + lane * 8) = lo;
}

extern "C" void kernel_launch(void* const* d_in, const int* in_sizes, int n_in,
                              void* d_out, int out_size, void* d_ws, size_t ws_size,
                              hipStream_t stream) {
    const float* x         = (const float*)d_in[0];
    const float* norm_w    = (const float*)d_in[1];
    const float* norm_b    = (const float*)d_in[2];
    const float* in_proj_w = (const float*)d_in[3];
    const float* conv_w    = (const float*)d_in[4];
    const float* conv_b    = (const float*)d_in[5];
    const float* x_proj_w  = (const float*)d_in[6];
    const float* dt_proj_w = (const float*)d_in[7];
    const float* dt_proj_b = (const float*)d_in[8];
    const float* A_log     = (const float*)d_in[9];
    const float* Dvec      = (const float*)d_in[10];
    const float* out_proj_w= (const float*)d_in[11];
    float* out = (float*)d_out;
    float* ws  = (float*)d_ws;

    const size_t M1 = (size_t)1024 * 1024;
    float* xn_dtT = ws;                 // xn (2M f) then dtT (4M f)
    float* xi_duT = ws + 4*M1;          // xiraw (dead after conv_pack) -> duT
    float* zbuf   = ws + 8*M1;
    float* xibuf  = ws + 12*M1;
    float* xdbl   = ws + 16*M1;         // 0.66M f (atomic-accumulated)
    float* ytbuf  = ws + 17*M1;         // 4M f
    unsigned short* Apack = (unsigned short*)(ws + 21*M1);  // fragment region
    unsigned short* Bpack = (unsigned short*)(ws + 26*M1);
    unsigned int* bcT = (unsigned int*)(ws + 21*M1);        // overlaps Apack (dead)

    // zero atomic-accumulated outputs (xdbl + out)
    zero2_kernel<<<(NROWS*XDBL_W + NROWS*D_MODEL + 1023) / 1024, 256, 0, stream>>>(
        xdbl, NROWS * XDBL_W, out, NROWS * D_MODEL);

    ln_kernel<<<NROWS / 4, 256, 0, stream>>>(x, norm_w, norm_b, xn_dtT);

    // ---- in_proj: M=4096,N=2048,K=512; xi half 3-term, z half 1-term ----
    pack_hilo<<<(16 * 256) / 4, 256, 0, stream>>>(xn_dtT, Apack, 4096, 256, 512);
    pack_hilo<<<(16 * 128) / 4, 256, 0, stream>>>(in_proj_w, Bpack, 2048, 128, 512);
    gemm_mfma<128,128,2,2,false><<<dim3(16, 32), 256, 0, stream>>>(
        Apack, Bpack, 4096, 2048, 512, /*cols3=*/DINNER, xi_duT, zbuf, DINNER);

    // ---- fused conv+SiLU+pack: writes xibuf fp32 + Apack (x_proj A) ----
    conv_pack<<<(32 * 256) / 4, 256, 0, stream>>>(
        xi_duT, conv_w, conv_b, xibuf, Apack);

    // ---- x_proj: M=4096,N=160(pad 192),K=1024; 3-term via blockIdx.z + atomics ----
    pack_hilo<<<(32 * 16) / 4, 256, 0, stream>>>(x_proj_w, Bpack, 160, 16, 1024);
    gemm_mfma<128,64,2,2,true><<<dim3(3, 32, 3), 256, 0, stream>>>(
        Apack, Bpack, 4096, 256, 1024, 0, xdbl, nullptr, XDBL_W);

    // ---- dt/du (tiled, coalesced transposed writes) + bcT pack; then scan ----
    dtdu_kernel<<<64 * 16, 256, 0, stream>>>(xdbl, dt_proj_w, dt_proj_b,
        xibuf, xn_dtT, xi_duT);
    bct_kernel<<<64, 256, 0, stream>>>(xdbl, bcT);
    scan_kernel<<<(BSZ * DINNER) / 4, 256, 0, stream>>>(
        xn_dtT, xi_duT, bcT, A_log, ytbuf);

    // ---- fused gate+pack: Apack = out_proj A operand (bcT dead) ----
    gate_pack<<<(32 * 256) / 4, 256, 0, stream>>>(
        ytbuf, xibuf, zbuf, Dvec, Apack);

    // ---- out_proj: M=4096,N=512,K=1024; 3-term via blockIdx.z + atomics ----
    pack_hilo<<<(32 * 32) / 4, 256, 0, stream>>>(out_proj_w, Bpack, 512, 32, 1024);
    gemm_mfma<128,64,2,2,true><<<dim3(8, 32, 3), 256, 0, stream>>>(
        Apack, Bpack, 4096, 512, 1024, 0, out, nullptr, D_MODEL);
}

// Round 11
// 307.228 us; speedup vs baseline: 1.4829x; 1.1155x over previous
//
#include <hip/hip_runtime.h>

#define D_MODEL 512
#define DINNER  1024
#define DSTATE  64
#define DTRANK  32
#define BSZ     2
#define NLEN    2048
#define NROWS   (BSZ*NLEN)   // 4096
#define XDBL_W  (DTRANK + 2*DSTATE)  // 160

typedef __attribute__((ext_vector_type(8))) short  bf16x8;
typedef __attribute__((ext_vector_type(4))) float  f32x4;
typedef __attribute__((ext_vector_type(8))) unsigned short u16x8;

__device__ __forceinline__ unsigned int rne16(float f) {
    unsigned int u = __float_as_uint(f);
    return (u + 0x7fffu + ((u >> 16) & 1)) >> 16;
}
__device__ __forceinline__ float fsilu(float x) {
    return x / (1.f + __builtin_amdgcn_exp2f(-x * 1.44269504f));
}

// ---------------- zero-init for atomic-accumulated outputs ----------------
__global__ __launch_bounds__(256) void zero2_kernel(float* __restrict__ p0, int n0,
        float* __restrict__ p1, int n1) {
    const int i = (blockIdx.x * 256 + threadIdx.x) * 4;
    if (i < n0) *(float4*)(p0 + i) = make_float4(0.f, 0.f, 0.f, 0.f);
    const int j = i - n0;
    if (j >= 0 && j < n1) *(float4*)(p1 + j) = make_float4(0.f, 0.f, 0.f, 0.f);
}

// ---------------- LayerNorm: one wave per row ----------------
__global__ __launch_bounds__(256) void ln_kernel(const float* __restrict__ x,
        const float* __restrict__ w, const float* __restrict__ bvec,
        float* __restrict__ xn) {
    const int wid = threadIdx.x >> 6, lane = threadIdx.x & 63;
    const int row = (blockIdx.x << 2) + wid;
    const float4* xp = (const float4*)(x + (size_t)row * D_MODEL);
    float4 v0 = xp[lane], v1 = xp[lane + 64];
    float s = v0.x + v0.y + v0.z + v0.w + v1.x + v1.y + v1.z + v1.w;
    float q = v0.x*v0.x + v0.y*v0.y + v0.z*v0.z + v0.w*v0.w
            + v1.x*v1.x + v1.y*v1.y + v1.z*v1.z + v1.w*v1.w;
    #pragma unroll
    for (int m = 32; m; m >>= 1) { s += __shfl_xor(s, m); q += __shfl_xor(q, m); }
    const float mean = s * (1.f / D_MODEL);
    const float var  = q * (1.f / D_MODEL) - mean * mean;
    const float rstd = rsqrtf(var + 1e-5f);
    const float4* wp = (const float4*)w;
    const float4* bp = (const float4*)bvec;
    float4 w0 = wp[lane], w1 = wp[lane + 64], b0 = bp[lane], b1 = bp[lane + 64];
    float4 o0, o1;
    o0.x = (v0.x - mean) * rstd * w0.x + b0.x;
    o0.y = (v0.y - mean) * rstd * w0.y + b0.y;
    o0.z = (v0.z - mean) * rstd * w0.z + b0.z;
    o0.w = (v0.w - mean) * rstd * w0.w + b0.w;
    o1.x = (v1.x - mean) * rstd * w1.x + b1.x;
    o1.y = (v1.y - mean) * rstd * w1.y + b1.y;
    o1.z = (v1.z - mean) * rstd * w1.z + b1.z;
    o1.w = (v1.w - mean) * rstd * w1.w + b1.w;
    float4* op = (float4*)(xn + (size_t)row * D_MODEL);
    op[lane] = o0; op[lane + 64] = o1;
}

// ---- pack fp32 (R x K row-major) -> fragment-major split-bf16 [2*K/32][Rpad/16][64][8]
__global__ __launch_bounds__(256) void pack_hilo(const float* __restrict__ src,
        unsigned short* __restrict__ dst, int R, int RT /* Rpad/16 */, int K) {
    const int wid = threadIdx.x >> 6, lane = threadIdx.x & 63;
    const int gid = blockIdx.x * 4 + wid;          // in [0, (K/32)*RT)
    const int kt = gid / RT, rt = gid - kt * RT;
    const int row = (rt << 4) + (lane & 15);
    const int KTK = K >> 5;
    u16x8 hi = {}, lo = {};
    if (row < R) {
        const float* s = src + (size_t)row * K + kt * 32 + ((lane >> 4) << 3);
        float4 f0 = *(const float4*)s;
        float4 f1 = *(const float4*)(s + 4);
        float ff[8] = {f0.x,f0.y,f0.z,f0.w,f1.x,f1.y,f1.z,f1.w};
        #pragma unroll
        for (int j = 0; j < 8; ++j) {
            unsigned int hb = rne16(ff[j]);
            float rem = ff[j] - __uint_as_float(hb << 16);
            hi[j] = (unsigned short)hb;
            lo[j] = (unsigned short)rne16(rem);
        }
    }
    *(u16x8*)(dst + ((size_t)kt * RT + rt) * 512 + lane * 8) = hi;
    *(u16x8*)(dst + ((size_t)(kt + KTK) * RT + rt) * 512 + lane * 8) = lo;
}

// ---- MFMA GEMM on packed operands, BK=64 ----
// ATOMIC=false: per-column-block term count (3-term if n0<cols3 else 1-term).
// ATOMIC=true : term per blockIdx.z (0:hi*hi, 1:lo*hi, 2:hi*lo); z>0 blocks with
//               n0>=cols3 exit immediately (their columns need only 1 term).
template<int BM, int BN, int WR, int WC, bool ATOMIC>
__global__ __launch_bounds__(256) void gemm_mfma(
        const unsigned short* __restrict__ Ap, const unsigned short* __restrict__ Bp,
        int M, int N, int K, int cols3,
        float* __restrict__ out0, float* __restrict__ out1, int split) {
    constexpr int MI = BM / (WR * 16);
    constexpr int NI = BN / (WC * 16);
    constexpr int APASS = BM / 64;
    constexpr int BPASS = BN / 64;
    __shared__ __align__(16) unsigned short sA[2 * BM * 32];
    __shared__ __align__(16) unsigned short sB[2 * BN * 32];
    const int tid = threadIdx.x;
    const int wid = tid >> 6, lane = tid & 63;
    const int wr = wid / WC, wc = wid % WC;
    const int m0 = blockIdx.y * BM, n0 = blockIdx.x * BN;
    if (ATOMIC && blockIdx.z > 0 && n0 >= cols3) return;   // uniform block exit
    const int MT = M >> 4, NT = N >> 4;
    const int KTK = K >> 5;
    const int KTv = ATOMIC ? KTK : ((n0 < cols3) ? 3 * KTK : KTK);
    const int aoff = (ATOMIC && blockIdx.z == 1) ? KTK : 0;
    const int boff = (ATOMIC && blockIdx.z == 2) ? KTK : 0;
    f32x4 acc[MI][NI] = {};
    for (int kt2 = 0; kt2 < KTv; kt2 += 2) {
        __syncthreads();
        #pragma unroll
        for (int tt = 0; tt < 2; ++tt) {
            const int kt = kt2 + tt;
            int a_kt, b_kt;
            if (ATOMIC) { a_kt = kt + aoff; b_kt = kt + boff; }
            else { a_kt = (kt < 2 * KTK) ? kt : kt - 2 * KTK;   // hi, lo, hi
                   b_kt = (kt < KTK) ? kt : kt - KTK; }         // hi, hi, lo
            const char* gA = (const char*)(Ap + ((size_t)a_kt * MT + (m0 >> 4)) * 512);
            const char* gB = (const char*)(Bp + ((size_t)b_kt * NT + (n0 >> 4)) * 512);
            #pragma unroll
            for (int p = 0; p < APASS; ++p)
                __builtin_amdgcn_global_load_lds(
                    (const __attribute__((address_space(1))) void*)(gA + p * 4096 + tid * 16),
                    (__attribute__((address_space(3))) void*)((char*)sA + tt * BM * 64 + p * 4096 + tid * 16),
                    16, 0, 0);
            #pragma unroll
            for (int p = 0; p < BPASS; ++p)
                __builtin_amdgcn_global_load_lds(
                    (const __attribute__((address_space(1))) void*)(gB + p * 4096 + tid * 16),
                    (__attribute__((address_space(3))) void*)((char*)sB + tt * BN * 64 + p * 4096 + tid * 16),
                    16, 0, 0);
        }
        __syncthreads();
        #pragma unroll
        for (int tt = 0; tt < 2; ++tt) {
            bf16x8 af[MI], bfr[NI];
            #pragma unroll
            for (int mi = 0; mi < MI; ++mi)
                af[mi] = *(const bf16x8*)((const char*)sA + tt*BM*64 + (wr*MI + mi)*1024 + lane*16);
            #pragma unroll
            for (int ni = 0; ni < NI; ++ni)
                bfr[ni] = *(const bf16x8*)((const char*)sB + tt*BN*64 + (wc*NI + ni)*1024 + lane*16);
            #pragma unroll
            for (int mi = 0; mi < MI; ++mi)
                #pragma unroll
                for (int ni = 0; ni < NI; ++ni)
                    acc[mi][ni] = __builtin_amdgcn_mfma_f32_16x16x32_bf16(
                        af[mi], bfr[ni], acc[mi][ni], 0, 0, 0);
        }
    }
    #pragma unroll
    for (int mi = 0; mi < MI; ++mi) {
        #pragma unroll
        for (int ni = 0; ni < NI; ++ni) {
            const int col = n0 + (wc*NI + ni)*16 + (lane & 15);
            const int rb_ = m0 + (wr*MI + mi)*16 + ((lane >> 4) << 2);
            if (col < split) {
                #pragma unroll
                for (int r = 0; r < 4; ++r) {
                    if (ATOMIC) atomicAdd(&out0[(size_t)(rb_ + r) * split + col], acc[mi][ni][r]);
                    else        out0[(size_t)(rb_ + r) * split + col] = acc[mi][ni][r];
                }
            } else if (!ATOMIC && out1 != nullptr) {
                #pragma unroll
                for (int r = 0; r < 4; ++r)
                    out1[(size_t)(rb_ + r) * (N - split) + (col - split)] = acc[mi][ni][r];
            }
        }
    }
}

// ---- fused causal depthwise conv (k=4) + SiLU + x_proj A-pack ----
__global__ __launch_bounds__(256) void conv_pack(const float* __restrict__ xr,
        const float* __restrict__ cw, const float* __restrict__ cb,
        float* __restrict__ xi, unsigned short* __restrict__ Ap) {
    const int wid = threadIdx.x >> 6, lane = threadIdx.x & 63;
    const int gid = (blockIdx.x << 2) + wid;     // [0, 32*256)
    const int kt = gid >> 8, rt = gid & 255;
    const int row = (rt << 4) + (lane & 15);
    const int n = row & (NLEN - 1);
    const int d0 = (kt << 5) + ((lane >> 4) << 3);
    const float* base = xr + (size_t)row * DINNER + d0;
    const float4 z4 = make_float4(0.f, 0.f, 0.f, 0.f);
    float4 c0 = *(const float4*)base,          c1 = *(const float4*)(base + 4);
    float4 a0 = (n >= 1) ? *(const float4*)(base - DINNER)     : z4;
    float4 a1 = (n >= 1) ? *(const float4*)(base - DINNER + 4) : z4;
    float4 b0 = (n >= 2) ? *(const float4*)(base - 2*DINNER)     : z4;
    float4 b1 = (n >= 2) ? *(const float4*)(base - 2*DINNER + 4) : z4;
    float4 e0 = (n >= 3) ? *(const float4*)(base - 3*DINNER)     : z4;
    float4 e1 = (n >= 3) ? *(const float4*)(base - 3*DINNER + 4) : z4;
    float cur[8] = {c0.x,c0.y,c0.z,c0.w,c1.x,c1.y,c1.z,c1.w};
    float p1[8]  = {a0.x,a0.y,a0.z,a0.w,a1.x,a1.y,a1.z,a1.w};
    float p2[8]  = {b0.x,b0.y,b0.z,b0.w,b1.x,b1.y,b1.z,b1.w};
    float p3[8]  = {e0.x,e0.y,e0.z,e0.w,e1.x,e1.y,e1.z,e1.w};
    float o[8];
    u16x8 hi, lo;
    #pragma unroll
    for (int j = 0; j < 8; ++j) {
        const float4 wv = *(const float4*)(cw + (d0 + j) * 4);
        float a = cb[d0 + j];
        a = fmaf(wv.w, cur[j], a);
        a = fmaf(wv.z, p1[j], a);
        a = fmaf(wv.y, p2[j], a);
        a = fmaf(wv.x, p3[j], a);
        o[j] = fsilu(a);
        unsigned int hb = rne16(o[j]);
        hi[j] = (unsigned short)hb;
        lo[j] = (unsigned short)rne16(o[j] - __uint_as_float(hb << 16));
    }
    float* xo = xi + (size_t)row * DINNER + d0;
    *(float4*)xo = make_float4(o[0], o[1], o[2], o[3]);
    *(float4*)(xo + 4) = make_float4(o[4], o[5], o[6], o[7]);
    *(u16x8*)(Ap + ((size_t)kt * 256 + rt) * 512 + lane * 8) = hi;
    *(u16x8*)(Ap + ((size_t)(kt + 32) * 256 + rt) * 512 + lane * 8) = lo;
}

// ---- dt/du: tiled GEMV + softplus + LDS transpose, coalesced [b][d][n] writes ----
__global__ __launch_bounds__(256) void dtdu_kernel(const float* __restrict__ xdbl,
        const float* __restrict__ W, const float* __restrict__ bias,
        const float* __restrict__ u, float* __restrict__ dtT,
        float* __restrict__ duT) {
    __shared__ float sdtr[64][33];
    __shared__ float sW[64][33];
    __shared__ float tt[64][65];
    const int nb = blockIdx.x & 63, db = blockIdx.x >> 6;
    const int row0 = nb << 6, d0 = db << 6;
    const int i = threadIdx.x >> 2, kq = (threadIdx.x & 3) << 3;
    {
        const float* s = xdbl + (size_t)(row0 + i) * XDBL_W + kq;
        *(float4*)&sdtr[i][kq]     = *(const float4*)s;
        *(float4*)&sdtr[i][kq + 4] = *(const float4*)(s + 4);
        const float* wsrc = W + (size_t)(d0 + i) * DTRANK + kq;
        *(float4*)&sW[i][kq]     = *(const float4*)wsrc;
        *(float4*)&sW[i][kq + 4] = *(const float4*)(wsrc + 4);
    }
    __syncthreads();
    const int i4 = (threadIdx.x >> 4) << 2;   // n sub-row
    const int j4 = (threadIdx.x & 15) << 2;   // d sub-col
    float dtv[4][4], duv[4][4];
    {
        float acc[4][4] = {};
        #pragma unroll
        for (int k = 0; k < DTRANK; ++k) {
            float a[4]  = {sdtr[i4][k], sdtr[i4+1][k], sdtr[i4+2][k], sdtr[i4+3][k]};
            float bb[4] = {sW[j4][k], sW[j4+1][k], sW[j4+2][k], sW[j4+3][k]};
            #pragma unroll
            for (int ii = 0; ii < 4; ++ii)
                #pragma unroll
                for (int jj = 0; jj < 4; ++jj)
                    acc[ii][jj] = fmaf(a[ii], bb[jj], acc[ii][jj]);
        }
        float4 bv = *(const float4*)(bias + d0 + j4);
        float bb4[4] = {bv.x, bv.y, bv.z, bv.w};
        #pragma unroll
        for (int ii = 0; ii < 4; ++ii) {
            float4 uv = *(const float4*)(u + (size_t)(row0 + i4 + ii) * DINNER + d0 + j4);
            float uu[4] = {uv.x, uv.y, uv.z, uv.w};
            #pragma unroll
            for (int jj = 0; jj < 4; ++jj) {
                float z = acc[ii][jj] + bb4[jj];
                float dt = (z > 20.f) ? z : log1pf(expf(z));
                dtv[ii][jj] = dt;
                duv[ii][jj] = dt * uu[jj];
            }
        }
    }
    const int b = row0 >> 11;
    const int n0 = row0 & (NLEN - 1);
    const int jt = threadIdx.x >> 2, iq = (threadIdx.x & 3) << 4;
    float* dstD = dtT + ((size_t)(b * DINNER + d0 + jt)) * NLEN + n0 + iq;
    float* dstU = duT + ((size_t)(b * DINNER + d0 + jt)) * NLEN + n0 + iq;
    // dt pass
    #pragma unroll
    for (int ii = 0; ii < 4; ++ii)
        #pragma unroll
        for (int jj = 0; jj < 4; ++jj)
            tt[i4 + ii][j4 + jj] = dtv[ii][jj];
    __syncthreads();
    #pragma unroll
    for (int r = 0; r < 4; ++r) {
        float4 o = make_float4(tt[iq+4*r+0][jt], tt[iq+4*r+1][jt],
                               tt[iq+4*r+2][jt], tt[iq+4*r+3][jt]);
        *(float4*)(dstD + 4*r) = o;
    }
    __syncthreads();
    // du pass
    #pragma unroll
    for (int ii = 0; ii < 4; ++ii)
        #pragma unroll
        for (int jj = 0; jj < 4; ++jj)
            tt[i4 + ii][j4 + jj] = duv[ii][jj];
    __syncthreads();
    #pragma unroll
    for (int r = 0; r < 4; ++r) {
        float4 o = make_float4(tt[iq+4*r+0][jt], tt[iq+4*r+1][jt],
                               tt[iq+4*r+2][jt], tt[iq+4*r+3][jt]);
        *(float4*)(dstU + 4*r) = o;
    }
}

// ---- pack B,C (from xdbl) into one u32 row-major: bc[row*64+s] = B | C<<16 ----
__global__ __launch_bounds__(256) void bc_pack(const float* __restrict__ xdbl,
        unsigned int* __restrict__ bc) {
    const int g = blockIdx.x * 256 + threadIdx.x;   // row*64+s
    const int s = g & 63, row = g >> 6;
    const float Bv = xdbl[(size_t)row * XDBL_W + DTRANK + s];
    const float Cv = xdbl[(size_t)row * XDBL_W + DTRANK + DSTATE + s];
    bc[g] = rne16(Bv) | (rne16(Cv) << 16);
}

// ---------------- selective scan (round-8 structure: the measured best) ----------------
// Wave = (b,d); lane = s. Per-step: coalesced bc dword load (lane=s contiguous),
// dt/du via per-64-gather + readlane broadcast; h-FMA the only serial chain; y
// via per-wave LDS-transpose reduce. Two bc sub-bases keep offsets in 13-bit imm.
__global__ __launch_bounds__(256) void scan_kernel(const float* __restrict__ dtT,
        const float* __restrict__ duT, const unsigned int* __restrict__ bc,
        const float* __restrict__ A_log, float* __restrict__ yt) {
    __shared__ float p[4][32][65];
    const int wid = threadIdx.x >> 6;
    const int w = (blockIdx.x << 2) + wid;   // b*1024+d
    const int lane = threadIdx.x & 63;
    const int b = w >> 10, d = w & (DINNER - 1);
    const float* dtp = dtT + (size_t)w * NLEN;
    const float* dup = duT + (size_t)w * NLEN;
    const unsigned int* bcp = bc + (size_t)b * NLEN * 64 + lane;
    float* yp = yt + (size_t)w * NLEN;
    const float kA = -__builtin_amdgcn_exp2f(A_log[d * DSTATE + lane] * 1.44269504f)
                     * 1.44269504f;   // A*log2(e)
    float (*pw)[65] = p[wid];
    const int rn = lane & 31, rs = (lane >> 5) << 5;
    float h = 0.f;
    for (int n0 = 0; n0 < NLEN; n0 += 64) {
        const float dtv = dtp[n0 + lane];   // coalesced
        const float dtu = dup[n0 + lane];   // coalesced
        #pragma unroll
        for (int half = 0; half < 2; ++half) {
            const unsigned int* bn  = bcp + (size_t)(n0 + 32 * half) * 64;
            const unsigned int* bn2 = bn + 16 * 64;
            #pragma unroll
            for (int j = 0; j < 32; ++j) {
                const unsigned int q = (j < 16) ? bn[(size_t)j * 64]
                                                : bn2[(size_t)(j - 16) * 64];
                const float Bv = __uint_as_float(q << 16);
                const float Cv = __uint_as_float(q & 0xffff0000u);
                const float sdt = __int_as_float(
                    __builtin_amdgcn_readlane(__float_as_int(dtv), 32 * half + j));
                const float sdu = __int_as_float(
                    __builtin_amdgcn_readlane(__float_as_int(dtu), 32 * half + j));
                h = fmaf(__builtin_amdgcn_exp2f(kA * sdt), h, sdu * Bv);
                pw[j][lane] = h * Cv;
            }
            float y0 = 0.f, y1 = 0.f, y2 = 0.f, y3 = 0.f;
            #pragma unroll
            for (int i = 0; i < 32; i += 4) {
                y0 += pw[rn][rs + i];
                y1 += pw[rn][rs + i + 1];
                y2 += pw[rn][rs + i + 2];
                y3 += pw[rn][rs + i + 3];
            }
            float y = (y0 + y1) + (y2 + y3);
            y += __shfl_xor(y, 32);
            if (lane < 32) yp[n0 + (half << 5) + rn] = y;
        }
    }
}

// ---- fused gate + out_proj A-pack: yg=(yt^T + xi*D)*silu(z) -> packed hi/lo ----
__global__ __launch_bounds__(256) void gate_pack(const float* __restrict__ yt,
        const float* __restrict__ xi, const float* __restrict__ z,
        const float* __restrict__ Dv, unsigned short* __restrict__ Ap) {
    const int wid = threadIdx.x >> 6, lane = threadIdx.x & 63;
    const int gid = (blockIdx.x << 2) + wid;     // [0, 32*256)
    const int kt = gid >> 8, rt = gid & 255;
    const int row = (rt << 4) + (lane & 15);
    const int n = row & (NLEN - 1), b = row >> 11;
    const int d0 = (kt << 5) + ((lane >> 4) << 3);
    const float* ytp = yt + ((size_t)(b * DINNER + d0)) * NLEN + n;
    const float* xp = xi + (size_t)row * DINNER + d0;
    const float* zp = z  + (size_t)row * DINNER + d0;
    float4 x0 = *(const float4*)xp, x1 = *(const float4*)(xp + 4);
    float4 z0 = *(const float4*)zp, z1 = *(const float4*)(zp + 4);
    float4 D0 = *(const float4*)(Dv + d0), D1 = *(const float4*)(Dv + d0 + 4);
    float xv[8] = {x0.x,x0.y,x0.z,x0.w,x1.x,x1.y,x1.z,x1.w};
    float zv[8] = {z0.x,z0.y,z0.z,z0.w,z1.x,z1.y,z1.z,z1.w};
    float dv[8] = {D0.x,D0.y,D0.z,D0.w,D1.x,D1.y,D1.z,D1.w};
    u16x8 hi, lo;
    #pragma unroll
    for (int j = 0; j < 8; ++j) {
        const float yv = ytp[(size_t)j * NLEN];
        const float g = fmaf(xv[j], dv[j], yv) * fsilu(zv[j]);
        unsigned int hb = rne16(g);
        hi[j] = (unsigned short)hb;
        lo[j] = (unsigned short)rne16(g - __uint_as_float(hb << 16));
    }
    *(u16x8*)(Ap + ((size_t)kt * 256 + rt) * 512 + lane * 8) = hi;
    *(u16x8*)(Ap + ((size_t)(kt + 32) * 256 + rt) * 512 + lane * 8) = lo;
}

extern "C" void kernel_launch(void* const* d_in, const int* in_sizes, int n_in,
                              void* d_out, int out_size, void* d_ws, size_t ws_size,
                              hipStream_t stream) {
    const float* x         = (const float*)d_in[0];
    const float* norm_w    = (const float*)d_in[1];
    const float* norm_b    = (const float*)d_in[2];
    const float* in_proj_w = (const float*)d_in[3];
    const float* conv_w    = (const float*)d_in[4];
    const float* conv_b    = (const float*)d_in[5];
    const float* x_proj_w  = (const float*)d_in[6];
    const float* dt_proj_w = (const float*)d_in[7];
    const float* dt_proj_b = (const float*)d_in[8];
    const float* A_log     = (const float*)d_in[9];
    const float* Dvec      = (const float*)d_in[10];
    const float* out_proj_w= (const float*)d_in[11];
    float* out = (float*)d_out;
    float* ws  = (float*)d_ws;

    const size_t M1 = (size_t)1024 * 1024;
    float* xn_dtT = ws;                 // xn (2M f) then dtT (4M f)
    float* xi_duT = ws + 4*M1;          // xiraw (dead after conv_pack) -> duT
    float* zbuf   = ws + 8*M1;
    float* xibuf  = ws + 12*M1;
    float* xdbl   = ws + 16*M1;         // 0.66M f (atomic-accumulated)
    float* ytbuf  = ws + 17*M1;         // 4M f
    unsigned short* Apack = (unsigned short*)(ws + 21*M1);  // fragment region
    unsigned short* Bpack = (unsigned short*)(ws + 26*M1);
    unsigned int* bcbuf = (unsigned int*)(ws + 21*M1);      // overlaps Apack (dead)

    // zero atomic-accumulated outputs (xdbl + out)
    zero2_kernel<<<(NROWS*XDBL_W + NROWS*D_MODEL + 1023) / 1024, 256, 0, stream>>>(
        xdbl, NROWS * XDBL_W, out, NROWS * D_MODEL);

    ln_kernel<<<NROWS / 4, 256, 0, stream>>>(x, norm_w, norm_b, xn_dtT);

    // ---- in_proj: M=4096,N=2048,K=512; xi half 3-term, z half 1-term ----
    pack_hilo<<<(16 * 256) / 4, 256, 0, stream>>>(xn_dtT, Apack, 4096, 256, 512);
    pack_hilo<<<(16 * 128) / 4, 256, 0, stream>>>(in_proj_w, Bpack, 2048, 128, 512);
    gemm_mfma<128,128,2,2,false><<<dim3(16, 32), 256, 0, stream>>>(
        Apack, Bpack, 4096, 2048, 512, /*cols3=*/DINNER, xi_duT, zbuf, DINNER);

    // ---- fused conv+SiLU+pack: writes xibuf fp32 + Apack (x_proj A) ----
    conv_pack<<<(32 * 256) / 4, 256, 0, stream>>>(
        xi_duT, conv_w, conv_b, xibuf, Apack);

    // ---- x_proj: M=4096,K=1024; dt cols (block 0) 3-term, B/C cols 1-term ----
    pack_hilo<<<(32 * 16) / 4, 256, 0, stream>>>(x_proj_w, Bpack, 160, 16, 1024);
    gemm_mfma<128,64,2,2,true><<<dim3(3, 32, 3), 256, 0, stream>>>(
        Apack, Bpack, 4096, 256, 1024, /*cols3=*/64, xdbl, nullptr, XDBL_W);

    // ---- dt/du transposes + row-major bc pack; then scan (round-8 structure) ----
    dtdu_kernel<<<64 * 16, 256, 0, stream>>>(xdbl, dt_proj_w, dt_proj_b,
        xibuf, xn_dtT, xi_duT);
    bc_pack<<<(NROWS * 64) / 256, 256, 0, stream>>>(xdbl, bcbuf);
    scan_kernel<<<(BSZ * DINNER) / 4, 256, 0, stream>>>(
        xn_dtT, xi_duT, bcbuf, A_log, ytbuf);

    // ---- fused gate+pack: Apack = out_proj A operand (bc dead) ----
    gate_pack<<<(32 * 256) / 4, 256, 0, stream>>>(
        ytbuf, xibuf, zbuf, Dvec, Apack);

    // ---- out_proj: M=4096,N=512,K=1024; 2-term (hi*hi + lo*hi) ----
    pack_hilo<<<(32 * 32) / 4, 256, 0, stream>>>(out_proj_w, Bpack, 512, 32, 1024);
    gemm_mfma<128,64,2,2,true><<<dim3(8, 32, 2), 256, 0, stream>>>(
        Apack, Bpack, 4096, 512, 1024, /*cols3=*/512, out, nullptr, D_MODEL);
}

// Round 12
// 297.907 us; speedup vs baseline: 1.5293x; 1.0313x over previous
//
#include <hip/hip_runtime.h>

#define D_MODEL 512
#define DINNER  1024
#define DSTATE  64
#define DTRANK  32
#define BSZ     2
#define NLEN    2048
#define NROWS   (BSZ*NLEN)   // 4096
#define XDBL_W  (DTRANK + 2*DSTATE)  // 160

typedef __attribute__((ext_vector_type(8))) short  bf16x8;
typedef __attribute__((ext_vector_type(4))) float  f32x4;
typedef __attribute__((ext_vector_type(8))) unsigned short u16x8;

__device__ __forceinline__ unsigned int rne16(float f) {
    unsigned int u = __float_as_uint(f);
    return (u + 0x7fffu + ((u >> 16) & 1)) >> 16;
}
__device__ __forceinline__ float fsilu(float x) {
    return x / (1.f + __builtin_amdgcn_exp2f(-x * 1.44269504f));
}

// ---------------- zero-init (xdbl only; x_proj accumulates atomically) ----------------
__global__ __launch_bounds__(256) void zero2_kernel(float* __restrict__ p0, int n0,
        float* __restrict__ p1, int n1) {
    const int i = (blockIdx.x * 256 + threadIdx.x) * 4;
    if (i < n0) *(float4*)(p0 + i) = make_float4(0.f, 0.f, 0.f, 0.f);
    const int j = i - n0;
    if (j >= 0 && j < n1) *(float4*)(p1 + j) = make_float4(0.f, 0.f, 0.f, 0.f);
}

// ---- fused LayerNorm + in_proj A-pack ----
// Block = 4 waves = 16 rows (one rt stripe). Each wave normalizes 4 rows into
// LDS [16][516]; barrier; each wave packs 4 ktiles of hi/lo fragments.
__global__ __launch_bounds__(256) void ln_pack(const float* __restrict__ x,
        const float* __restrict__ w, const float* __restrict__ bvec,
        unsigned short* __restrict__ Ap) {
    __shared__ float xs[16][516];
    const int wid = threadIdx.x >> 6, lane = threadIdx.x & 63;
    const int rt = blockIdx.x;               // 0..255
    const float4* wp = (const float4*)w;
    const float4* bp = (const float4*)bvec;
    const float4 w0 = wp[lane], w1 = wp[lane + 64];
    const float4 b0 = bp[lane], b1 = bp[lane + 64];
    #pragma unroll
    for (int pq = 0; pq < 4; ++pq) {
        const int r = (wid << 2) + pq;       // 0..15
        const int row = (rt << 4) + r;
        const float4* xp = (const float4*)(x + (size_t)row * D_MODEL);
        float4 v0 = xp[lane], v1 = xp[lane + 64];
        float s = v0.x + v0.y + v0.z + v0.w + v1.x + v1.y + v1.z + v1.w;
        float q = v0.x*v0.x + v0.y*v0.y + v0.z*v0.z + v0.w*v0.w
                + v1.x*v1.x + v1.y*v1.y + v1.z*v1.z + v1.w*v1.w;
        #pragma unroll
        for (int m = 32; m; m >>= 1) { s += __shfl_xor(s, m); q += __shfl_xor(q, m); }
        const float mean = s * (1.f / D_MODEL);
        const float var  = q * (1.f / D_MODEL) - mean * mean;
        const float rstd = rsqrtf(var + 1e-5f);
        float4 o0, o1;
        o0.x = (v0.x - mean) * rstd * w0.x + b0.x;
        o0.y = (v0.y - mean) * rstd * w0.y + b0.y;
        o0.z = (v0.z - mean) * rstd * w0.z + b0.z;
        o0.w = (v0.w - mean) * rstd * w0.w + b0.w;
        o1.x = (v1.x - mean) * rstd * w1.x + b1.x;
        o1.y = (v1.y - mean) * rstd * w1.y + b1.y;
        o1.z = (v1.z - mean) * rstd * w1.z + b1.z;
        o1.w = (v1.w - mean) * rstd * w1.w + b1.w;
        *(float4*)&xs[r][lane << 2] = o0;
        *(float4*)&xs[r][256 + (lane << 2)] = o1;
    }
    __syncthreads();
    const int r = lane & 15;
    const int cq = (lane >> 4) << 3;
    #pragma unroll
    for (int q = 0; q < 4; ++q) {
        const int kt = (wid << 2) + q;       // 0..15 (KTK=16 for K=512)
        const int c0 = (kt << 5) + cq;
        float4 f0 = *(const float4*)&xs[r][c0];
        float4 f1 = *(const float4*)&xs[r][c0 + 4];
        float ff[8] = {f0.x,f0.y,f0.z,f0.w,f1.x,f1.y,f1.z,f1.w};
        u16x8 hi, lo;
        #pragma unroll
        for (int j = 0; j < 8; ++j) {
            unsigned int hb = rne16(ff[j]);
            hi[j] = (unsigned short)hb;
            lo[j] = (unsigned short)rne16(ff[j] - __uint_as_float(hb << 16));
        }
        *(u16x8*)(Ap + ((size_t)kt * 256 + rt) * 512 + lane * 8) = hi;
        *(u16x8*)(Ap + ((size_t)(kt + 16) * 256 + rt) * 512 + lane * 8) = lo;
    }
}

// ---- pack fp32 (R x K row-major) -> fragment-major split-bf16 [2*K/32][Rpad/16][64][8]
__global__ __launch_bounds__(256) void pack_hilo(const float* __restrict__ src,
        unsigned short* __restrict__ dst, int R, int RT /* Rpad/16 */, int K) {
    const int wid = threadIdx.x >> 6, lane = threadIdx.x & 63;
    const int gid = blockIdx.x * 4 + wid;          // in [0, (K/32)*RT)
    const int kt = gid / RT, rt = gid - kt * RT;
    const int row = (rt << 4) + (lane & 15);
    const int KTK = K >> 5;
    u16x8 hi = {}, lo = {};
    if (row < R) {
        const float* s = src + (size_t)row * K + kt * 32 + ((lane >> 4) << 3);
        float4 f0 = *(const float4*)s;
        float4 f1 = *(const float4*)(s + 4);
        float ff[8] = {f0.x,f0.y,f0.z,f0.w,f1.x,f1.y,f1.z,f1.w};
        #pragma unroll
        for (int j = 0; j < 8; ++j) {
            unsigned int hb = rne16(ff[j]);
            float rem = ff[j] - __uint_as_float(hb << 16);
            hi[j] = (unsigned short)hb;
            lo[j] = (unsigned short)rne16(rem);
        }
    }
    *(u16x8*)(dst + ((size_t)kt * RT + rt) * 512 + lane * 8) = hi;
    *(u16x8*)(dst + ((size_t)(kt + KTK) * RT + rt) * 512 + lane * 8) = lo;
}

// ---- MFMA GEMM on packed operands, BK=64 ----
// ATOMIC=false: column blocks with n0<cols3 run `terms` passes (1..3: hi*hi,
//               lo*hi, hi*lo via virtual-kt mapping), others 1; direct stores.
// ATOMIC=true : term per blockIdx.z; z>0 blocks with n0>=cols3 exit; atomicAdd.
template<int BM, int BN, int WR, int WC, bool ATOMIC>
__global__ __launch_bounds__(256) void gemm_mfma(
        const unsigned short* __restrict__ Ap, const unsigned short* __restrict__ Bp,
        int M, int N, int K, int cols3, int terms,
        float* __restrict__ out0, float* __restrict__ out1, int split) {
    constexpr int MI = BM / (WR * 16);
    constexpr int NI = BN / (WC * 16);
    constexpr int APASS = BM / 64;
    constexpr int BPASS = BN / 64;
    __shared__ __align__(16) unsigned short sA[2 * BM * 32];
    __shared__ __align__(16) unsigned short sB[2 * BN * 32];
    const int tid = threadIdx.x;
    const int wid = tid >> 6, lane = tid & 63;
    const int wr = wid / WC, wc = wid % WC;
    const int m0 = blockIdx.y * BM, n0 = blockIdx.x * BN;
    if (ATOMIC && blockIdx.z > 0 && n0 >= cols3) return;   // uniform block exit
    const int MT = M >> 4, NT = N >> 4;
    const int KTK = K >> 5;
    const int KTv = ATOMIC ? KTK : ((n0 < cols3) ? terms * KTK : KTK);
    const int aoff = (ATOMIC && blockIdx.z == 1) ? KTK : 0;
    const int boff = (ATOMIC && blockIdx.z == 2) ? KTK : 0;
    f32x4 acc[MI][NI] = {};
    for (int kt2 = 0; kt2 < KTv; kt2 += 2) {
        __syncthreads();
        #pragma unroll
        for (int tt = 0; tt < 2; ++tt) {
            const int kt = kt2 + tt;
            int a_kt, b_kt;
            if (ATOMIC) { a_kt = kt + aoff; b_kt = kt + boff; }
            else { a_kt = (kt < 2 * KTK) ? kt : kt - 2 * KTK;   // hi, lo, hi
                   b_kt = (kt < KTK) ? kt : kt - KTK; }         // hi, hi, lo
            const char* gA = (const char*)(Ap + ((size_t)a_kt * MT + (m0 >> 4)) * 512);
            const char* gB = (const char*)(Bp + ((size_t)b_kt * NT + (n0 >> 4)) * 512);
            #pragma unroll
            for (int p = 0; p < APASS; ++p)
                __builtin_amdgcn_global_load_lds(
                    (const __attribute__((address_space(1))) void*)(gA + p * 4096 + tid * 16),
                    (__attribute__((address_space(3))) void*)((char*)sA + tt * BM * 64 + p * 4096 + tid * 16),
                    16, 0, 0);
            #pragma unroll
            for (int p = 0; p < BPASS; ++p)
                __builtin_amdgcn_global_load_lds(
                    (const __attribute__((address_space(1))) void*)(gB + p * 4096 + tid * 16),
                    (__attribute__((address_space(3))) void*)((char*)sB + tt * BN * 64 + p * 4096 + tid * 16),
                    16, 0, 0);
        }
        __syncthreads();
        #pragma unroll
        for (int tt = 0; tt < 2; ++tt) {
            bf16x8 af[MI], bfr[NI];
            #pragma unroll
            for (int mi = 0; mi < MI; ++mi)
                af[mi] = *(const bf16x8*)((const char*)sA + tt*BM*64 + (wr*MI + mi)*1024 + lane*16);
            #pragma unroll
            for (int ni = 0; ni < NI; ++ni)
                bfr[ni] = *(const bf16x8*)((const char*)sB + tt*BN*64 + (wc*NI + ni)*1024 + lane*16);
            #pragma unroll
            for (int mi = 0; mi < MI; ++mi)
                #pragma unroll
                for (int ni = 0; ni < NI; ++ni)
                    acc[mi][ni] = __builtin_amdgcn_mfma_f32_16x16x32_bf16(
                        af[mi], bfr[ni], acc[mi][ni], 0, 0, 0);
        }
    }
    #pragma unroll
    for (int mi = 0; mi < MI; ++mi) {
        #pragma unroll
        for (int ni = 0; ni < NI; ++ni) {
            const int col = n0 + (wc*NI + ni)*16 + (lane & 15);
            const int rb_ = m0 + (wr*MI + mi)*16 + ((lane >> 4) << 2);
            if (col < split) {
                #pragma unroll
                for (int r = 0; r < 4; ++r) {
                    if (ATOMIC) atomicAdd(&out0[(size_t)(rb_ + r) * split + col], acc[mi][ni][r]);
                    else        out0[(size_t)(rb_ + r) * split + col] = acc[mi][ni][r];
                }
            } else if (!ATOMIC && out1 != nullptr) {
                #pragma unroll
                for (int r = 0; r < 4; ++r)
                    out1[(size_t)(rb_ + r) * (N - split) + (col - split)] = acc[mi][ni][r];
            }
        }
    }
}

// ---- fused causal depthwise conv (k=4) + SiLU + x_proj A-pack ----
__global__ __launch_bounds__(256) void conv_pack(const float* __restrict__ xr,
        const float* __restrict__ cw, const float* __restrict__ cb,
        float* __restrict__ xi, unsigned short* __restrict__ Ap) {
    const int wid = threadIdx.x >> 6, lane = threadIdx.x & 63;
    const int gid = (blockIdx.x << 2) + wid;     // [0, 32*256)
    const int kt = gid >> 8, rt = gid & 255;
    const int row = (rt << 4) + (lane & 15);
    const int n = row & (NLEN - 1);
    const int d0 = (kt << 5) + ((lane >> 4) << 3);
    const float* base = xr + (size_t)row * DINNER + d0;
    const float4 z4 = make_float4(0.f, 0.f, 0.f, 0.f);
    float4 c0 = *(const float4*)base,          c1 = *(const float4*)(base + 4);
    float4 a0 = (n >= 1) ? *(const float4*)(base - DINNER)     : z4;
    float4 a1 = (n >= 1) ? *(const float4*)(base - DINNER + 4) : z4;
    float4 b0 = (n >= 2) ? *(const float4*)(base - 2*DINNER)     : z4;
    float4 b1 = (n >= 2) ? *(const float4*)(base - 2*DINNER + 4) : z4;
    float4 e0 = (n >= 3) ? *(const float4*)(base - 3*DINNER)     : z4;
    float4 e1 = (n >= 3) ? *(const float4*)(base - 3*DINNER + 4) : z4;
    float cur[8] = {c0.x,c0.y,c0.z,c0.w,c1.x,c1.y,c1.z,c1.w};
    float p1[8]  = {a0.x,a0.y,a0.z,a0.w,a1.x,a1.y,a1.z,a1.w};
    float p2[8]  = {b0.x,b0.y,b0.z,b0.w,b1.x,b1.y,b1.z,b1.w};
    float p3[8]  = {e0.x,e0.y,e0.z,e0.w,e1.x,e1.y,e1.z,e1.w};
    float o[8];
    u16x8 hi, lo;
    #pragma unroll
    for (int j = 0; j < 8; ++j) {
        const float4 wv = *(const float4*)(cw + (d0 + j) * 4);
        float a = cb[d0 + j];
        a = fmaf(wv.w, cur[j], a);
        a = fmaf(wv.z, p1[j], a);
        a = fmaf(wv.y, p2[j], a);
        a = fmaf(wv.x, p3[j], a);
        o[j] = fsilu(a);
        unsigned int hb = rne16(o[j]);
        hi[j] = (unsigned short)hb;
        lo[j] = (unsigned short)rne16(o[j] - __uint_as_float(hb << 16));
    }
    float* xo = xi + (size_t)row * DINNER + d0;
    *(float4*)xo = make_float4(o[0], o[1], o[2], o[3]);
    *(float4*)(xo + 4) = make_float4(o[4], o[5], o[6], o[7]);
    *(u16x8*)(Ap + ((size_t)kt * 256 + rt) * 512 + lane * 8) = hi;
    *(u16x8*)(Ap + ((size_t)(kt + 32) * 256 + rt) * 512 + lane * 8) = lo;
}

// ---- dt/du: tiled GEMV + softplus + LDS transpose, coalesced [b][d][n] writes ----
__global__ __launch_bounds__(256) void dtdu_kernel(const float* __restrict__ xdbl,
        const float* __restrict__ W, const float* __restrict__ bias,
        const float* __restrict__ u, float* __restrict__ dtT,
        float* __restrict__ duT) {
    __shared__ float sdtr[64][33];
    __shared__ float sW[64][33];
    __shared__ float tt[64][65];
    const int nb = blockIdx.x & 63, db = blockIdx.x >> 6;
    const int row0 = nb << 6, d0 = db << 6;
    const int i = threadIdx.x >> 2, kq = (threadIdx.x & 3) << 3;
    {
        const float* s = xdbl + (size_t)(row0 + i) * XDBL_W + kq;
        *(float4*)&sdtr[i][kq]     = *(const float4*)s;
        *(float4*)&sdtr[i][kq + 4] = *(const float4*)(s + 4);
        const float* wsrc = W + (size_t)(d0 + i) * DTRANK + kq;
        *(float4*)&sW[i][kq]     = *(const float4*)wsrc;
        *(float4*)&sW[i][kq + 4] = *(const float4*)(wsrc + 4);
    }
    __syncthreads();
    const int i4 = (threadIdx.x >> 4) << 2;   // n sub-row
    const int j4 = (threadIdx.x & 15) << 2;   // d sub-col
    float dtv[4][4], duv[4][4];
    {
        float acc[4][4] = {};
        #pragma unroll
        for (int k = 0; k < DTRANK; ++k) {
            float a[4]  = {sdtr[i4][k], sdtr[i4+1][k], sdtr[i4+2][k], sdtr[i4+3][k]};
            float bb[4] = {sW[j4][k], sW[j4+1][k], sW[j4+2][k], sW[j4+3][k]};
            #pragma unroll
            for (int ii = 0; ii < 4; ++ii)
                #pragma unroll
                for (int jj = 0; jj < 4; ++jj)
                    acc[ii][jj] = fmaf(a[ii], bb[jj], acc[ii][jj]);
        }
        float4 bv = *(const float4*)(bias + d0 + j4);
        float bb4[4] = {bv.x, bv.y, bv.z, bv.w};
        #pragma unroll
        for (int ii = 0; ii < 4; ++ii) {
            float4 uv = *(const float4*)(u + (size_t)(row0 + i4 + ii) * DINNER + d0 + j4);
            float uu[4] = {uv.x, uv.y, uv.z, uv.w};
            #pragma unroll
            for (int jj = 0; jj < 4; ++jj) {
                float z = acc[ii][jj] + bb4[jj];
                float dt = (z > 20.f) ? z : log1pf(expf(z));
                dtv[ii][jj] = dt;
                duv[ii][jj] = dt * uu[jj];
            }
        }
    }
    const int b = row0 >> 11;
    const int n0 = row0 & (NLEN - 1);
    const int jt = threadIdx.x >> 2, iq = (threadIdx.x & 3) << 4;
    float* dstD = dtT + ((size_t)(b * DINNER + d0 + jt)) * NLEN + n0 + iq;
    float* dstU = duT + ((size_t)(b * DINNER + d0 + jt)) * NLEN + n0 + iq;
    #pragma unroll
    for (int ii = 0; ii < 4; ++ii)
        #pragma unroll
        for (int jj = 0; jj < 4; ++jj)
            tt[i4 + ii][j4 + jj] = dtv[ii][jj];
    __syncthreads();
    #pragma unroll
    for (int r = 0; r < 4; ++r) {
        float4 o = make_float4(tt[iq+4*r+0][jt], tt[iq+4*r+1][jt],
                               tt[iq+4*r+2][jt], tt[iq+4*r+3][jt]);
        *(float4*)(dstD + 4*r) = o;
    }
    __syncthreads();
    #pragma unroll
    for (int ii = 0; ii < 4; ++ii)
        #pragma unroll
        for (int jj = 0; jj < 4; ++jj)
            tt[i4 + ii][j4 + jj] = duv[ii][jj];
    __syncthreads();
    #pragma unroll
    for (int r = 0; r < 4; ++r) {
        float4 o = make_float4(tt[iq+4*r+0][jt], tt[iq+4*r+1][jt],
                               tt[iq+4*r+2][jt], tt[iq+4*r+3][jt]);
        *(float4*)(dstU + 4*r) = o;
    }
}

// ---- pack B,C (from xdbl) into one u32 row-major: bc[row*64+s] = B | C<<16 ----
__global__ __launch_bounds__(256) void bc_pack(const float* __restrict__ xdbl,
        unsigned int* __restrict__ bc) {
    const int g = blockIdx.x * 256 + threadIdx.x;   // row*64+s
    const int s = g & 63, row = g >> 6;
    const float Bv = xdbl[(size_t)row * XDBL_W + DTRANK + s];
    const float Cv = xdbl[(size_t)row * XDBL_W + DTRANK + DSTATE + s];
    bc[g] = rne16(Bv) | (rne16(Cv) << 16);
}

// ---------------- selective scan (round-8 structure: the measured best) ----------------
__global__ __launch_bounds__(256) void scan_kernel(const float* __restrict__ dtT,
        const float* __restrict__ duT, const unsigned int* __restrict__ bc,
        const float* __restrict__ A_log, float* __restrict__ yt) {
    __shared__ float p[4][32][65];
    const int wid = threadIdx.x >> 6;
    const int w = (blockIdx.x << 2) + wid;   // b*1024+d
    const int lane = threadIdx.x & 63;
    const int b = w >> 10, d = w & (DINNER - 1);
    const float* dtp = dtT + (size_t)w * NLEN;
    const float* dup = duT + (size_t)w * NLEN;
    const unsigned int* bcp = bc + (size_t)b * NLEN * 64 + lane;
    float* yp = yt + (size_t)w * NLEN;
    const float kA = -__builtin_amdgcn_exp2f(A_log[d * DSTATE + lane] * 1.44269504f)
                     * 1.44269504f;   // A*log2(e)
    float (*pw)[65] = p[wid];
    const int rn = lane & 31, rs = (lane >> 5) << 5;
    float h = 0.f;
    for (int n0 = 0; n0 < NLEN; n0 += 64) {
        const float dtv = dtp[n0 + lane];   // coalesced
        const float dtu = dup[n0 + lane];   // coalesced
        #pragma unroll
        for (int half = 0; half < 2; ++half) {
            const unsigned int* bn  = bcp + (size_t)(n0 + 32 * half) * 64;
            const unsigned int* bn2 = bn + 16 * 64;
            #pragma unroll
            for (int j = 0; j < 32; ++j) {
                const unsigned int q = (j < 16) ? bn[(size_t)j * 64]
                                                : bn2[(size_t)(j - 16) * 64];
                const float Bv = __uint_as_float(q << 16);
                const float Cv = __uint_as_float(q & 0xffff0000u);
                const float sdt = __int_as_float(
                    __builtin_amdgcn_readlane(__float_as_int(dtv), 32 * half + j));
                const float sdu = __int_as_float(
                    __builtin_amdgcn_readlane(__float_as_int(dtu), 32 * half + j));
                h = fmaf(__builtin_amdgcn_exp2f(kA * sdt), h, sdu * Bv);
                pw[j][lane] = h * Cv;
            }
            float y0 = 0.f, y1 = 0.f, y2 = 0.f, y3 = 0.f;
            #pragma unroll
            for (int i = 0; i < 32; i += 4) {
                y0 += pw[rn][rs + i];
                y1 += pw[rn][rs + i + 1];
                y2 += pw[rn][rs + i + 2];
                y3 += pw[rn][rs + i + 3];
            }
            float y = (y0 + y1) + (y2 + y3);
            y += __shfl_xor(y, 32);
            if (lane < 32) yp[n0 + (half << 5) + rn] = y;
        }
    }
}

// ---- fused gate + out_proj A-pack ----
__global__ __launch_bounds__(256) void gate_pack(const float* __restrict__ yt,
        const float* __restrict__ xi, const float* __restrict__ z,
        const float* __restrict__ Dv, unsigned short* __restrict__ Ap) {
    const int wid = threadIdx.x >> 6, lane = threadIdx.x & 63;
    const int gid = (blockIdx.x << 2) + wid;     // [0, 32*256)
    const int kt = gid >> 8, rt = gid & 255;
    const int row = (rt << 4) + (lane & 15);
    const int n = row & (NLEN - 1), b = row >> 11;
    const int d0 = (kt << 5) + ((lane >> 4) << 3);
    const float* ytp = yt + ((size_t)(b * DINNER + d0)) * NLEN + n;
    const float* xp = xi + (size_t)row * DINNER + d0;
    const float* zp = z  + (size_t)row * DINNER + d0;
    float4 x0 = *(const float4*)xp, x1 = *(const float4*)(xp + 4);
    float4 z0 = *(const float4*)zp, z1 = *(const float4*)(zp + 4);
    float4 D0 = *(const float4*)(Dv + d0), D1 = *(const float4*)(Dv + d0 + 4);
    float xv[8] = {x0.x,x0.y,x0.z,x0.w,x1.x,x1.y,x1.z,x1.w};
    float zv[8] = {z0.x,z0.y,z0.z,z0.w,z1.x,z1.y,z1.z,z1.w};
    float dv[8] = {D0.x,D0.y,D0.z,D0.w,D1.x,D1.y,D1.z,D1.w};
    u16x8 hi, lo;
    #pragma unroll
    for (int j = 0; j < 8; ++j) {
        const float yv = ytp[(size_t)j * NLEN];
        const float g = fmaf(xv[j], dv[j], yv) * fsilu(zv[j]);
        unsigned int hb = rne16(g);
        hi[j] = (unsigned short)hb;
        lo[j] = (unsigned short)rne16(g - __uint_as_float(hb << 16));
    }
    *(u16x8*)(Ap + ((size_t)kt * 256 + rt) * 512 + lane * 8) = hi;
    *(u16x8*)(Ap + ((size_t)(kt + 32) * 256 + rt) * 512 + lane * 8) = lo;
}

extern "C" void kernel_launch(void* const* d_in, const int* in_sizes, int n_in,
                              void* d_out, int out_size, void* d_ws, size_t ws_size,
                              hipStream_t stream) {
    const float* x         = (const float*)d_in[0];
    const float* norm_w    = (const float*)d_in[1];
    const float* norm_b    = (const float*)d_in[2];
    const float* in_proj_w = (const float*)d_in[3];
    const float* conv_w    = (const float*)d_in[4];
    const float* conv_b    = (const float*)d_in[5];
    const float* x_proj_w  = (const float*)d_in[6];
    const float* dt_proj_w = (const float*)d_in[7];
    const float* dt_proj_b = (const float*)d_in[8];
    const float* A_log     = (const float*)d_in[9];
    const float* Dvec      = (const float*)d_in[10];
    const float* out_proj_w= (const float*)d_in[11];
    float* out = (float*)d_out;
    float* ws  = (float*)d_ws;

    const size_t M1 = (size_t)1024 * 1024;
    float* dtT    = ws;                 // dtT (4M f)
    float* xi_duT = ws + 4*M1;          // xiraw (dead after conv_pack) -> duT
    float* zbuf   = ws + 8*M1;
    float* xibuf  = ws + 12*M1;
    float* xdbl   = ws + 16*M1;         // 0.66M f (atomic-accumulated)
    float* ytbuf  = ws + 17*M1;         // 4M f
    unsigned short* Apack = (unsigned short*)(ws + 21*M1);  // fragment region
    unsigned short* Bpack = (unsigned short*)(ws + 26*M1);
    unsigned int* bcbuf = (unsigned int*)(ws + 21*M1);      // overlaps Apack (dead)

    // zero atomic-accumulated xdbl
    zero2_kernel<<<(NROWS*XDBL_W) / 1024, 256, 0, stream>>>(
        xdbl, NROWS * XDBL_W, out, 0);

    // ---- fused LN + in_proj A-pack ----
    ln_pack<<<256, 256, 0, stream>>>(x, norm_w, norm_b, Apack);

    // ---- in_proj: M=4096,N=2048,K=512; xi half 3-term, z half 1-term ----
    pack_hilo<<<(16 * 128) / 4, 256, 0, stream>>>(in_proj_w, Bpack, 2048, 128, 512);
    gemm_mfma<128,128,2,2,false><<<dim3(16, 32), 256, 0, stream>>>(
        Apack, Bpack, 4096, 2048, 512, /*cols3=*/DINNER, /*terms=*/3,
        xi_duT, zbuf, DINNER);

    // ---- fused conv+SiLU+pack: writes xibuf fp32 + Apack (x_proj A) ----
    conv_pack<<<(32 * 256) / 4, 256, 0, stream>>>(
        xi_duT, conv_w, conv_b, xibuf, Apack);

    // ---- x_proj: M=4096,K=1024; dt cols 3-term (atomic z-split), B/C cols 1-term ----
    pack_hilo<<<(32 * 16) / 4, 256, 0, stream>>>(x_proj_w, Bpack, 160, 16, 1024);
    gemm_mfma<128,64,2,2,true><<<dim3(3, 32, 3), 256, 0, stream>>>(
        Apack, Bpack, 4096, 256, 1024, /*cols3=*/64, /*terms=*/0,
        xdbl, nullptr, XDBL_W);

    // ---- dt/du transposes + row-major bc pack; then scan ----
    dtdu_kernel<<<64 * 16, 256, 0, stream>>>(xdbl, dt_proj_w, dt_proj_b,
        xibuf, dtT, xi_duT);
    bc_pack<<<(NROWS * 64) / 256, 256, 0, stream>>>(xdbl, bcbuf);
    scan_kernel<<<(BSZ * DINNER) / 4, 256, 0, stream>>>(
        dtT, xi_duT, bcbuf, A_log, ytbuf);

    // ---- fused gate+pack: Apack = out_proj A operand (bc dead) ----
    gate_pack<<<(32 * 256) / 4, 256, 0, stream>>>(
        ytbuf, xibuf, zbuf, Dvec, Apack);

    // ---- out_proj: M=4096,N=512,K=1024; 2-term single dispatch, no atomics ----
    pack_hilo<<<(32 * 32) / 4, 256, 0, stream>>>(out_proj_w, Bpack, 512, 32, 1024);
    gemm_mfma<64,64,2,2,false><<<dim3(8, 64), 256, 0, stream>>>(
        Apack, Bpack, 4096, 512, 1024, /*cols3=*/512, /*terms=*/2,
        out, nullptr, D_MODEL);
}

// Round 13
// 272.411 us; speedup vs baseline: 1.6725x; 1.0936x over previous
//
#include <hip/hip_runtime.h>

#define D_MODEL 512
#define DINNER  1024
#define DSTATE  64
#define DTRANK  32
#define BSZ     2
#define NLEN    2048
#define NROWS   (BSZ*NLEN)   // 4096
#define XDBL_W  (DTRANK + 2*DSTATE)  // 160

typedef __attribute__((ext_vector_type(8))) short  bf16x8;
typedef __attribute__((ext_vector_type(4))) float  f32x4;
typedef __attribute__((ext_vector_type(8))) unsigned short u16x8;

__device__ __forceinline__ unsigned int rne16(float f) {
    unsigned int u = __float_as_uint(f);
    return (u + 0x7fffu + ((u >> 16) & 1)) >> 16;
}
__device__ __forceinline__ float fsilu(float x) {
    return x / (1.f + __builtin_amdgcn_exp2f(-x * 1.44269504f));
}

// ---- device helper: pack fp32 (RxK row-major) -> fragment-major split-bf16 ----
__device__ __forceinline__ void pack_frag(const float* __restrict__ src,
        unsigned short* __restrict__ dst, int R, int RT, int K,
        int gid, int lane) {
    const int kt = gid / RT, rt = gid - kt * RT;
    const int row = (rt << 4) + (lane & 15);
    const int KTK = K >> 5;
    u16x8 hi = {}, lo = {};
    if (row < R) {
        const float* s = src + (size_t)row * K + kt * 32 + ((lane >> 4) << 3);
        float4 f0 = *(const float4*)s;
        float4 f1 = *(const float4*)(s + 4);
        float ff[8] = {f0.x,f0.y,f0.z,f0.w,f1.x,f1.y,f1.z,f1.w};
        #pragma unroll
        for (int j = 0; j < 8; ++j) {
            unsigned int hb = rne16(ff[j]);
            hi[j] = (unsigned short)hb;
            lo[j] = (unsigned short)rne16(ff[j] - __uint_as_float(hb << 16));
        }
    }
    *(u16x8*)(dst + ((size_t)kt * RT + rt) * 512 + lane * 8) = hi;
    *(u16x8*)(dst + ((size_t)(kt + KTK) * RT + rt) * 512 + lane * 8) = lo;
}

// ---- prologue: LN+in_proj-A-pack | 3 weight packs | xdbl zero, by block range ----
__global__ __launch_bounds__(256) void prologue(const float* __restrict__ x,
        const float* __restrict__ nw, const float* __restrict__ nb,
        const float* __restrict__ in_w, const float* __restrict__ x_w,
        const float* __restrict__ out_w, unsigned short* __restrict__ Ap,
        unsigned short* __restrict__ BpIn, unsigned short* __restrict__ BpX,
        unsigned short* __restrict__ BpOut, float* __restrict__ xdbl) {
    __shared__ float xs[16][516];
    const int bid = blockIdx.x;
    const int wid = threadIdx.x >> 6, lane = threadIdx.x & 63;
    if (bid < 256) {
        // --- fused LayerNorm + in_proj A-pack (rt = bid) ---
        const int rt = bid;
        const float4* wp = (const float4*)nw;
        const float4* bp = (const float4*)nb;
        const float4 w0 = wp[lane], w1 = wp[lane + 64];
        const float4 b0 = bp[lane], b1 = bp[lane + 64];
        #pragma unroll
        for (int pq = 0; pq < 4; ++pq) {
            const int r = (wid << 2) + pq;
            const int row = (rt << 4) + r;
            const float4* xp = (const float4*)(x + (size_t)row * D_MODEL);
            float4 v0 = xp[lane], v1 = xp[lane + 64];
            float s = v0.x + v0.y + v0.z + v0.w + v1.x + v1.y + v1.z + v1.w;
            float q = v0.x*v0.x + v0.y*v0.y + v0.z*v0.z + v0.w*v0.w
                    + v1.x*v1.x + v1.y*v1.y + v1.z*v1.z + v1.w*v1.w;
            #pragma unroll
            for (int m = 32; m; m >>= 1) { s += __shfl_xor(s, m); q += __shfl_xor(q, m); }
            const float mean = s * (1.f / D_MODEL);
            const float var  = q * (1.f / D_MODEL) - mean * mean;
            const float rstd = rsqrtf(var + 1e-5f);
            float4 o0, o1;
            o0.x = (v0.x - mean) * rstd * w0.x + b0.x;
            o0.y = (v0.y - mean) * rstd * w0.y + b0.y;
            o0.z = (v0.z - mean) * rstd * w0.z + b0.z;
            o0.w = (v0.w - mean) * rstd * w0.w + b0.w;
            o1.x = (v1.x - mean) * rstd * w1.x + b1.x;
            o1.y = (v1.y - mean) * rstd * w1.y + b1.y;
            o1.z = (v1.z - mean) * rstd * w1.z + b1.z;
            o1.w = (v1.w - mean) * rstd * w1.w + b1.w;
            *(float4*)&xs[r][lane << 2] = o0;
            *(float4*)&xs[r][256 + (lane << 2)] = o1;
        }
        __syncthreads();
        const int r = lane & 15;
        const int cq = (lane >> 4) << 3;
        #pragma unroll
        for (int q = 0; q < 4; ++q) {
            const int kt = (wid << 2) + q;       // KTK=16 for K=512
            const int c0 = (kt << 5) + cq;
            float4 f0 = *(const float4*)&xs[r][c0];
            float4 f1 = *(const float4*)&xs[r][c0 + 4];
            float ff[8] = {f0.x,f0.y,f0.z,f0.w,f1.x,f1.y,f1.z,f1.w};
            u16x8 hi, lo;
            #pragma unroll
            for (int j = 0; j < 8; ++j) {
                unsigned int hb = rne16(ff[j]);
                hi[j] = (unsigned short)hb;
                lo[j] = (unsigned short)rne16(ff[j] - __uint_as_float(hb << 16));
            }
            *(u16x8*)(Ap + ((size_t)kt * 256 + rt) * 512 + lane * 8) = hi;
            *(u16x8*)(Ap + ((size_t)(kt + 16) * 256 + rt) * 512 + lane * 8) = lo;
        }
    } else if (bid < 768) {
        pack_frag(in_w, BpIn, 2048, 128, 512, (bid - 256) * 4 + wid, lane);
    } else if (bid < 896) {
        pack_frag(x_w, BpX, 160, 16, 1024, (bid - 768) * 4 + wid, lane);
    } else if (bid < 1152) {
        pack_frag(out_w, BpOut, 512, 32, 1024, (bid - 896) * 4 + wid, lane);
    } else {
        // zero xdbl: 160 blocks x 4096 floats
        float* p = xdbl + (size_t)(bid - 1152) * 4096 + threadIdx.x * 4;
        const float4 z4 = make_float4(0.f, 0.f, 0.f, 0.f);
        *(float4*)p = z4; *(float4*)(p + 1024) = z4;
        *(float4*)(p + 2048) = z4; *(float4*)(p + 3072) = z4;
    }
}

// ---- MFMA GEMM on packed operands, BK=64 ----
// ATOMIC=false: column blocks with n0<cols3 run `terms` passes (hi*hi, lo*hi,
//               hi*lo via virtual-kt mapping), others 1; direct stores.
// ATOMIC=true : term per blockIdx.z; z>0 blocks with n0>=cols3 exit; atomicAdd.
template<int BM, int BN, int WR, int WC, bool ATOMIC>
__global__ __launch_bounds__(256) void gemm_mfma(
        const unsigned short* __restrict__ Ap, const unsigned short* __restrict__ Bp,
        int M, int N, int K, int cols3, int terms,
        float* __restrict__ out0, float* __restrict__ out1, int split) {
    constexpr int MI = BM / (WR * 16);
    constexpr int NI = BN / (WC * 16);
    constexpr int APASS = BM / 64;
    constexpr int BPASS = BN / 64;
    __shared__ __align__(16) unsigned short sA[2 * BM * 32];
    __shared__ __align__(16) unsigned short sB[2 * BN * 32];
    const int tid = threadIdx.x;
    const int wid = tid >> 6, lane = tid & 63;
    const int wr = wid / WC, wc = wid % WC;
    const int m0 = blockIdx.y * BM, n0 = blockIdx.x * BN;
    if (ATOMIC && blockIdx.z > 0 && n0 >= cols3) return;
    const int MT = M >> 4, NT = N >> 4;
    const int KTK = K >> 5;
    const int KTv = ATOMIC ? KTK : ((n0 < cols3) ? terms * KTK : KTK);
    const int aoff = (ATOMIC && blockIdx.z == 1) ? KTK : 0;
    const int boff = (ATOMIC && blockIdx.z == 2) ? KTK : 0;
    f32x4 acc[MI][NI] = {};
    for (int kt2 = 0; kt2 < KTv; kt2 += 2) {
        __syncthreads();
        #pragma unroll
        for (int tt = 0; tt < 2; ++tt) {
            const int kt = kt2 + tt;
            int a_kt, b_kt;
            if (ATOMIC) { a_kt = kt + aoff; b_kt = kt + boff; }
            else { a_kt = (kt < 2 * KTK) ? kt : kt - 2 * KTK;   // hi, lo, hi
                   b_kt = (kt < KTK) ? kt : kt - KTK; }         // hi, hi, lo
            const char* gA = (const char*)(Ap + ((size_t)a_kt * MT + (m0 >> 4)) * 512);
            const char* gB = (const char*)(Bp + ((size_t)b_kt * NT + (n0 >> 4)) * 512);
            #pragma unroll
            for (int p = 0; p < APASS; ++p)
                __builtin_amdgcn_global_load_lds(
                    (const __attribute__((address_space(1))) void*)(gA + p * 4096 + tid * 16),
                    (__attribute__((address_space(3))) void*)((char*)sA + tt * BM * 64 + p * 4096 + tid * 16),
                    16, 0, 0);
            #pragma unroll
            for (int p = 0; p < BPASS; ++p)
                __builtin_amdgcn_global_load_lds(
                    (const __attribute__((address_space(1))) void*)(gB + p * 4096 + tid * 16),
                    (__attribute__((address_space(3))) void*)((char*)sB + tt * BN * 64 + p * 4096 + tid * 16),
                    16, 0, 0);
        }
        __syncthreads();
        #pragma unroll
        for (int tt = 0; tt < 2; ++tt) {
            bf16x8 af[MI], bfr[NI];
            #pragma unroll
            for (int mi = 0; mi < MI; ++mi)
                af[mi] = *(const bf16x8*)((const char*)sA + tt*BM*64 + (wr*MI + mi)*1024 + lane*16);
            #pragma unroll
            for (int ni = 0; ni < NI; ++ni)
                bfr[ni] = *(const bf16x8*)((const char*)sB + tt*BN*64 + (wc*NI + ni)*1024 + lane*16);
            #pragma unroll
            for (int mi = 0; mi < MI; ++mi)
                #pragma unroll
                for (int ni = 0; ni < NI; ++ni)
                    acc[mi][ni] = __builtin_amdgcn_mfma_f32_16x16x32_bf16(
                        af[mi], bfr[ni], acc[mi][ni], 0, 0, 0);
        }
    }
    #pragma unroll
    for (int mi = 0; mi < MI; ++mi) {
        #pragma unroll
        for (int ni = 0; ni < NI; ++ni) {
            const int col = n0 + (wc*NI + ni)*16 + (lane & 15);
            const int rb_ = m0 + (wr*MI + mi)*16 + ((lane >> 4) << 2);
            if (col < split) {
                #pragma unroll
                for (int r = 0; r < 4; ++r) {
                    if (ATOMIC) atomicAdd(&out0[(size_t)(rb_ + r) * split + col], acc[mi][ni][r]);
                    else        out0[(size_t)(rb_ + r) * split + col] = acc[mi][ni][r];
                }
            } else if (!ATOMIC && out1 != nullptr) {
                #pragma unroll
                for (int r = 0; r < 4; ++r)
                    out1[(size_t)(rb_ + r) * (N - split) + (col - split)] = acc[mi][ni][r];
            }
        }
    }
}

// ---- fused causal depthwise conv (k=4) + SiLU + x_proj A-pack ----
__global__ __launch_bounds__(256) void conv_pack(const float* __restrict__ xr,
        const float* __restrict__ cw, const float* __restrict__ cb,
        float* __restrict__ xi, unsigned short* __restrict__ Ap) {
    const int wid = threadIdx.x >> 6, lane = threadIdx.x & 63;
    const int gid = (blockIdx.x << 2) + wid;     // [0, 32*256)
    const int kt = gid >> 8, rt = gid & 255;
    const int row = (rt << 4) + (lane & 15);
    const int n = row & (NLEN - 1);
    const int d0 = (kt << 5) + ((lane >> 4) << 3);
    const float* base = xr + (size_t)row * DINNER + d0;
    const float4 z4 = make_float4(0.f, 0.f, 0.f, 0.f);
    float4 c0 = *(const float4*)base,          c1 = *(const float4*)(base + 4);
    float4 a0 = (n >= 1) ? *(const float4*)(base - DINNER)     : z4;
    float4 a1 = (n >= 1) ? *(const float4*)(base - DINNER + 4) : z4;
    float4 b0 = (n >= 2) ? *(const float4*)(base - 2*DINNER)     : z4;
    float4 b1 = (n >= 2) ? *(const float4*)(base - 2*DINNER + 4) : z4;
    float4 e0 = (n >= 3) ? *(const float4*)(base - 3*DINNER)     : z4;
    float4 e1 = (n >= 3) ? *(const float4*)(base - 3*DINNER + 4) : z4;
    float cur[8] = {c0.x,c0.y,c0.z,c0.w,c1.x,c1.y,c1.z,c1.w};
    float p1[8]  = {a0.x,a0.y,a0.z,a0.w,a1.x,a1.y,a1.z,a1.w};
    float p2[8]  = {b0.x,b0.y,b0.z,b0.w,b1.x,b1.y,b1.z,b1.w};
    float p3[8]  = {e0.x,e0.y,e0.z,e0.w,e1.x,e1.y,e1.z,e1.w};
    float o[8];
    u16x8 hi, lo;
    #pragma unroll
    for (int j = 0; j < 8; ++j) {
        const float4 wv = *(const float4*)(cw + (d0 + j) * 4);
        float a = cb[d0 + j];
        a = fmaf(wv.w, cur[j], a);
        a = fmaf(wv.z, p1[j], a);
        a = fmaf(wv.y, p2[j], a);
        a = fmaf(wv.x, p3[j], a);
        o[j] = fsilu(a);
        unsigned int hb = rne16(o[j]);
        hi[j] = (unsigned short)hb;
        lo[j] = (unsigned short)rne16(o[j] - __uint_as_float(hb << 16));
    }
    float* xo = xi + (size_t)row * DINNER + d0;
    *(float4*)xo = make_float4(o[0], o[1], o[2], o[3]);
    *(float4*)(xo + 4) = make_float4(o[4], o[5], o[6], o[7]);
    *(u16x8*)(Ap + ((size_t)kt * 256 + rt) * 512 + lane * 8) = hi;
    *(u16x8*)(Ap + ((size_t)(kt + 32) * 256 + rt) * 512 + lane * 8) = lo;
}

// ---- dt/du tiled GEMV+softplus+transpose (blocks [0,1024)) + bc pack ([1024,1088)) ----
__global__ __launch_bounds__(256) void dtdu_kernel(const float* __restrict__ xdbl,
        const float* __restrict__ W, const float* __restrict__ bias,
        const float* __restrict__ u, float* __restrict__ dtT,
        float* __restrict__ duT, unsigned int* __restrict__ bc) {
    if (blockIdx.x >= 1024) {
        // bc pack: bc[row*64+s] = bf16(B) | bf16(C)<<16
        const int row0 = (blockIdx.x - 1024) << 6;
        #pragma unroll
        for (int k = 0; k < 16; ++k) {
            const int g = threadIdx.x * 16 + k;      // 0..4095
            const int lr = g >> 6, s = g & 63;
            const float* src = xdbl + (size_t)(row0 + lr) * XDBL_W + DTRANK + s;
            bc[(size_t)(row0 + lr) * 64 + s] = rne16(src[0]) | (rne16(src[DSTATE]) << 16);
        }
        return;
    }
    __shared__ float sdtr[64][33];
    __shared__ float sW[64][33];
    __shared__ float tt[64][65];
    const int nb = blockIdx.x & 63, db = blockIdx.x >> 6;
    const int row0 = nb << 6, d0 = db << 6;
    const int i = threadIdx.x >> 2, kq = (threadIdx.x & 3) << 3;
    {
        const float* s = xdbl + (size_t)(row0 + i) * XDBL_W + kq;
        *(float4*)&sdtr[i][kq]     = *(const float4*)s;
        *(float4*)&sdtr[i][kq + 4] = *(const float4*)(s + 4);
        const float* wsrc = W + (size_t)(d0 + i) * DTRANK + kq;
        *(float4*)&sW[i][kq]     = *(const float4*)wsrc;
        *(float4*)&sW[i][kq + 4] = *(const float4*)(wsrc + 4);
    }
    __syncthreads();
    const int i4 = (threadIdx.x >> 4) << 2;
    const int j4 = (threadIdx.x & 15) << 2;
    float dtv[4][4], duv[4][4];
    {
        float acc[4][4] = {};
        #pragma unroll
        for (int k = 0; k < DTRANK; ++k) {
            float a[4]  = {sdtr[i4][k], sdtr[i4+1][k], sdtr[i4+2][k], sdtr[i4+3][k]};
            float bb[4] = {sW[j4][k], sW[j4+1][k], sW[j4+2][k], sW[j4+3][k]};
            #pragma unroll
            for (int ii = 0; ii < 4; ++ii)
                #pragma unroll
                for (int jj = 0; jj < 4; ++jj)
                    acc[ii][jj] = fmaf(a[ii], bb[jj], acc[ii][jj]);
        }
        float4 bv = *(const float4*)(bias + d0 + j4);
        float bb4[4] = {bv.x, bv.y, bv.z, bv.w};
        #pragma unroll
        for (int ii = 0; ii < 4; ++ii) {
            float4 uv = *(const float4*)(u + (size_t)(row0 + i4 + ii) * DINNER + d0 + j4);
            float uu[4] = {uv.x, uv.y, uv.z, uv.w};
            #pragma unroll
            for (int jj = 0; jj < 4; ++jj) {
                float z = acc[ii][jj] + bb4[jj];
                float dt = (z > 20.f) ? z : log1pf(expf(z));
                dtv[ii][jj] = dt;
                duv[ii][jj] = dt * uu[jj];
            }
        }
    }
    const int b = row0 >> 11;
    const int n0 = row0 & (NLEN - 1);
    const int jt = threadIdx.x >> 2, iq = (threadIdx.x & 3) << 4;
    float* dstD = dtT + ((size_t)(b * DINNER + d0 + jt)) * NLEN + n0 + iq;
    float* dstU = duT + ((size_t)(b * DINNER + d0 + jt)) * NLEN + n0 + iq;
    #pragma unroll
    for (int ii = 0; ii < 4; ++ii)
        #pragma unroll
        for (int jj = 0; jj < 4; ++jj)
            tt[i4 + ii][j4 + jj] = dtv[ii][jj];
    __syncthreads();
    #pragma unroll
    for (int r = 0; r < 4; ++r) {
        float4 o = make_float4(tt[iq+4*r+0][jt], tt[iq+4*r+1][jt],
                               tt[iq+4*r+2][jt], tt[iq+4*r+3][jt]);
        *(float4*)(dstD + 4*r) = o;
    }
    __syncthreads();
    #pragma unroll
    for (int ii = 0; ii < 4; ++ii)
        #pragma unroll
        for (int jj = 0; jj < 4; ++jj)
            tt[i4 + ii][j4 + jj] = duv[ii][jj];
    __syncthreads();
    #pragma unroll
    for (int r = 0; r < 4; ++r) {
        float4 o = make_float4(tt[iq+4*r+0][jt], tt[iq+4*r+1][jt],
                               tt[iq+4*r+2][jt], tt[iq+4*r+3][jt]);
        *(float4*)(dstU + 4*r) = o;
    }
}

// ---------------- selective scan: LDS-broadcast dt/du, reg-prefetched gathers ----------------
// Per-step: 1 coalesced bc dword (VMEM, imm offset), 1 uniform ds_read_b64 of
// (dt,du) (broadcast, no readlane SGPR hazard), exp2+fma+mul, pw write.
// Next 64-block's dt/du gathers prefetched into regs during current block.
__global__ __launch_bounds__(256) void scan_kernel(const float* __restrict__ dtT,
        const float* __restrict__ duT, const unsigned int* __restrict__ bc,
        const float* __restrict__ A_log, float* __restrict__ yt) {
    __shared__ float p[4][32][65];
    __shared__ float2 dd[4][64];
    const int wid = threadIdx.x >> 6;
    const int w = (blockIdx.x << 2) + wid;   // b*1024+d
    const int lane = threadIdx.x & 63;
    const int b = w >> 10, d = w & (DINNER - 1);
    const float* dtp = dtT + (size_t)w * NLEN;
    const float* dup = duT + (size_t)w * NLEN;
    const unsigned int* bcp = bc + (size_t)b * NLEN * 64 + lane;
    float* yp = yt + (size_t)w * NLEN;
    const float kA = -__builtin_amdgcn_exp2f(A_log[d * DSTATE + lane] * 1.44269504f)
                     * 1.44269504f;   // A*log2(e)
    float (*pw)[65] = p[wid];
    float2* ddw = dd[wid];
    const int rn = lane & 31, rs = (lane >> 5) << 5;
    float h = 0.f;
    float gdt = dtp[lane], gdu = dup[lane];
    for (int n0 = 0; n0 < NLEN; n0 += 64) {
        ddw[lane] = make_float2(gdt, gdu);      // wave-private; lgkmcnt-ordered
        if (n0 + 64 < NLEN) { gdt = dtp[n0 + 64 + lane]; gdu = dup[n0 + 64 + lane]; }
        #pragma unroll
        for (int half = 0; half < 2; ++half) {
            const unsigned int* bn  = bcp + (size_t)(n0 + 32 * half) * 64;
            const unsigned int* bn2 = bn + 16 * 64;
            #pragma unroll
            for (int j = 0; j < 32; ++j) {
                const int st = (half << 5) + j;
                const unsigned int q = (j < 16) ? bn[(size_t)j * 64]
                                                : bn2[(size_t)(j - 16) * 64];
                const float2 v = ddw[st];        // uniform ds_read_b64 broadcast
                const float Bv = __uint_as_float(q << 16);
                const float Cv = __uint_as_float(q & 0xffff0000u);
                h = fmaf(__builtin_amdgcn_exp2f(kA * v.x), h, v.y * Bv);
                pw[j][lane] = h * Cv;
            }
            float y0 = 0.f, y1 = 0.f, y2 = 0.f, y3 = 0.f;
            #pragma unroll
            for (int i = 0; i < 32; i += 4) {
                y0 += pw[rn][rs + i];
                y1 += pw[rn][rs + i + 1];
                y2 += pw[rn][rs + i + 2];
                y3 += pw[rn][rs + i + 3];
            }
            float y = (y0 + y1) + (y2 + y3);
            y += __shfl_xor(y, 32);
            if (lane < 32) yp[n0 + (half << 5) + rn] = y;
        }
    }
}

// ---- fused gate + out_proj A-pack ----
__global__ __launch_bounds__(256) void gate_pack(const float* __restrict__ yt,
        const float* __restrict__ xi, const float* __restrict__ z,
        const float* __restrict__ Dv, unsigned short* __restrict__ Ap) {
    const int wid = threadIdx.x >> 6, lane = threadIdx.x & 63;
    const int gid = (blockIdx.x << 2) + wid;     // [0, 32*256)
    const int kt = gid >> 8, rt = gid & 255;
    const int row = (rt << 4) + (lane & 15);
    const int n = row & (NLEN - 1), b = row >> 11;
    const int d0 = (kt << 5) + ((lane >> 4) << 3);
    const float* ytp = yt + ((size_t)(b * DINNER + d0)) * NLEN + n;
    const float* xp = xi + (size_t)row * DINNER + d0;
    const float* zp = z  + (size_t)row * DINNER + d0;
    float4 x0 = *(const float4*)xp, x1 = *(const float4*)(xp + 4);
    float4 z0 = *(const float4*)zp, z1 = *(const float4*)(zp + 4);
    float4 D0 = *(const float4*)(Dv + d0), D1 = *(const float4*)(Dv + d0 + 4);
    float xv[8] = {x0.x,x0.y,x0.z,x0.w,x1.x,x1.y,x1.z,x1.w};
    float zv[8] = {z0.x,z0.y,z0.z,z0.w,z1.x,z1.y,z1.z,z1.w};
    float dv[8] = {D0.x,D0.y,D0.z,D0.w,D1.x,D1.y,D1.z,D1.w};
    u16x8 hi, lo;
    #pragma unroll
    for (int j = 0; j < 8; ++j) {
        const float yv = ytp[(size_t)j * NLEN];
        const float g = fmaf(xv[j], dv[j], yv) * fsilu(zv[j]);
        unsigned int hb = rne16(g);
        hi[j] = (unsigned short)hb;
        lo[j] = (unsigned short)rne16(g - __uint_as_float(hb << 16));
    }
    *(u16x8*)(Ap + ((size_t)kt * 256 + rt) * 512 + lane * 8) = hi;
    *(u16x8*)(Ap + ((size_t)(kt + 32) * 256 + rt) * 512 + lane * 8) = lo;
}

extern "C" void kernel_launch(void* const* d_in, const int* in_sizes, int n_in,
                              void* d_out, int out_size, void* d_ws, size_t ws_size,
                              hipStream_t stream) {
    const float* x         = (const float*)d_in[0];
    const float* norm_w    = (const float*)d_in[1];
    const float* norm_b    = (const float*)d_in[2];
    const float* in_proj_w = (const float*)d_in[3];
    const float* conv_w    = (const float*)d_in[4];
    const float* conv_b    = (const float*)d_in[5];
    const float* x_proj_w  = (const float*)d_in[6];
    const float* dt_proj_w = (const float*)d_in[7];
    const float* dt_proj_b = (const float*)d_in[8];
    const float* A_log     = (const float*)d_in[9];
    const float* Dvec      = (const float*)d_in[10];
    const float* out_proj_w= (const float*)d_in[11];
    float* out = (float*)d_out;
    float* ws  = (float*)d_ws;

    const size_t M1 = (size_t)1024 * 1024;
    float* dtT    = ws;                 // 4M f
    float* xi_duT = ws + 4*M1;          // xiraw (dead after conv_pack) -> duT
    float* zbuf   = ws + 8*M1;
    float* xibuf  = ws + 12*M1;
    float* xdbl   = ws + 16*M1;         // 0.64M f (atomic-accumulated)
    float* ytbuf  = ws + 17*M1;         // 4M f
    unsigned short* Apack = (unsigned short*)(ws + 21*M1);  // 20MB region
    unsigned int*   bcbuf = (unsigned int*)(ws + 21*M1);    // overlaps Apack (ordered)
    unsigned short* BpIn  = (unsigned short*)(ws + 26*M1);  // 2M u16
    unsigned short* BpX   = (unsigned short*)(ws + 27*M1);  // 0.5M u16
    unsigned short* BpOut = (unsigned short*)(ws + 27*M1 + 512*1024);  // 1M u16
    // total 28M floats = 112 MB

    // ---- prologue: LN+A-pack | weight packs | xdbl zero ----
    prologue<<<1312, 256, 0, stream>>>(x, norm_w, norm_b, in_proj_w, x_proj_w,
        out_proj_w, Apack, BpIn, BpX, BpOut, xdbl);

    // ---- in_proj: M=4096,N=2048,K=512; xi half 3-term, z half 1-term ----
    gemm_mfma<128,128,2,2,false><<<dim3(16, 32), 256, 0, stream>>>(
        Apack, BpIn, 4096, 2048, 512, /*cols3=*/DINNER, /*terms=*/3,
        xi_duT, zbuf, DINNER);

    // ---- fused conv+SiLU+pack: xibuf fp32 + Apack (x_proj A) ----
    conv_pack<<<(32 * 256) / 4, 256, 0, stream>>>(
        xi_duT, conv_w, conv_b, xibuf, Apack);

    // ---- x_proj: dt cols 3-term (atomic z-split), B/C cols 1-term ----
    gemm_mfma<128,64,2,2,true><<<dim3(3, 32, 3), 256, 0, stream>>>(
        Apack, BpX, 4096, 256, 1024, /*cols3=*/64, /*terms=*/0,
        xdbl, nullptr, XDBL_W);

    // ---- dt/du transposes + bc pack (one kernel); then scan ----
    dtdu_kernel<<<1024 + 64, 256, 0, stream>>>(xdbl, dt_proj_w, dt_proj_b,
        xibuf, dtT, xi_duT, bcbuf);
    scan_kernel<<<(BSZ * DINNER) / 4, 256, 0, stream>>>(
        dtT, xi_duT, bcbuf, A_log, ytbuf);

    // ---- fused gate+pack: Apack = out_proj A operand (bc dead) ----
    gate_pack<<<(32 * 256) / 4, 256, 0, stream>>>(
        ytbuf, xibuf, zbuf, Dvec, Apack);

    // ---- out_proj: M=4096,N=512,K=1024; 2-term single dispatch ----
    gemm_mfma<64,64,2,2,false><<<dim3(8, 64), 256, 0, stream>>>(
        Apack, BpOut, 4096, 512, 1024, /*cols3=*/512, /*terms=*/2,
        out, nullptr, D_MODEL);
}

// Round 14
// 256.776 us; speedup vs baseline: 1.7743x; 1.0609x over previous
//
#include <hip/hip_runtime.h>

#define D_MODEL 512
#define DINNER  1024
#define DSTATE  64
#define DTRANK  32
#define BSZ     2
#define NLEN    2048
#define NROWS   (BSZ*NLEN)   // 4096
#define XDBL_W  (DTRANK + 2*DSTATE)  // 160

typedef __attribute__((ext_vector_type(8))) short  bf16x8;
typedef __attribute__((ext_vector_type(4))) float  f32x4;
typedef __attribute__((ext_vector_type(8))) unsigned short u16x8;

__device__ __forceinline__ unsigned int rne16(float f) {
    unsigned int u = __float_as_uint(f);
    return (u + 0x7fffu + ((u >> 16) & 1)) >> 16;
}
__device__ __forceinline__ float fsilu(float x) {
    return x / (1.f + __builtin_amdgcn_exp2f(-x * 1.44269504f));
}

// ---- device helper: pack fp32 (RxK row-major) -> fragment-major split-bf16 ----
__device__ __forceinline__ void pack_frag(const float* __restrict__ src,
        unsigned short* __restrict__ dst, int R, int RT, int K,
        int gid, int lane) {
    const int kt = gid / RT, rt = gid - kt * RT;
    const int row = (rt << 4) + (lane & 15);
    const int KTK = K >> 5;
    u16x8 hi = {}, lo = {};
    if (row < R) {
        const float* s = src + (size_t)row * K + kt * 32 + ((lane >> 4) << 3);
        float4 f0 = *(const float4*)s;
        float4 f1 = *(const float4*)(s + 4);
        float ff[8] = {f0.x,f0.y,f0.z,f0.w,f1.x,f1.y,f1.z,f1.w};
        #pragma unroll
        for (int j = 0; j < 8; ++j) {
            unsigned int hb = rne16(ff[j]);
            hi[j] = (unsigned short)hb;
            lo[j] = (unsigned short)rne16(ff[j] - __uint_as_float(hb << 16));
        }
    }
    *(u16x8*)(dst + ((size_t)kt * RT + rt) * 512 + lane * 8) = hi;
    *(u16x8*)(dst + ((size_t)(kt + KTK) * RT + rt) * 512 + lane * 8) = lo;
}

// ---- prologue: LN+in_proj-A-pack | 3 weight packs | xdbl zero, by block range ----
__global__ __launch_bounds__(256) void prologue(const float* __restrict__ x,
        const float* __restrict__ nw, const float* __restrict__ nb,
        const float* __restrict__ in_w, const float* __restrict__ x_w,
        const float* __restrict__ out_w, unsigned short* __restrict__ Ap,
        unsigned short* __restrict__ BpIn, unsigned short* __restrict__ BpX,
        unsigned short* __restrict__ BpOut, float* __restrict__ xdbl) {
    __shared__ float xs[16][516];
    const int bid = blockIdx.x;
    const int wid = threadIdx.x >> 6, lane = threadIdx.x & 63;
    if (bid < 256) {
        const int rt = bid;
        const float4* wp = (const float4*)nw;
        const float4* bp = (const float4*)nb;
        const float4 w0 = wp[lane], w1 = wp[lane + 64];
        const float4 b0 = bp[lane], b1 = bp[lane + 64];
        #pragma unroll
        for (int pq = 0; pq < 4; ++pq) {
            const int r = (wid << 2) + pq;
            const int row = (rt << 4) + r;
            const float4* xp = (const float4*)(x + (size_t)row * D_MODEL);
            float4 v0 = xp[lane], v1 = xp[lane + 64];
            float s = v0.x + v0.y + v0.z + v0.w + v1.x + v1.y + v1.z + v1.w;
            float q = v0.x*v0.x + v0.y*v0.y + v0.z*v0.z + v0.w*v0.w
                    + v1.x*v1.x + v1.y*v1.y + v1.z*v1.z + v1.w*v1.w;
            #pragma unroll
            for (int m = 32; m; m >>= 1) { s += __shfl_xor(s, m); q += __shfl_xor(q, m); }
            const float mean = s * (1.f / D_MODEL);
            const float var  = q * (1.f / D_MODEL) - mean * mean;
            const float rstd = rsqrtf(var + 1e-5f);
            float4 o0, o1;
            o0.x = (v0.x - mean) * rstd * w0.x + b0.x;
            o0.y = (v0.y - mean) * rstd * w0.y + b0.y;
            o0.z = (v0.z - mean) * rstd * w0.z + b0.z;
            o0.w = (v0.w - mean) * rstd * w0.w + b0.w;
            o1.x = (v1.x - mean) * rstd * w1.x + b1.x;
            o1.y = (v1.y - mean) * rstd * w1.y + b1.y;
            o1.z = (v1.z - mean) * rstd * w1.z + b1.z;
            o1.w = (v1.w - mean) * rstd * w1.w + b1.w;
            *(float4*)&xs[r][lane << 2] = o0;
            *(float4*)&xs[r][256 + (lane << 2)] = o1;
        }
        __syncthreads();
        const int r = lane & 15;
        const int cq = (lane >> 4) << 3;
        #pragma unroll
        for (int q = 0; q < 4; ++q) {
            const int kt = (wid << 2) + q;       // KTK=16 for K=512
            const int c0 = (kt << 5) + cq;
            float4 f0 = *(const float4*)&xs[r][c0];
            float4 f1 = *(const float4*)&xs[r][c0 + 4];
            float ff[8] = {f0.x,f0.y,f0.z,f0.w,f1.x,f1.y,f1.z,f1.w};
            u16x8 hi, lo;
            #pragma unroll
            for (int j = 0; j < 8; ++j) {
                unsigned int hb = rne16(ff[j]);
                hi[j] = (unsigned short)hb;
                lo[j] = (unsigned short)rne16(ff[j] - __uint_as_float(hb << 16));
            }
            *(u16x8*)(Ap + ((size_t)kt * 256 + rt) * 512 + lane * 8) = hi;
            *(u16x8*)(Ap + ((size_t)(kt + 16) * 256 + rt) * 512 + lane * 8) = lo;
        }
    } else if (bid < 768) {
        pack_frag(in_w, BpIn, 2048, 128, 512, (bid - 256) * 4 + wid, lane);
    } else if (bid < 896) {
        pack_frag(x_w, BpX, 160, 16, 1024, (bid - 768) * 4 + wid, lane);
    } else if (bid < 1152) {
        pack_frag(out_w, BpOut, 512, 32, 1024, (bid - 896) * 4 + wid, lane);
    } else {
        float* p = xdbl + (size_t)(bid - 1152) * 4096 + threadIdx.x * 4;
        const float4 z4 = make_float4(0.f, 0.f, 0.f, 0.f);
        *(float4*)p = z4; *(float4*)(p + 1024) = z4;
        *(float4*)(p + 2048) = z4; *(float4*)(p + 3072) = z4;
    }
}

// ---- MFMA GEMM on packed operands, BK=64 ----
template<int BM, int BN, int WR, int WC, bool ATOMIC>
__global__ __launch_bounds__(256) void gemm_mfma(
        const unsigned short* __restrict__ Ap, const unsigned short* __restrict__ Bp,
        int M, int N, int K, int cols3, int terms,
        float* __restrict__ out0, float* __restrict__ out1, int split) {
    constexpr int MI = BM / (WR * 16);
    constexpr int NI = BN / (WC * 16);
    constexpr int APASS = BM / 64;
    constexpr int BPASS = BN / 64;
    __shared__ __align__(16) unsigned short sA[2 * BM * 32];
    __shared__ __align__(16) unsigned short sB[2 * BN * 32];
    const int tid = threadIdx.x;
    const int wid = tid >> 6, lane = tid & 63;
    const int wr = wid / WC, wc = wid % WC;
    const int m0 = blockIdx.y * BM, n0 = blockIdx.x * BN;
    if (ATOMIC && blockIdx.z > 0 && n0 >= cols3) return;
    const int MT = M >> 4, NT = N >> 4;
    const int KTK = K >> 5;
    const int KTv = ATOMIC ? KTK : ((n0 < cols3) ? terms * KTK : KTK);
    const int aoff = (ATOMIC && blockIdx.z == 1) ? KTK : 0;
    const int boff = (ATOMIC && blockIdx.z == 2) ? KTK : 0;
    f32x4 acc[MI][NI] = {};
    for (int kt2 = 0; kt2 < KTv; kt2 += 2) {
        __syncthreads();
        #pragma unroll
        for (int tt = 0; tt < 2; ++tt) {
            const int kt = kt2 + tt;
            int a_kt, b_kt;
            if (ATOMIC) { a_kt = kt + aoff; b_kt = kt + boff; }
            else { a_kt = (kt < 2 * KTK) ? kt : kt - 2 * KTK;   // hi, lo, hi
                   b_kt = (kt < KTK) ? kt : kt - KTK; }         // hi, hi, lo
            const char* gA = (const char*)(Ap + ((size_t)a_kt * MT + (m0 >> 4)) * 512);
            const char* gB = (const char*)(Bp + ((size_t)b_kt * NT + (n0 >> 4)) * 512);
            #pragma unroll
            for (int p = 0; p < APASS; ++p)
                __builtin_amdgcn_global_load_lds(
                    (const __attribute__((address_space(1))) void*)(gA + p * 4096 + tid * 16),
                    (__attribute__((address_space(3))) void*)((char*)sA + tt * BM * 64 + p * 4096 + tid * 16),
                    16, 0, 0);
            #pragma unroll
            for (int p = 0; p < BPASS; ++p)
                __builtin_amdgcn_global_load_lds(
                    (const __attribute__((address_space(1))) void*)(gB + p * 4096 + tid * 16),
                    (__attribute__((address_space(3))) void*)((char*)sB + tt * BN * 64 + p * 4096 + tid * 16),
                    16, 0, 0);
        }
        __syncthreads();
        #pragma unroll
        for (int tt = 0; tt < 2; ++tt) {
            bf16x8 af[MI], bfr[NI];
            #pragma unroll
            for (int mi = 0; mi < MI; ++mi)
                af[mi] = *(const bf16x8*)((const char*)sA + tt*BM*64 + (wr*MI + mi)*1024 + lane*16);
            #pragma unroll
            for (int ni = 0; ni < NI; ++ni)
                bfr[ni] = *(const bf16x8*)((const char*)sB + tt*BN*64 + (wc*NI + ni)*1024 + lane*16);
            #pragma unroll
            for (int mi = 0; mi < MI; ++mi)
                #pragma unroll
                for (int ni = 0; ni < NI; ++ni)
                    acc[mi][ni] = __builtin_amdgcn_mfma_f32_16x16x32_bf16(
                        af[mi], bfr[ni], acc[mi][ni], 0, 0, 0);
        }
    }
    #pragma unroll
    for (int mi = 0; mi < MI; ++mi) {
        #pragma unroll
        for (int ni = 0; ni < NI; ++ni) {
            const int col = n0 + (wc*NI + ni)*16 + (lane & 15);
            const int rb_ = m0 + (wr*MI + mi)*16 + ((lane >> 4) << 2);
            if (col < split) {
                #pragma unroll
                for (int r = 0; r < 4; ++r) {
                    if (ATOMIC) atomicAdd(&out0[(size_t)(rb_ + r) * split + col], acc[mi][ni][r]);
                    else        out0[(size_t)(rb_ + r) * split + col] = acc[mi][ni][r];
                }
            } else if (!ATOMIC && out1 != nullptr) {
                #pragma unroll
                for (int r = 0; r < 4; ++r)
                    out1[(size_t)(rb_ + r) * (N - split) + (col - split)] = acc[mi][ni][r];
            }
        }
    }
}

// ---- fused causal depthwise conv (k=4) + SiLU + x_proj A-pack ----
__global__ __launch_bounds__(256) void conv_pack(const float* __restrict__ xr,
        const float* __restrict__ cw, const float* __restrict__ cb,
        float* __restrict__ xi, unsigned short* __restrict__ Ap) {
    const int wid = threadIdx.x >> 6, lane = threadIdx.x & 63;
    const int gid = (blockIdx.x << 2) + wid;     // [0, 32*256)
    const int kt = gid >> 8, rt = gid & 255;
    const int row = (rt << 4) + (lane & 15);
    const int n = row & (NLEN - 1);
    const int d0 = (kt << 5) + ((lane >> 4) << 3);
    const float* base = xr + (size_t)row * DINNER + d0;
    const float4 z4 = make_float4(0.f, 0.f, 0.f, 0.f);
    float4 c0 = *(const float4*)base,          c1 = *(const float4*)(base + 4);
    float4 a0 = (n >= 1) ? *(const float4*)(base - DINNER)     : z4;
    float4 a1 = (n >= 1) ? *(const float4*)(base - DINNER + 4) : z4;
    float4 b0 = (n >= 2) ? *(const float4*)(base - 2*DINNER)     : z4;
    float4 b1 = (n >= 2) ? *(const float4*)(base - 2*DINNER + 4) : z4;
    float4 e0 = (n >= 3) ? *(const float4*)(base - 3*DINNER)     : z4;
    float4 e1 = (n >= 3) ? *(const float4*)(base - 3*DINNER + 4) : z4;
    float cur[8] = {c0.x,c0.y,c0.z,c0.w,c1.x,c1.y,c1.z,c1.w};
    float p1[8]  = {a0.x,a0.y,a0.z,a0.w,a1.x,a1.y,a1.z,a1.w};
    float p2[8]  = {b0.x,b0.y,b0.z,b0.w,b1.x,b1.y,b1.z,b1.w};
    float p3[8]  = {e0.x,e0.y,e0.z,e0.w,e1.x,e1.y,e1.z,e1.w};
    float o[8];
    u16x8 hi, lo;
    #pragma unroll
    for (int j = 0; j < 8; ++j) {
        const float4 wv = *(const float4*)(cw + (d0 + j) * 4);
        float a = cb[d0 + j];
        a = fmaf(wv.w, cur[j], a);
        a = fmaf(wv.z, p1[j], a);
        a = fmaf(wv.y, p2[j], a);
        a = fmaf(wv.x, p3[j], a);
        o[j] = fsilu(a);
        unsigned int hb = rne16(o[j]);
        hi[j] = (unsigned short)hb;
        lo[j] = (unsigned short)rne16(o[j] - __uint_as_float(hb << 16));
    }
    float* xo = xi + (size_t)row * DINNER + d0;
    *(float4*)xo = make_float4(o[0], o[1], o[2], o[3]);
    *(float4*)(xo + 4) = make_float4(o[4], o[5], o[6], o[7]);
    *(u16x8*)(Ap + ((size_t)kt * 256 + rt) * 512 + lane * 8) = hi;
    *(u16x8*)(Ap + ((size_t)(kt + 32) * 256 + rt) * 512 + lane * 8) = lo;
}

// ---- dt/du tiled GEMV+softplus+transpose ([0,1024)) + quad-bc pack ([1024,1088)) ----
// bc quad layout: bc[(row>>2)*256 + s*4 + (row&3)] = bf16(B) | bf16(C)<<16
__global__ __launch_bounds__(256) void dtdu_kernel(const float* __restrict__ xdbl,
        const float* __restrict__ W, const float* __restrict__ bias,
        const float* __restrict__ u, float* __restrict__ dtT,
        float* __restrict__ duT, unsigned int* __restrict__ bc) {
    if (blockIdx.x >= 1024) {
        const int row0 = (blockIdx.x - 1024) << 6;
        #pragma unroll
        for (int k = 0; k < 16; ++k) {
            const int g = threadIdx.x * 16 + k;      // 0..4095
            const int lr = g >> 6, s = g & 63;
            const int row = row0 + lr;
            const float* src = xdbl + (size_t)row * XDBL_W + DTRANK + s;
            bc[(size_t)(row >> 2) * 256 + s * 4 + (row & 3)] =
                rne16(src[0]) | (rne16(src[DSTATE]) << 16);
        }
        return;
    }
    __shared__ float sdtr[64][33];
    __shared__ float sW[64][33];
    __shared__ float tt[64][65];
    const int nb = blockIdx.x & 63, db = blockIdx.x >> 6;
    const int row0 = nb << 6, d0 = db << 6;
    const int i = threadIdx.x >> 2, kq = (threadIdx.x & 3) << 3;
    {
        const float* s = xdbl + (size_t)(row0 + i) * XDBL_W + kq;
        *(float4*)&sdtr[i][kq]     = *(const float4*)s;
        *(float4*)&sdtr[i][kq + 4] = *(const float4*)(s + 4);
        const float* wsrc = W + (size_t)(d0 + i) * DTRANK + kq;
        *(float4*)&sW[i][kq]     = *(const float4*)wsrc;
        *(float4*)&sW[i][kq + 4] = *(const float4*)(wsrc + 4);
    }
    __syncthreads();
    const int i4 = (threadIdx.x >> 4) << 2;
    const int j4 = (threadIdx.x & 15) << 2;
    float dtv[4][4], duv[4][4];
    {
        float acc[4][4] = {};
        #pragma unroll
        for (int k = 0; k < DTRANK; ++k) {
            float a[4]  = {sdtr[i4][k], sdtr[i4+1][k], sdtr[i4+2][k], sdtr[i4+3][k]};
            float bb[4] = {sW[j4][k], sW[j4+1][k], sW[j4+2][k], sW[j4+3][k]};
            #pragma unroll
            for (int ii = 0; ii < 4; ++ii)
                #pragma unroll
                for (int jj = 0; jj < 4; ++jj)
                    acc[ii][jj] = fmaf(a[ii], bb[jj], acc[ii][jj]);
        }
        float4 bv = *(const float4*)(bias + d0 + j4);
        float bb4[4] = {bv.x, bv.y, bv.z, bv.w};
        #pragma unroll
        for (int ii = 0; ii < 4; ++ii) {
            float4 uv = *(const float4*)(u + (size_t)(row0 + i4 + ii) * DINNER + d0 + j4);
            float uu[4] = {uv.x, uv.y, uv.z, uv.w};
            #pragma unroll
            for (int jj = 0; jj < 4; ++jj) {
                float z = acc[ii][jj] + bb4[jj];
                float dt = (z > 20.f) ? z : log1pf(expf(z));
                dtv[ii][jj] = dt;
                duv[ii][jj] = dt * uu[jj];
            }
        }
    }
    const int b = row0 >> 11;
    const int n0 = row0 & (NLEN - 1);
    const int jt = threadIdx.x >> 2, iq = (threadIdx.x & 3) << 4;
    float* dstD = dtT + ((size_t)(b * DINNER + d0 + jt)) * NLEN + n0 + iq;
    float* dstU = duT + ((size_t)(b * DINNER + d0 + jt)) * NLEN + n0 + iq;
    #pragma unroll
    for (int ii = 0; ii < 4; ++ii)
        #pragma unroll
        for (int jj = 0; jj < 4; ++jj)
            tt[i4 + ii][j4 + jj] = dtv[ii][jj];
    __syncthreads();
    #pragma unroll
    for (int r = 0; r < 4; ++r) {
        float4 o = make_float4(tt[iq+4*r+0][jt], tt[iq+4*r+1][jt],
                               tt[iq+4*r+2][jt], tt[iq+4*r+3][jt]);
        *(float4*)(dstD + 4*r) = o;
    }
    __syncthreads();
    #pragma unroll
    for (int ii = 0; ii < 4; ++ii)
        #pragma unroll
        for (int jj = 0; jj < 4; ++jj)
            tt[i4 + ii][j4 + jj] = duv[ii][jj];
    __syncthreads();
    #pragma unroll
    for (int r = 0; r < 4; ++r) {
        float4 o = make_float4(tt[iq+4*r+0][jt], tt[iq+4*r+1][jt],
                               tt[iq+4*r+2][jt], tt[iq+4*r+3][jt]);
        *(float4*)(dstU + 4*r) = o;
    }
}

// ---------------- selective scan: quad-packed bc (dwordx4 = 4 steps) ----------------
// Per 4 steps: 1 coalesced global_load_dwordx4; per step: 1 uniform ds_read_b64
// (dt,du broadcast), exp2+fma+mul, pw write. Next-block dt/du reg-prefetched.
__global__ __launch_bounds__(256) void scan_kernel(const float* __restrict__ dtT,
        const float* __restrict__ duT, const unsigned int* __restrict__ bc,
        const float* __restrict__ A_log, float* __restrict__ yt) {
    __shared__ float p[4][32][65];
    __shared__ float2 dd[4][64];
    const int wid = threadIdx.x >> 6;
    const int w = (blockIdx.x << 2) + wid;   // b*1024+d
    const int lane = threadIdx.x & 63;
    const int b = w >> 10, d = w & (DINNER - 1);
    const float* dtp = dtT + (size_t)w * NLEN;
    const float* dup = duT + (size_t)w * NLEN;
    const unsigned int* bcb = bc + (size_t)b * NLEN * 64 + lane * 4;  // quad layout
    float* yp = yt + (size_t)w * NLEN;
    const float kA = -__builtin_amdgcn_exp2f(A_log[d * DSTATE + lane] * 1.44269504f)
                     * 1.44269504f;   // A*log2(e)
    float (*pw)[65] = p[wid];
    float2* ddw = dd[wid];
    const int rn = lane & 31, rs = (lane >> 5) << 5;
    float h = 0.f;
    float gdt = dtp[lane], gdu = dup[lane];
    for (int n0 = 0; n0 < NLEN; n0 += 64) {
        ddw[lane] = make_float2(gdt, gdu);      // wave-private; lgkmcnt-ordered
        if (n0 + 64 < NLEN) { gdt = dtp[n0 + 64 + lane]; gdu = dup[n0 + 64 + lane]; }
        const unsigned int* bq = bcb + (size_t)n0 * 64;   // 16 quads of 256 u32
        #pragma unroll
        for (int half = 0; half < 2; ++half) {
            const unsigned int* bh  = bq + (half << 3) * 256;
            const unsigned int* bh2 = bh + 4 * 256;
            #pragma unroll
            for (int g = 0; g < 8; ++g) {
                const uint4 qv = (g < 4) ? *(const uint4*)(bh + g * 256)
                                         : *(const uint4*)(bh2 + (g - 4) * 256);
                #pragma unroll
                for (int e = 0; e < 4; ++e) {
                    const int j = (g << 2) + e;            // 0..31 within half
                    const unsigned int q = (e == 0) ? qv.x : (e == 1) ? qv.y
                                         : (e == 2) ? qv.z : qv.w;
                    const float2 v = ddw[(half << 5) + j];  // uniform broadcast
                    const float Bv = __uint_as_float(q << 16);
                    const float Cv = __uint_as_float(q & 0xffff0000u);
                    h = fmaf(__builtin_amdgcn_exp2f(kA * v.x), h, v.y * Bv);
                    pw[j][lane] = h * Cv;
                }
            }
            float y0 = 0.f, y1 = 0.f, y2 = 0.f, y3 = 0.f;
            #pragma unroll
            for (int i = 0; i < 32; i += 4) {
                y0 += pw[rn][rs + i];
                y1 += pw[rn][rs + i + 1];
                y2 += pw[rn][rs + i + 2];
                y3 += pw[rn][rs + i + 3];
            }
            float y = (y0 + y1) + (y2 + y3);
            y += __shfl_xor(y, 32);
            if (lane < 32) yp[n0 + (half << 5) + rn] = y;
        }
    }
}

// ---- fused gate + out_proj A-pack ----
__global__ __launch_bounds__(256) void gate_pack(const float* __restrict__ yt,
        const float* __restrict__ xi, const float* __restrict__ z,
        const float* __restrict__ Dv, unsigned short* __restrict__ Ap) {
    const int wid = threadIdx.x >> 6, lane = threadIdx.x & 63;
    const int gid = (blockIdx.x << 2) + wid;     // [0, 32*256)
    const int kt = gid >> 8, rt = gid & 255;
    const int row = (rt << 4) + (lane & 15);
    const int n = row & (NLEN - 1), b = row >> 11;
    const int d0 = (kt << 5) + ((lane >> 4) << 3);
    const float* ytp = yt + ((size_t)(b * DINNER + d0)) * NLEN + n;
    const float* xp = xi + (size_t)row * DINNER + d0;
    const float* zp = z  + (size_t)row * DINNER + d0;
    float4 x0 = *(const float4*)xp, x1 = *(const float4*)(xp + 4);
    float4 z0 = *(const float4*)zp, z1 = *(const float4*)(zp + 4);
    float4 D0 = *(const float4*)(Dv + d0), D1 = *(const float4*)(Dv + d0 + 4);
    float xv[8] = {x0.x,x0.y,x0.z,x0.w,x1.x,x1.y,x1.z,x1.w};
    float zv[8] = {z0.x,z0.y,z0.z,z0.w,z1.x,z1.y,z1.z,z1.w};
    float dv[8] = {D0.x,D0.y,D0.z,D0.w,D1.x,D1.y,D1.z,D1.w};
    u16x8 hi, lo;
    #pragma unroll
    for (int j = 0; j < 8; ++j) {
        const float yv = ytp[(size_t)j * NLEN];
        const float g = fmaf(xv[j], dv[j], yv) * fsilu(zv[j]);
        unsigned int hb = rne16(g);
        hi[j] = (unsigned short)hb;
        lo[j] = (unsigned short)rne16(g - __uint_as_float(hb << 16));
    }
    *(u16x8*)(Ap + ((size_t)kt * 256 + rt) * 512 + lane * 8) = hi;
    *(u16x8*)(Ap + ((size_t)(kt + 32) * 256 + rt) * 512 + lane * 8) = lo;
}

extern "C" void kernel_launch(void* const* d_in, const int* in_sizes, int n_in,
                              void* d_out, int out_size, void* d_ws, size_t ws_size,
                              hipStream_t stream) {
    const float* x         = (const float*)d_in[0];
    const float* norm_w    = (const float*)d_in[1];
    const float* norm_b    = (const float*)d_in[2];
    const float* in_proj_w = (const float*)d_in[3];
    const float* conv_w    = (const float*)d_in[4];
    const float* conv_b    = (const float*)d_in[5];
    const float* x_proj_w  = (const float*)d_in[6];
    const float* dt_proj_w = (const float*)d_in[7];
    const float* dt_proj_b = (const float*)d_in[8];
    const float* A_log     = (const float*)d_in[9];
    const float* Dvec      = (const float*)d_in[10];
    const float* out_proj_w= (const float*)d_in[11];
    float* out = (float*)d_out;
    float* ws  = (float*)d_ws;

    const size_t M1 = (size_t)1024 * 1024;
    float* dtT    = ws;                 // 4M f
    float* xi_duT = ws + 4*M1;          // xiraw (dead after conv_pack) -> duT
    float* zbuf   = ws + 8*M1;
    float* xibuf  = ws + 12*M1;
    float* xdbl   = ws + 16*M1;         // 0.64M f (atomic-accumulated)
    float* ytbuf  = ws + 17*M1;         // 4M f
    unsigned short* Apack = (unsigned short*)(ws + 21*M1);  // 20MB region
    unsigned int*   bcbuf = (unsigned int*)(ws + 21*M1);    // overlaps Apack (ordered)
    unsigned short* BpIn  = (unsigned short*)(ws + 26*M1);
    unsigned short* BpX   = (unsigned short*)(ws + 27*M1);
    unsigned short* BpOut = (unsigned short*)(ws + 27*M1 + 512*1024);

    // ---- prologue: LN+A-pack | weight packs | xdbl zero ----
    prologue<<<1312, 256, 0, stream>>>(x, norm_w, norm_b, in_proj_w, x_proj_w,
        out_proj_w, Apack, BpIn, BpX, BpOut, xdbl);

    // ---- in_proj: M=4096,N=2048,K=512; xi half 2-term, z half 1-term ----
    gemm_mfma<128,128,2,2,false><<<dim3(16, 32), 256, 0, stream>>>(
        Apack, BpIn, 4096, 2048, 512, /*cols3=*/DINNER, /*terms=*/2,
        xi_duT, zbuf, DINNER);

    // ---- fused conv+SiLU+pack: xibuf fp32 + Apack (x_proj A) ----
    conv_pack<<<(32 * 256) / 4, 256, 0, stream>>>(
        xi_duT, conv_w, conv_b, xibuf, Apack);

    // ---- x_proj: dt cols 2-term (atomic z-split), B/C cols 1-term ----
    gemm_mfma<128,64,2,2,true><<<dim3(3, 32, 2), 256, 0, stream>>>(
        Apack, BpX, 4096, 256, 1024, /*cols3=*/64, /*terms=*/0,
        xdbl, nullptr, XDBL_W);

    // ---- dt/du transposes + quad-bc pack (one kernel); then scan ----
    dtdu_kernel<<<1024 + 64, 256, 0, stream>>>(xdbl, dt_proj_w, dt_proj_b,
        xibuf, dtT, xi_duT, bcbuf);
    scan_kernel<<<(BSZ * DINNER) / 4, 256, 0, stream>>>(
        dtT, xi_duT, bcbuf, A_log, ytbuf);

    // ---- fused gate+pack: Apack = out_proj A operand (bc dead) ----
    gate_pack<<<(32 * 256) / 4, 256, 0, stream>>>(
        ytbuf, xibuf, zbuf, Dvec, Apack);

    // ---- out_proj: M=4096,N=512,K=1024; 2-term single dispatch ----
    gemm_mfma<64,64,2,2,false><<<dim3(8, 64), 256, 0, stream>>>(
        Apack, BpOut, 4096, 512, 1024, /*cols3=*/512, /*terms=*/2,
        out, nullptr, D_MODEL);
}